// Round 5
// baseline (1378.757 us; speedup 1.0000x reference)
//
#include <hip/hip_runtime.h>
#include <math.h>

#define B_ 16
#define L_ 1024
#define M_TOT (B_*L_)   // 16384

__device__ __forceinline__ float wave_reduce_sum(float v) {
#pragma unroll
  for (int o = 32; o >= 1; o >>= 1) v += __shfl_xor(v, o, 64);
  return v;
}

__device__ __forceinline__ unsigned short f2bf(float f) {
  union { float f; unsigned u; } v; v.f = f;
  unsigned r = v.u + 0x7FFFu + ((v.u >> 16) & 1u);
  return (unsigned short)(r >> 16);
}
__device__ __forceinline__ float bf2f(unsigned short s) {
  union { unsigned u; float f; } v; v.u = ((unsigned)s) << 16; return v.f;
}

// ---------------- featurize: 4 points per 256-thr block ----------------
__global__ __launch_bounds__(256) void featurize_kernel(
    const float* __restrict__ pts, const float* __restrict__ fs, const float* __restrict__ ft,
    const float* __restrict__ w_space, const float* __restrict__ b_space,
    const float* __restrict__ w_time, const float* __restrict__ b_time,
    const float* __restrict__ w_fout, const float* __restrict__ b_fout,
    const float* __restrict__ w_gate, const float* __restrict__ b_gate,
    float* __restrict__ z, int* __restrict__ boundary)
{
  const int sub = threadIdx.x >> 6;
  const int d   = threadIdx.x & 63;
  const int p   = blockIdx.x * 4 + sub;
  const float TWO_PI = 6.283185307179586f;
  __shared__ float feat[4][32];
  __shared__ float tfeat[4][16];
  __shared__ float g96[4][96];
  const float x = pts[p*3+0], y = pts[p*3+1], t = pts[p*3+2];
  if (d < 16) {
    float sp = (x*fs[d] + y*fs[16+d]) * TWO_PI;
    feat[sub][d]    = sinf(sp);
    feat[sub][16+d] = cosf(sp);
  } else if (d < 24) {
    int r = d - 16;
    float tp = t * ft[r] * TWO_PI;
    tfeat[sub][r]   = sinf(tp);
    tfeat[sub][8+r] = cosf(tp);
  }
  __syncthreads();
  float sf = b_space[d];
#pragma unroll
  for (int k2 = 0; k2 < 32; ++k2) sf = fmaf(feat[sub][k2], w_space[k2*64+d], sf);
  g96[sub][d] = sf;
  if (d < 32) {
    float tf = b_time[d];
#pragma unroll
    for (int k2 = 0; k2 < 16; ++k2) tf = fmaf(tfeat[sub][k2], w_time[k2*32+d], tf);
    g96[sub][64+d] = tf;
  }
  __syncthreads();
  float zv = b_fout[d];
#pragma unroll
  for (int k2 = 0; k2 < 96; ++k2) zv = fmaf(g96[sub][k2], w_fout[k2*64+d], zv);
  z[(size_t)p*64+d] = zv;
  float gv = wave_reduce_sum(zv * w_gate[d]);
  if (d == 0) {
    float logit = gv + b_gate[0];
    float gate = 1.0f / (1.0f + expf(-logit));
    int bnd = (gate > 0.5f) ? 1 : 0;
    if ((p & (L_-1)) == 0) bnd = 1;
    boundary[p] = bnd;
  }
}

// ---------------- scan: seg_id, seg_start, n_seg ----------------
__global__ __launch_bounds__(1024) void scan_kernel(const int* __restrict__ boundary,
    int* __restrict__ seg_id, int* __restrict__ seg_start, int* __restrict__ n_seg)
{
  __shared__ int sc[1024];
  const int b = blockIdx.x, l = threadIdx.x;
  const int v = boundary[b*L_ + l];
  sc[l] = v;
  __syncthreads();
  for (int off = 1; off < 1024; off <<= 1) {
    int add = (l >= off) ? sc[l - off] : 0;
    __syncthreads();
    sc[l] += add;
    __syncthreads();
  }
  const int sid = sc[l] - 1;
  seg_id[b*L_ + l] = sid;
  if (v) seg_start[b*(L_+1) + sid] = l;
  if (l == L_-1) {
    n_seg[b] = sid + 1;
    seg_start[b*(L_+1) + sid + 1] = L_;
  }
}

// ---------------- GEMM v3: wave-uniform W slices, A transposed in LDS ----------
// block = 256 thr (4 waves); wave w computes 16 cols [ct*64 + w*16 .. +16)
// grid: dim3(M/64, NPARTS*PN/64). W layout: [NPARTS][K][PN]; C: [M][NPARTS*PN].
template<int K, int PN, int NPARTS, bool RELU, bool GATED>
__global__ __launch_bounds__(256) void gemm3_kernel(
    const float* __restrict__ A, const float* __restrict__ W,
    const float* __restrict__ bias, float* __restrict__ C,
    const int* __restrict__ nseg)
{
  constexpr int NOUT = NPARTS * PN;
  constexpr int CPP  = PN / 64;
  const int row0 = blockIdx.x * 64;
  if (GATED) { const int b = row0 >> 10; if ((row0 & (L_-1)) >= nseg[b]) return; }
  const int ct   = blockIdx.y;
  const int part = ct / CPP;
  const int sub  = (ct % CPP) * 64;
  const float* Wp = W + (size_t)part * K * PN + sub;
  const int cbase = part * PN + sub;
  const int wv = (int)threadIdx.x >> 6;
  const int ln = (int)threadIdx.x & 63;
  const int n0 = wv * 16;
  const int row = row0 + ln;

  __shared__ float As[32][68];   // [k][m], +4 pad

  float acc[16];
#pragma unroll
  for (int i = 0; i < 16; ++i) acc[i] = 0.f;

  for (int k0 = 0; k0 < K; k0 += 32) {
    __syncthreads();
    {
      const int r = (int)threadIdx.x >> 2;        // 0..63
      const int c = ((int)threadIdx.x & 3) * 8;   // 0,8,16,24
      const float4* src = reinterpret_cast<const float4*>(A + (size_t)(row0 + r)*K + k0 + c);
      float4 v0 = src[0], v1 = src[1];
      As[c+0][r] = v0.x; As[c+1][r] = v0.y; As[c+2][r] = v0.z; As[c+3][r] = v0.w;
      As[c+4][r] = v1.x; As[c+5][r] = v1.y; As[c+6][r] = v1.z; As[c+7][r] = v1.w;
    }
    __syncthreads();
#pragma unroll
    for (int kk = 0; kk < 32; ++kk) {
      const float a = As[kk][ln];
      const float4* wr = reinterpret_cast<const float4*>(Wp + (size_t)(k0 + kk) * PN + n0);
      float4 w0 = wr[0], w1 = wr[1], w2 = wr[2], w3 = wr[3];
      acc[ 0] = fmaf(a, w0.x, acc[ 0]); acc[ 1] = fmaf(a, w0.y, acc[ 1]);
      acc[ 2] = fmaf(a, w0.z, acc[ 2]); acc[ 3] = fmaf(a, w0.w, acc[ 3]);
      acc[ 4] = fmaf(a, w1.x, acc[ 4]); acc[ 5] = fmaf(a, w1.y, acc[ 5]);
      acc[ 6] = fmaf(a, w1.z, acc[ 6]); acc[ 7] = fmaf(a, w1.w, acc[ 7]);
      acc[ 8] = fmaf(a, w2.x, acc[ 8]); acc[ 9] = fmaf(a, w2.y, acc[ 9]);
      acc[10] = fmaf(a, w2.z, acc[10]); acc[11] = fmaf(a, w2.w, acc[11]);
      acc[12] = fmaf(a, w3.x, acc[12]); acc[13] = fmaf(a, w3.y, acc[13]);
      acc[14] = fmaf(a, w3.z, acc[14]); acc[15] = fmaf(a, w3.w, acc[15]);
    }
  }
  const float* bp = bias + cbase + n0;
  float4 b0 = reinterpret_cast<const float4*>(bp)[0];
  float4 b1 = reinterpret_cast<const float4*>(bp)[1];
  float4 b2 = reinterpret_cast<const float4*>(bp)[2];
  float4 b3 = reinterpret_cast<const float4*>(bp)[3];
  float o[16];
  o[0]=acc[0]+b0.x; o[1]=acc[1]+b0.y; o[2]=acc[2]+b0.z; o[3]=acc[3]+b0.w;
  o[4]=acc[4]+b1.x; o[5]=acc[5]+b1.y; o[6]=acc[6]+b1.z; o[7]=acc[7]+b1.w;
  o[8]=acc[8]+b2.x; o[9]=acc[9]+b2.y; o[10]=acc[10]+b2.z; o[11]=acc[11]+b2.w;
  o[12]=acc[12]+b3.x; o[13]=acc[13]+b3.y; o[14]=acc[14]+b3.z; o[15]=acc[15]+b3.w;
  if (RELU) {
#pragma unroll
    for (int i = 0; i < 16; ++i) o[i] = fmaxf(o[i], 0.f);
  }
  float4* cp = reinterpret_cast<float4*>(C + (size_t)row*NOUT + cbase + n0);
  cp[0] = make_float4(o[0],o[1],o[2],o[3]);
  cp[1] = make_float4(o[4],o[5],o[6],o[7]);
  cp[2] = make_float4(o[8],o[9],o[10],o[11]);
  cp[3] = make_float4(o[12],o[13],o[14],o[15]);
}

// ---------------- segment attention (block-diagonal, exact; fixed-shift) -------
// qkv packed: [row][3][64]; q at +0, k at +64, v at +128 (h*32 within part)
__global__ __launch_bounds__(64) void seg_attn_kernel(
    const float* __restrict__ qkv,
    const int* __restrict__ seg_id, const int* __restrict__ seg_start,
    float* __restrict__ ao)
{
  const int idx = blockIdx.x * 64 + threadIdx.x;  // ((b*L + pt)*2 + h)
  const int h  = idx & 1;
  const int pt = (idx >> 1) & (L_-1);
  const int b  = idx >> 11;
  const float scale = 0.17677669529663687f; // 1/sqrt(32)
  float qv[32];
  {
    const float4* qp = reinterpret_cast<const float4*>(qkv + (size_t)(b*L_+pt)*192 + h*32);
#pragma unroll
    for (int j4 = 0; j4 < 8; ++j4) {
      float4 t4 = qp[j4];
      qv[j4*4+0]=t4.x*scale; qv[j4*4+1]=t4.y*scale; qv[j4*4+2]=t4.z*scale; qv[j4*4+3]=t4.w*scale;
    }
  }
  const int s  = seg_id[b*L_ + pt];
  const int j0 = seg_start[b*(L_+1) + s];
  const int j1 = seg_start[b*(L_+1) + s + 1];
  float lsum = 0.f;
  float acc[32];
#pragma unroll
  for (int d = 0; d < 32; ++d) acc[d] = 0.f;
  for (int j = j0; j < j1; ++j) {
    const float* base = qkv + (size_t)(b*L_ + j)*192 + h*32;
    const float4* kp = reinterpret_cast<const float4*>(base + 64);
    float dot = 0.f;
#pragma unroll
    for (int j4 = 0; j4 < 8; ++j4) {
      float4 t4 = kp[j4];
      dot = fmaf(qv[j4*4+0], t4.x, dot);
      dot = fmaf(qv[j4*4+1], t4.y, dot);
      dot = fmaf(qv[j4*4+2], t4.z, dot);
      dot = fmaf(qv[j4*4+3], t4.w, dot);
    }
    const float p = __expf(fminf(dot, 30.f));
    lsum += p;
    const float4* vp = reinterpret_cast<const float4*>(base + 128);
#pragma unroll
    for (int j4 = 0; j4 < 8; ++j4) {
      float4 t4 = vp[j4];
      acc[j4*4+0] = fmaf(p, t4.x, acc[j4*4+0]);
      acc[j4*4+1] = fmaf(p, t4.y, acc[j4*4+1]);
      acc[j4*4+2] = fmaf(p, t4.z, acc[j4*4+2]);
      acc[j4*4+3] = fmaf(p, t4.w, acc[j4*4+3]);
    }
  }
  const float inv = 1.0f / lsum;
  float* op = ao + (size_t)(b*L_+pt)*64 + h*32;
#pragma unroll
  for (int d = 0; d < 32; ++d) op[d] = acc[d] * inv;
}

// ---------------- global attention: 256 thr, NQ=2, kt=8 key-split --------------
// grid: blockIdx.x = (((b*4 + h)*2 + qt)*8 + kt)
// xqkv packed: [row][3][128]; q +0, k +128, v +256
__global__ __launch_bounds__(256) void glb_attn_kernel(
    const float* __restrict__ xqkv, const int* __restrict__ n_seg,
    unsigned short* __restrict__ part_acc, float* __restrict__ part_lsum)
{
  const int kt = blockIdx.x & 7;
  const int qt = (blockIdx.x >> 3) & 1;
  const int h  = (blockIdx.x >> 4) & 3;
  const int b  = blockIdx.x >> 6;
  const int ns = n_seg[b];
  if (qt*512 >= ns) return;
  const int kchunk = (ns + 7) >> 3;
  const int kbeg = kt * kchunk;
  const int kend = min(ns, kbeg + kchunk);
  if (kbeg >= kend) return;

  const int tid = (int)threadIdx.x;
  const int q0 = qt*512 + tid;
  const int q1 = q0 + 256;
  const bool a0 = q0 < ns, a1 = q1 < ns;
  const float scale = 0.17677669529663687f;

  __shared__ float Ks[64][36];
  __shared__ float Vs[64][36];

  float qv0[32], qv1[32];
#pragma unroll
  for (int d = 0; d < 32; ++d) { qv0[d] = 0.f; qv1[d] = 0.f; }
  if (a0) {
    const float4* qp = reinterpret_cast<const float4*>(xqkv + (size_t)(b*L_+q0)*384 + h*32);
#pragma unroll
    for (int j4 = 0; j4 < 8; ++j4) {
      float4 t4 = qp[j4];
      qv0[j4*4+0]=t4.x*scale; qv0[j4*4+1]=t4.y*scale; qv0[j4*4+2]=t4.z*scale; qv0[j4*4+3]=t4.w*scale;
    }
  }
  if (a1) {
    const float4* qp = reinterpret_cast<const float4*>(xqkv + (size_t)(b*L_+q1)*384 + h*32);
#pragma unroll
    for (int j4 = 0; j4 < 8; ++j4) {
      float4 t4 = qp[j4];
      qv1[j4*4+0]=t4.x*scale; qv1[j4*4+1]=t4.y*scale; qv1[j4*4+2]=t4.z*scale; qv1[j4*4+3]=t4.w*scale;
    }
  }

  float l0 = 0.f, l1 = 0.f;
  float acc0[32], acc1[32];
#pragma unroll
  for (int d = 0; d < 32; ++d) { acc0[d] = 0.f; acc1[d] = 0.f; }

  for (int j0 = kbeg; j0 < kend; j0 += 64) {
    const int nj = min(64, kend - j0);
    __syncthreads();
    {
      const int jr = tid >> 2;
      const int c  = (tid & 3) * 8;
      if (jr < nj) {
        const float* base = xqkv + (size_t)(b*L_ + j0 + jr)*384 + h*32 + c;
        *reinterpret_cast<float4*>(&Ks[jr][c])   = *reinterpret_cast<const float4*>(base + 128);
        *reinterpret_cast<float4*>(&Ks[jr][c+4]) = *reinterpret_cast<const float4*>(base + 132);
        *reinterpret_cast<float4*>(&Vs[jr][c])   = *reinterpret_cast<const float4*>(base + 256);
        *reinterpret_cast<float4*>(&Vs[jr][c+4]) = *reinterpret_cast<const float4*>(base + 260);
      }
    }
    __syncthreads();
#pragma unroll 2
    for (int j = 0; j < nj; ++j) {
      const float4* kr = reinterpret_cast<const float4*>(&Ks[j][0]);
      float s0a=0.f,s0b=0.f,s1a=0.f,s1b=0.f;
#pragma unroll
      for (int j4 = 0; j4 < 8; ++j4) {
        float4 t4 = kr[j4];
        s0a = fmaf(qv0[j4*4+0], t4.x, s0a);
        s0b = fmaf(qv0[j4*4+1], t4.y, s0b);
        s0a = fmaf(qv0[j4*4+2], t4.z, s0a);
        s0b = fmaf(qv0[j4*4+3], t4.w, s0b);
        s1a = fmaf(qv1[j4*4+0], t4.x, s1a);
        s1b = fmaf(qv1[j4*4+1], t4.y, s1b);
        s1a = fmaf(qv1[j4*4+2], t4.z, s1a);
        s1b = fmaf(qv1[j4*4+3], t4.w, s1b);
      }
      const float p0 = __expf(fminf(s0a + s0b, 30.f));
      const float p1 = __expf(fminf(s1a + s1b, 30.f));
      l0 += p0; l1 += p1;
      const float4* vr = reinterpret_cast<const float4*>(&Vs[j][0]);
#pragma unroll
      for (int j4 = 0; j4 < 8; ++j4) {
        float4 t4 = vr[j4];
        acc0[j4*4+0] = fmaf(p0, t4.x, acc0[j4*4+0]);
        acc0[j4*4+1] = fmaf(p0, t4.y, acc0[j4*4+1]);
        acc0[j4*4+2] = fmaf(p0, t4.z, acc0[j4*4+2]);
        acc0[j4*4+3] = fmaf(p0, t4.w, acc0[j4*4+3]);
        acc1[j4*4+0] = fmaf(p1, t4.x, acc1[j4*4+0]);
        acc1[j4*4+1] = fmaf(p1, t4.y, acc1[j4*4+1]);
        acc1[j4*4+2] = fmaf(p1, t4.z, acc1[j4*4+2]);
        acc1[j4*4+3] = fmaf(p1, t4.w, acc1[j4*4+3]);
      }
    }
  }
  const int pslot = ((b*4 + h)*8 + kt)*1024;
  if (a0) {
    part_lsum[pslot + q0] = l0;
    unsigned int pw[16];
#pragma unroll
    for (int i = 0; i < 16; ++i)
      pw[i] = (unsigned)f2bf(acc0[2*i]) | ((unsigned)f2bf(acc0[2*i+1]) << 16);
    uint4* pa = reinterpret_cast<uint4*>(part_acc + (size_t)(pslot + q0)*32);
#pragma unroll
    for (int i = 0; i < 4; ++i) {
      uint4 u; u.x = pw[i*4+0]; u.y = pw[i*4+1]; u.z = pw[i*4+2]; u.w = pw[i*4+3];
      pa[i] = u;
    }
  }
  if (a1) {
    part_lsum[pslot + q1] = l1;
    unsigned int pw[16];
#pragma unroll
    for (int i = 0; i < 16; ++i)
      pw[i] = (unsigned)f2bf(acc1[2*i]) | ((unsigned)f2bf(acc1[2*i+1]) << 16);
    uint4* pa = reinterpret_cast<uint4*>(part_acc + (size_t)(pslot + q1)*32);
#pragma unroll
    for (int i = 0; i < 4; ++i) {
      uint4 u; u.x = pw[i*4+0]; u.y = pw[i*4+1]; u.z = pw[i*4+2]; u.w = pw[i*4+3];
      pa[i] = u;
    }
  }
}

// ---------------- merge 8 kt partials -> normalized attention output -----------
__global__ __launch_bounds__(256) void glb_merge_kernel(
    const unsigned short* __restrict__ part_acc, const float* __restrict__ part_lsum,
    const int* __restrict__ n_seg, float* __restrict__ ao)
{
  const int qt = blockIdx.x & 15;
  const int h  = (blockIdx.x >> 4) & 3;
  const int b  = blockIdx.x >> 6;
  const int ns = n_seg[b];
  if (qt*64 >= ns) return;
  const int q  = qt*64 + ((int)threadIdx.x >> 2);
  if (q >= ns) return;
  const int dg = ((int)threadIdx.x & 3) * 8;
  const int kchunk = (ns + 7) >> 3;
  float ls = 0.f;
  float a[8];
#pragma unroll
  for (int i = 0; i < 8; ++i) a[i] = 0.f;
#pragma unroll
  for (int kt = 0; kt < 8; ++kt) {
    if (kt * kchunk < ns) {
      const int base = ((b*4 + h)*8 + kt)*1024 + q;
      ls += part_lsum[base];
      const uint4 pv = *reinterpret_cast<const uint4*>(part_acc + (size_t)base*32 + dg);
      a[0] += bf2f((unsigned short)(pv.x & 0xFFFF)); a[1] += bf2f((unsigned short)(pv.x >> 16));
      a[2] += bf2f((unsigned short)(pv.y & 0xFFFF)); a[3] += bf2f((unsigned short)(pv.y >> 16));
      a[4] += bf2f((unsigned short)(pv.z & 0xFFFF)); a[5] += bf2f((unsigned short)(pv.z >> 16));
      a[6] += bf2f((unsigned short)(pv.w & 0xFFFF)); a[7] += bf2f((unsigned short)(pv.w >> 16));
    }
  }
  const float inv = 1.0f / ls;
  float* op = ao + (size_t)(b*L_ + q)*128 + h*32 + dg;
  reinterpret_cast<float4*>(op)[0] = make_float4(a[0]*inv, a[1]*inv, a[2]*inv, a[3]*inv);
  reinterpret_cast<float4*>(op)[1] = make_float4(a[4]*inv, a[5]*inv, a[6]*inv, a[7]*inv);
}

// ---------------- LN(x+r) D=64: 4 rows per 256-thr block ----------------
__global__ __launch_bounds__(256) void ln64_kernel(
    float* __restrict__ x, const float* __restrict__ r,
    const float* __restrict__ gam, const float* __restrict__ bet)
{
  const int row = blockIdx.x*4 + ((int)threadIdx.x >> 6);
  const int d = (int)threadIdx.x & 63;
  float val = x[(size_t)row*64 + d] + r[(size_t)row*64 + d];
  float s = wave_reduce_sum(val);
  const float mean = s * (1.0f/64.0f);
  const float dv = val - mean;
  float s2 = wave_reduce_sum(dv*dv);
  x[(size_t)row*64 + d] = dv * rsqrtf(s2*(1.0f/64.0f) + 1e-5f) * gam[d] + bet[d];
}

// ---------------- LN(x+r) D=128 gated: 2 rows per 256-thr block ----------------
__global__ __launch_bounds__(256) void ln128_kernel(
    float* __restrict__ x, const float* __restrict__ r,
    const float* __restrict__ gam, const float* __restrict__ bet,
    const int* __restrict__ nseg)
{
  const int row0 = blockIdx.x*2;
  const int b = row0 >> 10;
  if ((row0 & (L_-1)) >= nseg[b]) return;
  const int sub = (int)threadIdx.x >> 7;
  const int d   = (int)threadIdx.x & 127;
  const int row = row0 + sub;
  const bool valid = (row & (L_-1)) < nseg[b];
  __shared__ float red[2][4];
  float val = 0.f;
  if (valid) val = x[(size_t)row*128 + d] + r[(size_t)row*128 + d];
  float s = wave_reduce_sum(val);
  if ((d & 63) == 0) red[sub][d >> 6] = s;
  __syncthreads();
  s = red[sub][0] + red[sub][1];
  const float mean = s * (1.0f/128.0f);
  const float dv = val - mean;
  float s2 = wave_reduce_sum(dv*dv);
  if ((d & 63) == 0) red[sub][2 + (d >> 6)] = s2;
  __syncthreads();
  s2 = red[sub][2] + red[sub][3];
  if (valid)
    x[(size_t)row*128 + d] = dv * rsqrtf(s2*(1.0f/128.0f) + 1e-5f) * gam[d] + bet[d];
}

// ---------------- segment mean pooling: 4 segs per 256-thr block ---------------
__global__ __launch_bounds__(256) void pool_kernel(
    const float* __restrict__ h, const int* __restrict__ seg_start,
    const int* __restrict__ n_seg, float* __restrict__ mean)
{
  const int gs = blockIdx.x*4 + ((int)threadIdx.x >> 6);
  const int b = gs >> 10, s = gs & (L_-1);
  const int d = (int)threadIdx.x & 63;
  if (s >= n_seg[b]) return;
  const int j0 = seg_start[b*(L_+1)+s], j1 = seg_start[b*(L_+1)+s+1];
  float acc = 0.f;
  for (int j = j0; j < j1; ++j) acc += h[(size_t)(b*L_+j)*64 + d];
  mean[(size_t)gs*64 + d] = acc / (float)(j1 - j0);
}

// ---------------- save row0 of xg (post-up-projection) for ns==1 path ----------
__global__ __launch_bounds__(128) void row0_kernel(
    const float* __restrict__ xg, float* __restrict__ semb0)
{
  semb0[blockIdx.x*128 + threadIdx.x] = xg[(size_t)blockIdx.x*L_*128 + threadIdx.x];
}

// ---------------- final pooling phase A: 16 chunks of 64 rows per batch --------
__global__ __launch_bounds__(128) void pool_final_kernel(
    const float* __restrict__ g, const int* __restrict__ n_seg,
    float* __restrict__ partial)   // [B_*16][128]
{
  const int b = blockIdx.x >> 4, c = blockIdx.x & 15;
  const int d = (int)threadIdx.x;
  const int ns = n_seg[b];
  const int i0 = c*64, i1 = min(ns, i0 + 64);
  float acc = 0.f;
  for (int i = i0; i < i1; ++i) acc += g[(size_t)(b*L_+i)*128 + d];
  partial[(size_t)blockIdx.x*128 + d] = acc;
}

// ---------------- final phase B: combine + 128x128 projection ------------------
__global__ __launch_bounds__(128) void final_kernel(
    const float* __restrict__ partial, const float* __restrict__ semb0,
    const int* __restrict__ n_seg, const float* __restrict__ fin_w,
    const float* __restrict__ fin_b, float* __restrict__ out)
{
  const int b = blockIdx.x, d = threadIdx.x;
  const int ns = n_seg[b];
  __shared__ float pl[128];
  float pooled;
  if (ns == 1) pooled = semb0[b*128 + d];
  else {
    float acc = 0.f;
#pragma unroll
    for (int c = 0; c < 16; ++c) acc += partial[(size_t)(b*16 + c)*128 + d];
    pooled = acc / (float)ns;
  }
  pl[d] = pooled;
  __syncthreads();
  float o = fin_b[d];
#pragma unroll 8
  for (int k2 = 0; k2 < 128; ++k2) o = fmaf(pl[k2], fin_w[k2*128+d], o);
  out[b*128+d] = o;
}

extern "C" void kernel_launch(void* const* d_in, const int* in_sizes, int n_in,
                              void* d_out, int out_size, void* d_ws, size_t ws_size,
                              hipStream_t stream) {
  const float* pts     = (const float*)d_in[0];
  const float* fs      = (const float*)d_in[1];
  const float* ft      = (const float*)d_in[2];
  const float* w_space = (const float*)d_in[3];
  const float* b_space = (const float*)d_in[4];
  const float* w_time  = (const float*)d_in[5];
  const float* b_time  = (const float*)d_in[6];
  const float* w_fout  = (const float*)d_in[7];
  const float* b_fout  = (const float*)d_in[8];
  const float* w_gate  = (const float*)d_in[9];
  const float* b_gate  = (const float*)d_in[10];
  const float* seg_attn_w = (const float*)d_in[11];
  const float* seg_attn_b = (const float*)d_in[12];
  const float* seg_ln_g   = (const float*)d_in[13];
  const float* seg_ln_b   = (const float*)d_in[14];
  const float* seg_ff1_w  = (const float*)d_in[15];
  const float* seg_ff1_b  = (const float*)d_in[16];
  const float* seg_ff2_w  = (const float*)d_in[17];
  const float* seg_ff2_b  = (const float*)d_in[18];
  const float* glb_attn_w = (const float*)d_in[19];
  const float* glb_attn_b = (const float*)d_in[20];
  const float* glb_ln_g   = (const float*)d_in[21];
  const float* glb_ln_b   = (const float*)d_in[22];
  const float* glb_ff1_w  = (const float*)d_in[23];
  const float* glb_ff1_b  = (const float*)d_in[24];
  const float* glb_ff2_w  = (const float*)d_in[25];
  const float* glb_ff2_b  = (const float*)d_in[26];
  const float* up_w    = (const float*)d_in[27];
  const float* up_b    = (const float*)d_in[28];
  const float* fin_w   = (const float*)d_in[29];
  const float* fin_b   = (const float*)d_in[30];

  // workspace layout (MB offsets):
  // 0-4 zx | 4-30 qkv/tmp | 30-38 aob(+pooled) | 38-46 xg | 46-47 ints
  // 47 semb0(8KB) +64KB partial(128KB) | 48-50 part_lsum | 50-84 part_acc(bf16)
  char* ws = (char*)d_ws;
  float* zx   = (float*)(ws);
  float* qkv  = (float*)(ws + ((size_t)4  << 20));
  float* tmp  = qkv;
  float* aob  = (float*)(ws + ((size_t)30 << 20));
  float* xg   = (float*)(ws + ((size_t)38 << 20));
  int* boundary  = (int*)(ws + ((size_t)46 << 20));
  int* seg_id    = boundary + M_TOT;
  int* seg_start = seg_id + M_TOT;
  int* n_seg     = seg_start + B_*(L_+1);
  float* semb0     = (float*)(ws + ((size_t)47 << 20));
  float* partial   = (float*)(ws + ((size_t)47 << 20) + 65536);
  float* part_lsum = (float*)(ws + ((size_t)48 << 20));
  unsigned short* part_acc = (unsigned short*)(ws + ((size_t)50 << 20));

  featurize_kernel<<<M_TOT/4, 256, 0, stream>>>(pts, fs, ft, w_space, b_space, w_time, b_time,
                                                w_fout, b_fout, w_gate, b_gate, zx, boundary);
  scan_kernel<<<B_, 1024, 0, stream>>>(boundary, seg_id, seg_start, n_seg);

  // ---- segment-level encoder (D=64, H=2, FF=128) ----
  for (int l = 0; l < 2; ++l) {
    const float* aw = seg_attn_w + (size_t)l*4*64*64;
    const float* ab = seg_attn_b + (size_t)l*4*64;
    gemm3_kernel<64,64,3,false,false><<<dim3(M_TOT/64,3),256,0,stream>>>(zx, aw, ab, qkv, nullptr);
    seg_attn_kernel<<<(M_TOT*2)/64, 64, 0, stream>>>(qkv, seg_id, seg_start, aob);
    gemm3_kernel<64,64,1,false,false><<<dim3(M_TOT/64,1),256,0,stream>>>(aob, aw + 3*4096, ab + 192, tmp, nullptr);
    ln64_kernel<<<M_TOT/4, 256, 0, stream>>>(zx, tmp, seg_ln_g + l*128, seg_ln_b + l*128);
    gemm3_kernel<64,128,1,true,false><<<dim3(M_TOT/64,2),256,0,stream>>>(zx, seg_ff1_w + (size_t)l*64*128, seg_ff1_b + l*128, tmp, nullptr);
    gemm3_kernel<128,64,1,false,false><<<dim3(M_TOT/64,1),256,0,stream>>>(tmp, seg_ff2_w + (size_t)l*128*64, seg_ff2_b + l*64, aob, nullptr);
    ln64_kernel<<<M_TOT/4, 256, 0, stream>>>(zx, aob, seg_ln_g + l*128 + 64, seg_ln_b + l*128 + 64);
  }

  // ---- pooling + up-projection (gated past n_seg) ----
  pool_kernel<<<M_TOT/4, 256, 0, stream>>>(zx, seg_start, n_seg, aob);
  gemm3_kernel<64,128,1,false,true><<<dim3(M_TOT/64,2),256,0,stream>>>(aob, up_w, up_b, xg, n_seg);
  row0_kernel<<<B_, 128, 0, stream>>>(xg, semb0);

  // ---- global-level encoder (D=128, H=4, FF=256), row-gated on n_seg ----
  for (int l = 0; l < 2; ++l) {
    const float* aw = glb_attn_w + (size_t)l*4*128*128;
    const float* ab = glb_attn_b + (size_t)l*4*128;
    gemm3_kernel<128,128,3,false,true><<<dim3(M_TOT/64,6),256,0,stream>>>(xg, aw, ab, qkv, n_seg);
    glb_attn_kernel<<<B_*4*2*8, 256, 0, stream>>>(qkv, n_seg, part_acc, part_lsum);
    glb_merge_kernel<<<B_*4*16, 256, 0, stream>>>(part_acc, part_lsum, n_seg, aob);
    gemm3_kernel<128,128,1,false,true><<<dim3(M_TOT/64,2),256,0,stream>>>(aob, aw + 3*16384, ab + 384, tmp, n_seg);
    ln128_kernel<<<M_TOT/2, 256, 0, stream>>>(xg, tmp, glb_ln_g + l*256, glb_ln_b + l*256, n_seg);
    gemm3_kernel<128,256,1,true,true><<<dim3(M_TOT/64,4),256,0,stream>>>(xg, glb_ff1_w + (size_t)l*128*256, glb_ff1_b + l*256, tmp, n_seg);
    gemm3_kernel<256,128,1,false,true><<<dim3(M_TOT/64,2),256,0,stream>>>(tmp, glb_ff2_w + (size_t)l*256*128, glb_ff2_b + l*128, aob, n_seg);
    ln128_kernel<<<M_TOT/2, 256, 0, stream>>>(xg, aob, glb_ln_g + l*256 + 128, glb_ln_b + l*256 + 128, n_seg);
  }

  pool_final_kernel<<<B_*16, 128, 0, stream>>>(xg, n_seg, partial);
  final_kernel<<<B_, 128, 0, stream>>>(partial, semb0, n_seg, fin_w, fin_b, (float*)d_out);
}

// Round 6
// 498.446 us; speedup vs baseline: 2.7661x; 2.7661x over previous
//
#include <hip/hip_runtime.h>
#include <math.h>

#define B_ 16
#define L_ 1024
#define M_TOT (B_*L_)   // 16384

typedef __attribute__((ext_vector_type(8))) short short8v;  // 8 bf16 (4 VGPRs)
typedef __attribute__((ext_vector_type(4))) float f32x4;

__device__ __forceinline__ float wave_reduce_sum(float v) {
#pragma unroll
  for (int o = 32; o >= 1; o >>= 1) v += __shfl_xor(v, o, 64);
  return v;
}

__device__ __forceinline__ unsigned short f2bf(float f) {
  union { float f; unsigned u; } v; v.f = f;
  unsigned r = v.u + 0x7FFFu + ((v.u >> 16) & 1u);
  return (unsigned short)(r >> 16);
}

// ---------------- weight pack: fp32 [nmat][K][N] -> MFMA B-frag bf16 layout ----
// dst idx = (((m*(K/32) + kt)*(N/16) + nt)*64 + l)*8 + j
// value   = W_m[kt*32 + (l>>4)*8 + j][nt*16 + (l&15)]
__global__ __launch_bounds__(256) void pack_w_kernel(
    const float* __restrict__ src, unsigned short* __restrict__ dst,
    int K, int N, int total)
{
  const int idx = blockIdx.x*256 + (int)threadIdx.x;
  if (idx >= total) return;
  const int l = idx & 63;
  int f = idx >> 6;
  const int ntn = N >> 4;
  const int nt = f % ntn; f /= ntn;
  const int ktn = K >> 5;
  const int kt = f % ktn;
  const int m  = f / ktn;
  const float* s = src + (size_t)m*K*N + (size_t)(kt*32 + ((l>>4)<<3))*N + nt*16 + (l&15);
  unsigned pw[4];
#pragma unroll
  for (int jj = 0; jj < 4; ++jj)
    pw[jj] = (unsigned)f2bf(s[(size_t)(2*jj)*N]) | ((unsigned)f2bf(s[(size_t)(2*jj+1)*N]) << 16);
  uint4 u; u.x = pw[0]; u.y = pw[1]; u.z = pw[2]; u.w = pw[3];
  *reinterpret_cast<uint4*>(dst + (size_t)idx*8) = u;
}

// ---------------- MFMA GEMM: C = act(A[M,K] @ W[K,PN per part] + bias) --------
// block 256 thr = 4 waves; wave w: rows [row0+w*16, +16), cols = 64-col strip ct.
// A: bf16 row-major [M][K]. Wpk: packed (above). grid(M/64, NPARTS*PN/64).
template<int K, int PN, int NPARTS, bool RELU, bool GATED, bool WF32, bool WBF>
__global__ __launch_bounds__(256) void mgemm_kernel(
    const unsigned short* __restrict__ Abf,
    const unsigned short* __restrict__ Wpk,
    const float* __restrict__ bias,
    float* __restrict__ C, unsigned short* __restrict__ Cbf,
    const int* __restrict__ nseg)
{
  constexpr int NOUT = NPARTS*PN;
  constexpr int KT = K/32;
  constexpr int NTP = PN/16;
  constexpr int CPP = PN/64;
  const int row0 = blockIdx.x * 64;
  if (GATED) { const int b = row0 >> 10; if ((row0 & (L_-1)) >= nseg[b]) return; }
  const int ct = blockIdx.y;
  const int part = ct / CPP;
  const int nt0  = (ct % CPP) * 4;
  const int wv = (int)threadIdx.x >> 6;
  const int ln = (int)threadIdx.x & 63;
  const int rbase = row0 + wv*16;
  // A frag: lane l -> row rbase+(l&15), k = kt*32 + (l>>4)*8 + j (contiguous 8)
  const unsigned short* aptr = Abf + (size_t)(rbase + (ln & 15))*K + ((ln >> 4) << 3);
  const unsigned short* bptr = Wpk + ((size_t)part*KT*NTP + nt0)*512 + (size_t)ln*8;
  f32x4 acc0 = {0.f,0.f,0.f,0.f}, acc1 = {0.f,0.f,0.f,0.f};
  f32x4 acc2 = {0.f,0.f,0.f,0.f}, acc3 = {0.f,0.f,0.f,0.f};
#pragma unroll
  for (int kt = 0; kt < KT; ++kt) {
    short8v a = *reinterpret_cast<const short8v*>(aptr + kt*32);
    const unsigned short* bk = bptr + (size_t)kt*NTP*512;
    short8v b0 = *reinterpret_cast<const short8v*>(bk);
    short8v b1 = *reinterpret_cast<const short8v*>(bk + 512);
    short8v b2 = *reinterpret_cast<const short8v*>(bk + 1024);
    short8v b3 = *reinterpret_cast<const short8v*>(bk + 1536);
    acc0 = __builtin_amdgcn_mfma_f32_16x16x32_bf16(a, b0, acc0, 0, 0, 0);
    acc1 = __builtin_amdgcn_mfma_f32_16x16x32_bf16(a, b1, acc1, 0, 0, 0);
    acc2 = __builtin_amdgcn_mfma_f32_16x16x32_bf16(a, b2, acc2, 0, 0, 0);
    acc3 = __builtin_amdgcn_mfma_f32_16x16x32_bf16(a, b3, acc3, 0, 0, 0);
  }
  // C/D: row = rbase + (l>>4)*4 + r, col = colb + i*16  [m89-verified mapping]
  const int colb = part*PN + nt0*16 + (ln & 15);
  const int rowe = rbase + ((ln >> 4) << 2);
  f32x4 av[4] = {acc0, acc1, acc2, acc3};
#pragma unroll
  for (int i = 0; i < 4; ++i) {
    const int col = colb + i*16;
    const float bs = bias[col];
#pragma unroll
    for (int r = 0; r < 4; ++r) {
      float v = av[i][r] + bs;
      if (RELU) v = fmaxf(v, 0.f);
      if (WF32) C[(size_t)(rowe + r)*NOUT + col] = v;
      if (WBF)  Cbf[(size_t)(rowe + r)*NOUT + col] = f2bf(v);
    }
  }
}

// ---------------- featurize: 4 points per 256-thr block (dual-write) ----------
__global__ __launch_bounds__(256) void featurize_kernel(
    const float* __restrict__ pts, const float* __restrict__ fs, const float* __restrict__ ft,
    const float* __restrict__ w_space, const float* __restrict__ b_space,
    const float* __restrict__ w_time, const float* __restrict__ b_time,
    const float* __restrict__ w_fout, const float* __restrict__ b_fout,
    const float* __restrict__ w_gate, const float* __restrict__ b_gate,
    float* __restrict__ z, unsigned short* __restrict__ zbf, int* __restrict__ boundary)
{
  const int sub = threadIdx.x >> 6;
  const int d   = threadIdx.x & 63;
  const int p   = blockIdx.x * 4 + sub;
  const float TWO_PI = 6.283185307179586f;
  __shared__ float feat[4][32];
  __shared__ float tfeat[4][16];
  __shared__ float g96[4][96];
  const float x = pts[p*3+0], y = pts[p*3+1], t = pts[p*3+2];
  if (d < 16) {
    float sp = (x*fs[d] + y*fs[16+d]) * TWO_PI;
    feat[sub][d]    = sinf(sp);
    feat[sub][16+d] = cosf(sp);
  } else if (d < 24) {
    int r = d - 16;
    float tp = t * ft[r] * TWO_PI;
    tfeat[sub][r]   = sinf(tp);
    tfeat[sub][8+r] = cosf(tp);
  }
  __syncthreads();
  float sf = b_space[d];
#pragma unroll
  for (int k2 = 0; k2 < 32; ++k2) sf = fmaf(feat[sub][k2], w_space[k2*64+d], sf);
  g96[sub][d] = sf;
  if (d < 32) {
    float tf = b_time[d];
#pragma unroll
    for (int k2 = 0; k2 < 16; ++k2) tf = fmaf(tfeat[sub][k2], w_time[k2*32+d], tf);
    g96[sub][64+d] = tf;
  }
  __syncthreads();
  float zv = b_fout[d];
#pragma unroll
  for (int k2 = 0; k2 < 96; ++k2) zv = fmaf(g96[sub][k2], w_fout[k2*64+d], zv);
  z[(size_t)p*64+d] = zv;
  zbf[(size_t)p*64+d] = f2bf(zv);
  float gv = wave_reduce_sum(zv * w_gate[d]);
  if (d == 0) {
    float logit = gv + b_gate[0];
    float gate = 1.0f / (1.0f + expf(-logit));
    int bnd = (gate > 0.5f) ? 1 : 0;
    if ((p & (L_-1)) == 0) bnd = 1;
    boundary[p] = bnd;
  }
}

// ---------------- scan: seg_id, seg_start, n_seg ----------------
__global__ __launch_bounds__(1024) void scan_kernel(const int* __restrict__ boundary,
    int* __restrict__ seg_id, int* __restrict__ seg_start, int* __restrict__ n_seg)
{
  __shared__ int sc[1024];
  const int b = blockIdx.x, l = threadIdx.x;
  const int v = boundary[b*L_ + l];
  sc[l] = v;
  __syncthreads();
  for (int off = 1; off < 1024; off <<= 1) {
    int add = (l >= off) ? sc[l - off] : 0;
    __syncthreads();
    sc[l] += add;
    __syncthreads();
  }
  const int sid = sc[l] - 1;
  seg_id[b*L_ + l] = sid;
  if (v) seg_start[b*(L_+1) + sid] = l;
  if (l == L_-1) {
    n_seg[b] = sid + 1;
    seg_start[b*(L_+1) + sid + 1] = L_;
  }
}

// ---------------- segment attention (block-diag exact; bf16 out) --------------
// qkv packed [row][3][64]; out: bf16 [row][64]
__global__ __launch_bounds__(64) void seg_attn_kernel(
    const float* __restrict__ qkv,
    const int* __restrict__ seg_id, const int* __restrict__ seg_start,
    unsigned short* __restrict__ aobf)
{
  const int idx = blockIdx.x * 64 + threadIdx.x;  // ((b*L + pt)*2 + h)
  const int h  = idx & 1;
  const int pt = (idx >> 1) & (L_-1);
  const int b  = idx >> 11;
  const float scale = 0.17677669529663687f;
  float qv[32];
  {
    const float4* qp = reinterpret_cast<const float4*>(qkv + (size_t)(b*L_+pt)*192 + h*32);
#pragma unroll
    for (int j4 = 0; j4 < 8; ++j4) {
      float4 t4 = qp[j4];
      qv[j4*4+0]=t4.x*scale; qv[j4*4+1]=t4.y*scale; qv[j4*4+2]=t4.z*scale; qv[j4*4+3]=t4.w*scale;
    }
  }
  const int s  = seg_id[b*L_ + pt];
  const int j0 = seg_start[b*(L_+1) + s];
  const int j1 = seg_start[b*(L_+1) + s + 1];
  float lsum = 0.f;
  float acc[32];
#pragma unroll
  for (int d = 0; d < 32; ++d) acc[d] = 0.f;
  for (int j = j0; j < j1; ++j) {
    const float* base = qkv + (size_t)(b*L_ + j)*192 + h*32;
    const float4* kp = reinterpret_cast<const float4*>(base + 64);
    float dot = 0.f;
#pragma unroll
    for (int j4 = 0; j4 < 8; ++j4) {
      float4 t4 = kp[j4];
      dot = fmaf(qv[j4*4+0], t4.x, dot);
      dot = fmaf(qv[j4*4+1], t4.y, dot);
      dot = fmaf(qv[j4*4+2], t4.z, dot);
      dot = fmaf(qv[j4*4+3], t4.w, dot);
    }
    const float p = __expf(fminf(dot, 30.f));
    lsum += p;
    const float4* vp = reinterpret_cast<const float4*>(base + 128);
#pragma unroll
    for (int j4 = 0; j4 < 8; ++j4) {
      float4 t4 = vp[j4];
      acc[j4*4+0] = fmaf(p, t4.x, acc[j4*4+0]);
      acc[j4*4+1] = fmaf(p, t4.y, acc[j4*4+1]);
      acc[j4*4+2] = fmaf(p, t4.z, acc[j4*4+2]);
      acc[j4*4+3] = fmaf(p, t4.w, acc[j4*4+3]);
    }
  }
  const float inv = 1.0f / lsum;
  unsigned* op = reinterpret_cast<unsigned*>(aobf + (size_t)(b*L_+pt)*64 + h*32);
#pragma unroll
  for (int d2 = 0; d2 < 16; ++d2)
    op[d2] = (unsigned)f2bf(acc[2*d2]*inv) | ((unsigned)f2bf(acc[2*d2+1]*inv) << 16);
}

// ---------------- global attention: 256 thr, NQ=2, kt=8 key-split --------------
__global__ __launch_bounds__(256) void glb_attn_kernel(
    const float* __restrict__ xqkv, const int* __restrict__ n_seg,
    unsigned short* __restrict__ part_acc, float* __restrict__ part_lsum)
{
  const int kt = blockIdx.x & 7;
  const int qt = (blockIdx.x >> 3) & 1;
  const int h  = (blockIdx.x >> 4) & 3;
  const int b  = blockIdx.x >> 6;
  const int ns = n_seg[b];
  if (qt*512 >= ns) return;
  const int kchunk = (ns + 7) >> 3;
  const int kbeg = kt * kchunk;
  const int kend = min(ns, kbeg + kchunk);
  if (kbeg >= kend) return;

  const int tid = (int)threadIdx.x;
  const int q0 = qt*512 + tid;
  const int q1 = q0 + 256;
  const bool a0 = q0 < ns, a1 = q1 < ns;
  const float scale = 0.17677669529663687f;

  __shared__ float Ks[64][36];
  __shared__ float Vs[64][36];

  float qv0[32], qv1[32];
#pragma unroll
  for (int d = 0; d < 32; ++d) { qv0[d] = 0.f; qv1[d] = 0.f; }
  if (a0) {
    const float4* qp = reinterpret_cast<const float4*>(xqkv + (size_t)(b*L_+q0)*384 + h*32);
#pragma unroll
    for (int j4 = 0; j4 < 8; ++j4) {
      float4 t4 = qp[j4];
      qv0[j4*4+0]=t4.x*scale; qv0[j4*4+1]=t4.y*scale; qv0[j4*4+2]=t4.z*scale; qv0[j4*4+3]=t4.w*scale;
    }
  }
  if (a1) {
    const float4* qp = reinterpret_cast<const float4*>(xqkv + (size_t)(b*L_+q1)*384 + h*32);
#pragma unroll
    for (int j4 = 0; j4 < 8; ++j4) {
      float4 t4 = qp[j4];
      qv1[j4*4+0]=t4.x*scale; qv1[j4*4+1]=t4.y*scale; qv1[j4*4+2]=t4.z*scale; qv1[j4*4+3]=t4.w*scale;
    }
  }

  float l0 = 0.f, l1 = 0.f;
  float acc0[32], acc1[32];
#pragma unroll
  for (int d = 0; d < 32; ++d) { acc0[d] = 0.f; acc1[d] = 0.f; }

  for (int j0 = kbeg; j0 < kend; j0 += 64) {
    const int nj = min(64, kend - j0);
    __syncthreads();
    {
      const int jr = tid >> 2;
      const int c  = (tid & 3) * 8;
      if (jr < nj) {
        const float* base = xqkv + (size_t)(b*L_ + j0 + jr)*384 + h*32 + c;
        *reinterpret_cast<float4*>(&Ks[jr][c])   = *reinterpret_cast<const float4*>(base + 128);
        *reinterpret_cast<float4*>(&Ks[jr][c+4]) = *reinterpret_cast<const float4*>(base + 132);
        *reinterpret_cast<float4*>(&Vs[jr][c])   = *reinterpret_cast<const float4*>(base + 256);
        *reinterpret_cast<float4*>(&Vs[jr][c+4]) = *reinterpret_cast<const float4*>(base + 260);
      }
    }
    __syncthreads();
#pragma unroll 2
    for (int j = 0; j < nj; ++j) {
      const float4* kr = reinterpret_cast<const float4*>(&Ks[j][0]);
      float s0a=0.f,s0b=0.f,s1a=0.f,s1b=0.f;
#pragma unroll
      for (int j4 = 0; j4 < 8; ++j4) {
        float4 t4 = kr[j4];
        s0a = fmaf(qv0[j4*4+0], t4.x, s0a);
        s0b = fmaf(qv0[j4*4+1], t4.y, s0b);
        s0a = fmaf(qv0[j4*4+2], t4.z, s0a);
        s0b = fmaf(qv0[j4*4+3], t4.w, s0b);
        s1a = fmaf(qv1[j4*4+0], t4.x, s1a);
        s1b = fmaf(qv1[j4*4+1], t4.y, s1b);
        s1a = fmaf(qv1[j4*4+2], t4.z, s1a);
        s1b = fmaf(qv1[j4*4+3], t4.w, s1b);
      }
      const float p0 = __expf(fminf(s0a + s0b, 30.f));
      const float p1 = __expf(fminf(s1a + s1b, 30.f));
      l0 += p0; l1 += p1;
      const float4* vr = reinterpret_cast<const float4*>(&Vs[j][0]);
#pragma unroll
      for (int j4 = 0; j4 < 8; ++j4) {
        float4 t4 = vr[j4];
        acc0[j4*4+0] = fmaf(p0, t4.x, acc0[j4*4+0]);
        acc0[j4*4+1] = fmaf(p0, t4.y, acc0[j4*4+1]);
        acc0[j4*4+2] = fmaf(p0, t4.z, acc0[j4*4+2]);
        acc0[j4*4+3] = fmaf(p0, t4.w, acc0[j4*4+3]);
        acc1[j4*4+0] = fmaf(p1, t4.x, acc1[j4*4+0]);
        acc1[j4*4+1] = fmaf(p1, t4.y, acc1[j4*4+1]);
        acc1[j4*4+2] = fmaf(p1, t4.z, acc1[j4*4+2]);
        acc1[j4*4+3] = fmaf(p1, t4.w, acc1[j4*4+3]);
      }
    }
  }
  const int pslot = ((b*4 + h)*8 + kt)*1024;
  if (a0) {
    part_lsum[pslot + q0] = l0;
    unsigned int pw[16];
#pragma unroll
    for (int i = 0; i < 16; ++i)
      pw[i] = (unsigned)f2bf(acc0[2*i]) | ((unsigned)f2bf(acc0[2*i+1]) << 16);
    uint4* pa = reinterpret_cast<uint4*>(part_acc + (size_t)(pslot + q0)*32);
#pragma unroll
    for (int i = 0; i < 4; ++i) {
      uint4 u; u.x = pw[i*4+0]; u.y = pw[i*4+1]; u.z = pw[i*4+2]; u.w = pw[i*4+3];
      pa[i] = u;
    }
  }
  if (a1) {
    part_lsum[pslot + q1] = l1;
    unsigned int pw[16];
#pragma unroll
    for (int i = 0; i < 16; ++i)
      pw[i] = (unsigned)f2bf(acc1[2*i]) | ((unsigned)f2bf(acc1[2*i+1]) << 16);
    uint4* pa = reinterpret_cast<uint4*>(part_acc + (size_t)(pslot + q1)*32);
#pragma unroll
    for (int i = 0; i < 4; ++i) {
      uint4 u; u.x = pw[i*4+0]; u.y = pw[i*4+1]; u.z = pw[i*4+2]; u.w = pw[i*4+3];
      pa[i] = u;
    }
  }
}

__device__ __forceinline__ float bf2f(unsigned short s) {
  union { unsigned u; float f; } v; v.u = ((unsigned)s) << 16; return v.f;
}

// ---------------- merge 8 kt partials -> bf16 attention output [row][128] -----
__global__ __launch_bounds__(256) void glb_merge_kernel(
    const unsigned short* __restrict__ part_acc, const float* __restrict__ part_lsum,
    const int* __restrict__ n_seg, unsigned short* __restrict__ aobf)
{
  const int qt = blockIdx.x & 15;
  const int h  = (blockIdx.x >> 4) & 3;
  const int b  = blockIdx.x >> 6;
  const int ns = n_seg[b];
  if (qt*64 >= ns) return;
  const int q  = qt*64 + ((int)threadIdx.x >> 2);
  if (q >= ns) return;
  const int dg = ((int)threadIdx.x & 3) * 8;
  const int kchunk = (ns + 7) >> 3;
  float ls = 0.f;
  float a[8];
#pragma unroll
  for (int i = 0; i < 8; ++i) a[i] = 0.f;
#pragma unroll
  for (int kt = 0; kt < 8; ++kt) {
    if (kt * kchunk < ns) {
      const int base = ((b*4 + h)*8 + kt)*1024 + q;
      ls += part_lsum[base];
      const uint4 pv = *reinterpret_cast<const uint4*>(part_acc + (size_t)base*32 + dg);
      a[0] += bf2f((unsigned short)(pv.x & 0xFFFF)); a[1] += bf2f((unsigned short)(pv.x >> 16));
      a[2] += bf2f((unsigned short)(pv.y & 0xFFFF)); a[3] += bf2f((unsigned short)(pv.y >> 16));
      a[4] += bf2f((unsigned short)(pv.z & 0xFFFF)); a[5] += bf2f((unsigned short)(pv.z >> 16));
      a[6] += bf2f((unsigned short)(pv.w & 0xFFFF)); a[7] += bf2f((unsigned short)(pv.w >> 16));
    }
  }
  const float inv = 1.0f / ls;
  unsigned* op = reinterpret_cast<unsigned*>(aobf + (size_t)(b*L_ + q)*128 + h*32 + dg);
#pragma unroll
  for (int i = 0; i < 4; ++i)
    op[i] = (unsigned)f2bf(a[2*i]*inv) | ((unsigned)f2bf(a[2*i+1]*inv) << 16);
}

// ---------------- LN(x+r) D=64: dual-write fp32 + bf16 ----------------
__global__ __launch_bounds__(256) void ln64_kernel(
    float* __restrict__ x, const float* __restrict__ r,
    const float* __restrict__ gam, const float* __restrict__ bet,
    unsigned short* __restrict__ xbf)
{
  const int row = blockIdx.x*4 + ((int)threadIdx.x >> 6);
  const int d = (int)threadIdx.x & 63;
  float val = x[(size_t)row*64 + d] + r[(size_t)row*64 + d];
  float s = wave_reduce_sum(val);
  const float mean = s * (1.0f/64.0f);
  const float dv = val - mean;
  float s2 = wave_reduce_sum(dv*dv);
  const float out = dv * rsqrtf(s2*(1.0f/64.0f) + 1e-5f) * gam[d] + bet[d];
  x[(size_t)row*64 + d] = out;
  xbf[(size_t)row*64 + d] = f2bf(out);
}

// ---------------- LN(x+r) D=128 gated: dual-write ----------------
__global__ __launch_bounds__(256) void ln128_kernel(
    float* __restrict__ x, const float* __restrict__ r,
    const float* __restrict__ gam, const float* __restrict__ bet,
    const int* __restrict__ nseg, unsigned short* __restrict__ xbf)
{
  const int row0 = blockIdx.x*2;
  const int b = row0 >> 10;
  if ((row0 & (L_-1)) >= nseg[b]) return;
  const int sub = (int)threadIdx.x >> 7;
  const int d   = (int)threadIdx.x & 127;
  const int row = row0 + sub;
  const bool valid = (row & (L_-1)) < nseg[b];
  __shared__ float red[2][4];
  float val = 0.f;
  if (valid) val = x[(size_t)row*128 + d] + r[(size_t)row*128 + d];
  float s = wave_reduce_sum(val);
  if ((d & 63) == 0) red[sub][d >> 6] = s;
  __syncthreads();
  s = red[sub][0] + red[sub][1];
  const float mean = s * (1.0f/128.0f);
  const float dv = val - mean;
  float s2 = wave_reduce_sum(dv*dv);
  if ((d & 63) == 0) red[sub][2 + (d >> 6)] = s2;
  __syncthreads();
  s2 = red[sub][2] + red[sub][3];
  if (valid) {
    const float out = dv * rsqrtf(s2*(1.0f/128.0f) + 1e-5f) * gam[d] + bet[d];
    x[(size_t)row*128 + d] = out;
    xbf[(size_t)row*128 + d] = f2bf(out);
  }
}

// ---------------- segment mean pooling -> bf16 [row][64] ----------------
__global__ __launch_bounds__(256) void pool_kernel(
    const float* __restrict__ h, const int* __restrict__ seg_start,
    const int* __restrict__ n_seg, unsigned short* __restrict__ meanbf)
{
  const int gs = blockIdx.x*4 + ((int)threadIdx.x >> 6);
  const int b = gs >> 10, s = gs & (L_-1);
  const int d = (int)threadIdx.x & 63;
  if (s >= n_seg[b]) return;
  const int j0 = seg_start[b*(L_+1)+s], j1 = seg_start[b*(L_+1)+s+1];
  float acc = 0.f;
  for (int j = j0; j < j1; ++j) acc += h[(size_t)(b*L_+j)*64 + d];
  meanbf[(size_t)gs*64 + d] = f2bf(acc / (float)(j1 - j0));
}

// ---------------- save row0 of xg for ns==1 path ----------------
__global__ __launch_bounds__(128) void row0_kernel(
    const float* __restrict__ xg, float* __restrict__ semb0)
{
  semb0[blockIdx.x*128 + threadIdx.x] = xg[(size_t)blockIdx.x*L_*128 + threadIdx.x];
}

// ---------------- final pooling phase A ----------------
__global__ __launch_bounds__(128) void pool_final_kernel(
    const float* __restrict__ g, const int* __restrict__ n_seg,
    float* __restrict__ partial)
{
  const int b = blockIdx.x >> 4, c = blockIdx.x & 15;
  const int d = (int)threadIdx.x;
  const int ns = n_seg[b];
  const int i0 = c*64, i1 = min(ns, i0 + 64);
  float acc = 0.f;
  for (int i = i0; i < i1; ++i) acc += g[(size_t)(b*L_+i)*128 + d];
  partial[(size_t)blockIdx.x*128 + d] = acc;
}

// ---------------- final phase B ----------------
__global__ __launch_bounds__(128) void final_kernel(
    const float* __restrict__ partial, const float* __restrict__ semb0,
    const int* __restrict__ n_seg, const float* __restrict__ fin_w,
    const float* __restrict__ fin_b, float* __restrict__ out)
{
  const int b = blockIdx.x, d = threadIdx.x;
  const int ns = n_seg[b];
  __shared__ float pl[128];
  float pooled;
  if (ns == 1) pooled = semb0[b*128 + d];
  else {
    float acc = 0.f;
#pragma unroll
    for (int c = 0; c < 16; ++c) acc += partial[(size_t)(b*16 + c)*128 + d];
    pooled = acc / (float)ns;
  }
  pl[d] = pooled;
  __syncthreads();
  float o = fin_b[d];
#pragma unroll 8
  for (int k2 = 0; k2 < 128; ++k2) o = fmaf(pl[k2], fin_w[k2*128+d], o);
  out[b*128+d] = o;
}

extern "C" void kernel_launch(void* const* d_in, const int* in_sizes, int n_in,
                              void* d_out, int out_size, void* d_ws, size_t ws_size,
                              hipStream_t stream) {
  const float* pts     = (const float*)d_in[0];
  const float* fs      = (const float*)d_in[1];
  const float* ft      = (const float*)d_in[2];
  const float* w_space = (const float*)d_in[3];
  const float* b_space = (const float*)d_in[4];
  const float* w_time  = (const float*)d_in[5];
  const float* b_time  = (const float*)d_in[6];
  const float* w_fout  = (const float*)d_in[7];
  const float* b_fout  = (const float*)d_in[8];
  const float* w_gate  = (const float*)d_in[9];
  const float* b_gate  = (const float*)d_in[10];
  const float* seg_attn_w = (const float*)d_in[11];
  const float* seg_attn_b = (const float*)d_in[12];
  const float* seg_ln_g   = (const float*)d_in[13];
  const float* seg_ln_b   = (const float*)d_in[14];
  const float* seg_ff1_w  = (const float*)d_in[15];
  const float* seg_ff1_b  = (const float*)d_in[16];
  const float* seg_ff2_w  = (const float*)d_in[17];
  const float* seg_ff2_b  = (const float*)d_in[18];
  const float* glb_attn_w = (const float*)d_in[19];
  const float* glb_attn_b = (const float*)d_in[20];
  const float* glb_ln_g   = (const float*)d_in[21];
  const float* glb_ln_b   = (const float*)d_in[22];
  const float* glb_ff1_w  = (const float*)d_in[23];
  const float* glb_ff1_b  = (const float*)d_in[24];
  const float* glb_ff2_w  = (const float*)d_in[25];
  const float* glb_ff2_b  = (const float*)d_in[26];
  const float* up_w    = (const float*)d_in[27];
  const float* up_b    = (const float*)d_in[28];
  const float* fin_w   = (const float*)d_in[29];
  const float* fin_b   = (const float*)d_in[30];

  // workspace layout (MB offsets):
  // 0-4  : zx f32 (seg phase)   | xg_bf [16384][128] bf16 (glb phase, alias)
  // 4-30 : qkv f32 / tmp f32 (alias, disjoint lifetimes)
  // 30-38: aob f32 (FF2 residual out)
  // 38-46: xg f32               | first 2MB also zx_bf (seg phase alias, dead before up)
  // 46-47: ints | 47: semb0+partial | 48-50: part_lsum
  // 50-58: tmp_bf (aliases part_acc head; lifetimes disjoint) | 50-84: part_acc
  // 84-88: abf (attn/pool bf16 outs) | 88-89: packed weights
  char* ws = (char*)d_ws;
  float* zx   = (float*)(ws);
  unsigned short* xg_bf = (unsigned short*)(ws);              // glb-phase alias of zx
  float* qkv  = (float*)(ws + ((size_t)4  << 20));
  float* tmp  = qkv;
  float* aob  = (float*)(ws + ((size_t)30 << 20));
  float* xg   = (float*)(ws + ((size_t)38 << 20));
  unsigned short* zx_bf = (unsigned short*)(ws + ((size_t)38 << 20));  // seg-phase alias of xg head
  int* boundary  = (int*)(ws + ((size_t)46 << 20));
  int* seg_id    = boundary + M_TOT;
  int* seg_start = seg_id + M_TOT;
  int* n_seg     = seg_start + B_*(L_+1);
  float* semb0     = (float*)(ws + ((size_t)47 << 20));
  float* partial   = (float*)(ws + ((size_t)47 << 20) + 65536);
  float* part_lsum = (float*)(ws + ((size_t)48 << 20));
  unsigned short* tmp_bf   = (unsigned short*)(ws + ((size_t)50 << 20));
  unsigned short* part_acc = (unsigned short*)(ws + ((size_t)50 << 20));
  unsigned short* abf      = (unsigned short*)(ws + ((size_t)84 << 20));
  unsigned short* wpk      = (unsigned short*)(ws + ((size_t)88 << 20));

  // packed-weight offsets (shorts)
  unsigned short* wpk_segA = wpk;                 // 8 x 4096
  unsigned short* wpk_segF1 = wpk + 32768;        // 2 x 8192
  unsigned short* wpk_segF2 = wpk + 49152;        // 2 x 8192
  unsigned short* wpk_glbA = wpk + 65536;         // 8 x 16384
  unsigned short* wpk_glbF1 = wpk + 196608;       // 2 x 32768
  unsigned short* wpk_glbF2 = wpk + 262144;       // 2 x 32768
  unsigned short* wpk_up   = wpk + 327680;        // 8192

  // ---- pack all weights to MFMA fragment layout (reads only d_in) ----
  pack_w_kernel<<<(4096*2+255)/256, 256, 0, stream>>>(seg_attn_w, wpk_segA, 64, 64, 8*2*4*64);
  pack_w_kernel<<<(2048+255)/256, 256, 0, stream>>>(seg_ff1_w, wpk_segF1, 64, 128, 2*2*8*64);
  pack_w_kernel<<<(2048+255)/256, 256, 0, stream>>>(seg_ff2_w, wpk_segF2, 128, 64, 2*4*4*64);
  pack_w_kernel<<<(16384+255)/256, 256, 0, stream>>>(glb_attn_w, wpk_glbA, 128, 128, 8*4*8*64);
  pack_w_kernel<<<(8192+255)/256, 256, 0, stream>>>(glb_ff1_w, wpk_glbF1, 128, 256, 2*4*16*64);
  pack_w_kernel<<<(8192+255)/256, 256, 0, stream>>>(glb_ff2_w, wpk_glbF2, 256, 128, 2*8*8*64);
  pack_w_kernel<<<(1024+255)/256, 256, 0, stream>>>(up_w, wpk_up, 64, 128, 1*2*8*64);

  featurize_kernel<<<M_TOT/4, 256, 0, stream>>>(pts, fs, ft, w_space, b_space, w_time, b_time,
                                                w_fout, b_fout, w_gate, b_gate, zx, zx_bf, boundary);
  scan_kernel<<<B_, 1024, 0, stream>>>(boundary, seg_id, seg_start, n_seg);

  // ---- segment-level encoder (D=64, H=2, FF=128) ----
  for (int l = 0; l < 2; ++l) {
    const float* ab = seg_attn_b + (size_t)l*4*64;
    mgemm_kernel<64,64,3,false,false,true,false><<<dim3(256,3),256,0,stream>>>(
        zx_bf, wpk_segA + (size_t)l*4*4096, ab, qkv, nullptr, nullptr);
    seg_attn_kernel<<<(M_TOT*2)/64, 64, 0, stream>>>(qkv, seg_id, seg_start, abf);
    mgemm_kernel<64,64,1,false,false,true,false><<<dim3(256,1),256,0,stream>>>(
        abf, wpk_segA + (size_t)(l*4+3)*4096, ab + 192, tmp, nullptr, nullptr);
    ln64_kernel<<<M_TOT/4, 256, 0, stream>>>(zx, tmp, seg_ln_g + l*128, seg_ln_b + l*128, zx_bf);
    mgemm_kernel<64,128,1,true,false,false,true><<<dim3(256,2),256,0,stream>>>(
        zx_bf, wpk_segF1 + (size_t)l*8192, seg_ff1_b + l*128, nullptr, tmp_bf, nullptr);
    mgemm_kernel<128,64,1,false,false,true,false><<<dim3(256,1),256,0,stream>>>(
        tmp_bf, wpk_segF2 + (size_t)l*8192, seg_ff2_b + l*64, aob, nullptr, nullptr);
    ln64_kernel<<<M_TOT/4, 256, 0, stream>>>(zx, aob, seg_ln_g + l*128 + 64, seg_ln_b + l*128 + 64, zx_bf);
  }

  // ---- pooling + up-projection (gated) ----
  pool_kernel<<<M_TOT/4, 256, 0, stream>>>(zx, seg_start, n_seg, abf);
  mgemm_kernel<64,128,1,false,true,true,true><<<dim3(256,2),256,0,stream>>>(
      abf, wpk_up, up_b, xg, xg_bf, n_seg);
  row0_kernel<<<B_, 128, 0, stream>>>(xg, semb0);

  // ---- global-level encoder (D=128, H=4, FF=256), row-gated ----
  for (int l = 0; l < 2; ++l) {
    const float* ab = glb_attn_b + (size_t)l*4*128;
    mgemm_kernel<128,128,3,false,true,true,false><<<dim3(256,6),256,0,stream>>>(
        xg_bf, wpk_glbA + (size_t)l*4*16384, ab, qkv, nullptr, n_seg);
    glb_attn_kernel<<<B_*4*2*8, 256, 0, stream>>>(qkv, n_seg, part_acc, part_lsum);
    glb_merge_kernel<<<B_*4*16, 256, 0, stream>>>(part_acc, part_lsum, n_seg, abf);
    mgemm_kernel<128,128,1,false,true,true,false><<<dim3(256,2),256,0,stream>>>(
        abf, wpk_glbA + (size_t)(l*4+3)*16384, ab + 384, tmp, nullptr, n_seg);
    ln128_kernel<<<M_TOT/2, 256, 0, stream>>>(xg, tmp, glb_ln_g + l*256, glb_ln_b + l*256, n_seg, xg_bf);
    mgemm_kernel<128,256,1,true,true,false,true><<<dim3(256,4),256,0,stream>>>(
        xg_bf, wpk_glbF1 + (size_t)l*32768, glb_ff1_b + l*256, nullptr, tmp_bf, n_seg);
    mgemm_kernel<256,128,1,false,true,true,false><<<dim3(256,2),256,0,stream>>>(
        tmp_bf, wpk_glbF2 + (size_t)l*32768, glb_ff2_b + l*128, aob, nullptr, n_seg);
    ln128_kernel<<<M_TOT/2, 256, 0, stream>>>(xg, aob, glb_ln_g + l*256 + 128, glb_ln_b + l*256 + 128, n_seg, xg_bf);
  }

  pool_final_kernel<<<B_*16, 128, 0, stream>>>(xg, n_seg, partial);
  final_kernel<<<B_, 128, 0, stream>>>(partial, semb0, n_seg, fin_w, fin_b, (float*)d_out);
}

// Round 7
// 319.106 us; speedup vs baseline: 4.3207x; 1.5620x over previous
//
#include <hip/hip_runtime.h>
#include <math.h>

#define B_ 16
#define L_ 1024
#define M_TOT (B_*L_)   // 16384

typedef __attribute__((ext_vector_type(8))) short short8v;  // 8 bf16 (4 VGPRs)
typedef __attribute__((ext_vector_type(4))) float f32x4;

__device__ __forceinline__ float wave_reduce_sum(float v) {
#pragma unroll
  for (int o = 32; o >= 1; o >>= 1) v += __shfl_xor(v, o, 64);
  return v;
}

__device__ __forceinline__ unsigned short f2bf(float f) {
  union { float f; unsigned u; } v; v.f = f;
  unsigned r = v.u + 0x7FFFu + ((v.u >> 16) & 1u);
  return (unsigned short)(r >> 16);
}

// ---------------- fused weight pack: fp32 [nmat][K][N] -> MFMA B-frag bf16 ----
// dst idx = (((m*(K/32) + kt)*(N/16) + nt)*64 + l)*8 + j
// value   = W_m[kt*32 + (l>>4)*8 + j][nt*16 + (l&15)]
__global__ __launch_bounds__(256) void pack_all_kernel(
    const float* __restrict__ s0, const float* __restrict__ s1,
    const float* __restrict__ s2, const float* __restrict__ s3,
    const float* __restrict__ s4, const float* __restrict__ s5,
    const float* __restrict__ s6, unsigned short* __restrict__ wpk)
{
  int idx = blockIdx.x*256 + (int)threadIdx.x;
  const float* src; unsigned short* dst; int K, N;
  if      (idx <  4096) { src=s0; dst=wpk;          K=64;  N=64;  }
  else if (idx <  6144) { src=s1; dst=wpk+32768;    K=64;  N=128; idx-=4096; }
  else if (idx <  8192) { src=s2; dst=wpk+49152;    K=128; N=64;  idx-=6144; }
  else if (idx < 24576) { src=s3; dst=wpk+65536;    K=128; N=128; idx-=8192; }
  else if (idx < 32768) { src=s4; dst=wpk+196608;   K=128; N=256; idx-=24576; }
  else if (idx < 40960) { src=s5; dst=wpk+262144;   K=256; N=128; idx-=32768; }
  else if (idx < 41984) { src=s6; dst=wpk+327680;   K=64;  N=128; idx-=40960; }
  else return;
  const int l = idx & 63;
  int f = idx >> 6;
  const int ntn = N >> 4;
  const int nt = f % ntn; f /= ntn;
  const int ktn = K >> 5;
  const int kt = f % ktn;
  const int m  = f / ktn;
  const float* s = src + (size_t)m*K*N + (size_t)(kt*32 + ((l>>4)<<3))*N + nt*16 + (l&15);
  unsigned pw[4];
#pragma unroll
  for (int jj = 0; jj < 4; ++jj)
    pw[jj] = (unsigned)f2bf(s[(size_t)(2*jj)*N]) | ((unsigned)f2bf(s[(size_t)(2*jj+1)*N]) << 16);
  uint4 u; u.x = pw[0]; u.y = pw[1]; u.z = pw[2]; u.w = pw[3];
  *reinterpret_cast<uint4*>(dst + (size_t)idx*8) = u;
}

// ---------------- MFMA GEMM: C = act(A[M,K] @ W[K,PN per part] + bias) --------
template<int K, int PN, int NPARTS, bool RELU, bool GATED, bool WF32, bool WBF>
__global__ __launch_bounds__(256) void mgemm_kernel(
    const unsigned short* __restrict__ Abf,
    const unsigned short* __restrict__ Wpk,
    const float* __restrict__ bias,
    float* __restrict__ C, unsigned short* __restrict__ Cbf,
    const int* __restrict__ nseg)
{
  constexpr int NOUT = NPARTS*PN;
  constexpr int KT = K/32;
  constexpr int NTP = PN/16;
  constexpr int CPP = PN/64;
  const int row0 = blockIdx.x * 64;
  if (GATED) { const int b = row0 >> 10; if ((row0 & (L_-1)) >= nseg[b]) return; }
  const int ct = blockIdx.y;
  const int part = ct / CPP;
  const int nt0  = (ct % CPP) * 4;
  const int wv = (int)threadIdx.x >> 6;
  const int ln = (int)threadIdx.x & 63;
  const int rbase = row0 + wv*16;
  const unsigned short* aptr = Abf + (size_t)(rbase + (ln & 15))*K + ((ln >> 4) << 3);
  const unsigned short* bptr = Wpk + ((size_t)part*KT*NTP + nt0)*512 + (size_t)ln*8;
  f32x4 acc0 = {0.f,0.f,0.f,0.f}, acc1 = {0.f,0.f,0.f,0.f};
  f32x4 acc2 = {0.f,0.f,0.f,0.f}, acc3 = {0.f,0.f,0.f,0.f};
#pragma unroll
  for (int kt = 0; kt < KT; ++kt) {
    short8v a = *reinterpret_cast<const short8v*>(aptr + kt*32);
    const unsigned short* bk = bptr + (size_t)kt*NTP*512;
    short8v b0 = *reinterpret_cast<const short8v*>(bk);
    short8v b1 = *reinterpret_cast<const short8v*>(bk + 512);
    short8v b2 = *reinterpret_cast<const short8v*>(bk + 1024);
    short8v b3 = *reinterpret_cast<const short8v*>(bk + 1536);
    acc0 = __builtin_amdgcn_mfma_f32_16x16x32_bf16(a, b0, acc0, 0, 0, 0);
    acc1 = __builtin_amdgcn_mfma_f32_16x16x32_bf16(a, b1, acc1, 0, 0, 0);
    acc2 = __builtin_amdgcn_mfma_f32_16x16x32_bf16(a, b2, acc2, 0, 0, 0);
    acc3 = __builtin_amdgcn_mfma_f32_16x16x32_bf16(a, b3, acc3, 0, 0, 0);
  }
  const int colb = part*PN + nt0*16 + (ln & 15);
  const int rowe = rbase + ((ln >> 4) << 2);
  f32x4 av[4] = {acc0, acc1, acc2, acc3};
#pragma unroll
  for (int i = 0; i < 4; ++i) {
    const int col = colb + i*16;
    const float bs = bias[col];
#pragma unroll
    for (int r = 0; r < 4; ++r) {
      float v = av[i][r] + bs;
      if (RELU) v = fmaxf(v, 0.f);
      if (WF32) C[(size_t)(rowe + r)*NOUT + col] = v;
      if (WBF)  Cbf[(size_t)(rowe + r)*NOUT + col] = f2bf(v);
    }
  }
}

// ---------------- featurize: 4 points per 256-thr block (dual-write) ----------
__global__ __launch_bounds__(256) void featurize_kernel(
    const float* __restrict__ pts, const float* __restrict__ fs, const float* __restrict__ ft,
    const float* __restrict__ w_space, const float* __restrict__ b_space,
    const float* __restrict__ w_time, const float* __restrict__ b_time,
    const float* __restrict__ w_fout, const float* __restrict__ b_fout,
    const float* __restrict__ w_gate, const float* __restrict__ b_gate,
    float* __restrict__ z, unsigned short* __restrict__ zbf, int* __restrict__ boundary)
{
  const int sub = threadIdx.x >> 6;
  const int d   = threadIdx.x & 63;
  const int p   = blockIdx.x * 4 + sub;
  const float TWO_PI = 6.283185307179586f;
  __shared__ float feat[4][32];
  __shared__ float tfeat[4][16];
  __shared__ float g96[4][96];
  const float x = pts[p*3+0], y = pts[p*3+1], t = pts[p*3+2];
  if (d < 16) {
    float sp = (x*fs[d] + y*fs[16+d]) * TWO_PI;
    feat[sub][d]    = sinf(sp);
    feat[sub][16+d] = cosf(sp);
  } else if (d < 24) {
    int r = d - 16;
    float tp = t * ft[r] * TWO_PI;
    tfeat[sub][r]   = sinf(tp);
    tfeat[sub][8+r] = cosf(tp);
  }
  __syncthreads();
  float sf = b_space[d];
#pragma unroll
  for (int k2 = 0; k2 < 32; ++k2) sf = fmaf(feat[sub][k2], w_space[k2*64+d], sf);
  g96[sub][d] = sf;
  if (d < 32) {
    float tf = b_time[d];
#pragma unroll
    for (int k2 = 0; k2 < 16; ++k2) tf = fmaf(tfeat[sub][k2], w_time[k2*32+d], tf);
    g96[sub][64+d] = tf;
  }
  __syncthreads();
  float zv = b_fout[d];
#pragma unroll
  for (int k2 = 0; k2 < 96; ++k2) zv = fmaf(g96[sub][k2], w_fout[k2*64+d], zv);
  z[(size_t)p*64+d] = zv;
  zbf[(size_t)p*64+d] = f2bf(zv);
  float gv = wave_reduce_sum(zv * w_gate[d]);
  if (d == 0) {
    float logit = gv + b_gate[0];
    float gate = 1.0f / (1.0f + expf(-logit));
    int bnd = (gate > 0.5f) ? 1 : 0;
    if ((p & (L_-1)) == 0) bnd = 1;
    boundary[p] = bnd;
  }
}

// ---------------- scan: seg_id, seg_start, n_seg ----------------
__global__ __launch_bounds__(1024) void scan_kernel(const int* __restrict__ boundary,
    int* __restrict__ seg_id, int* __restrict__ seg_start, int* __restrict__ n_seg)
{
  __shared__ int sc[1024];
  const int b = blockIdx.x, l = threadIdx.x;
  const int v = boundary[b*L_ + l];
  sc[l] = v;
  __syncthreads();
  for (int off = 1; off < 1024; off <<= 1) {
    int add = (l >= off) ? sc[l - off] : 0;
    __syncthreads();
    sc[l] += add;
    __syncthreads();
  }
  const int sid = sc[l] - 1;
  seg_id[b*L_ + l] = sid;
  if (v) seg_start[b*(L_+1) + sid] = l;
  if (l == L_-1) {
    n_seg[b] = sid + 1;
    seg_start[b*(L_+1) + sid + 1] = L_;
  }
}

// ---------------- segment attention (block-diag exact; bf16 out) --------------
__global__ __launch_bounds__(64) void seg_attn_kernel(
    const float* __restrict__ qkv,
    const int* __restrict__ seg_id, const int* __restrict__ seg_start,
    unsigned short* __restrict__ aobf)
{
  const int idx = blockIdx.x * 64 + threadIdx.x;  // ((b*L + pt)*2 + h)
  const int h  = idx & 1;
  const int pt = (idx >> 1) & (L_-1);
  const int b  = idx >> 11;
  const float scale = 0.17677669529663687f;
  float qv[32];
  {
    const float4* qp = reinterpret_cast<const float4*>(qkv + (size_t)(b*L_+pt)*192 + h*32);
#pragma unroll
    for (int j4 = 0; j4 < 8; ++j4) {
      float4 t4 = qp[j4];
      qv[j4*4+0]=t4.x*scale; qv[j4*4+1]=t4.y*scale; qv[j4*4+2]=t4.z*scale; qv[j4*4+3]=t4.w*scale;
    }
  }
  const int s  = seg_id[b*L_ + pt];
  const int j0 = seg_start[b*(L_+1) + s];
  const int j1 = seg_start[b*(L_+1) + s + 1];
  float lsum = 0.f;
  float acc[32];
#pragma unroll
  for (int d = 0; d < 32; ++d) acc[d] = 0.f;
  for (int j = j0; j < j1; ++j) {
    const float* base = qkv + (size_t)(b*L_ + j)*192 + h*32;
    const float4* kp = reinterpret_cast<const float4*>(base + 64);
    float dot = 0.f;
#pragma unroll
    for (int j4 = 0; j4 < 8; ++j4) {
      float4 t4 = kp[j4];
      dot = fmaf(qv[j4*4+0], t4.x, dot);
      dot = fmaf(qv[j4*4+1], t4.y, dot);
      dot = fmaf(qv[j4*4+2], t4.z, dot);
      dot = fmaf(qv[j4*4+3], t4.w, dot);
    }
    const float p = __expf(fminf(dot, 30.f));
    lsum += p;
    const float4* vp = reinterpret_cast<const float4*>(base + 128);
#pragma unroll
    for (int j4 = 0; j4 < 8; ++j4) {
      float4 t4 = vp[j4];
      acc[j4*4+0] = fmaf(p, t4.x, acc[j4*4+0]);
      acc[j4*4+1] = fmaf(p, t4.y, acc[j4*4+1]);
      acc[j4*4+2] = fmaf(p, t4.z, acc[j4*4+2]);
      acc[j4*4+3] = fmaf(p, t4.w, acc[j4*4+3]);
    }
  }
  const float inv = 1.0f / lsum;
  unsigned* op = reinterpret_cast<unsigned*>(aobf + (size_t)(b*L_+pt)*64 + h*32);
#pragma unroll
  for (int d2 = 0; d2 < 16; ++d2)
    op[d2] = (unsigned)f2bf(acc[2*d2]*inv) | ((unsigned)f2bf(acc[2*d2+1]*inv) << 16);
}

// ---------------- V fragment pack for MFMA attention -------------------------
// vfrag[(((b*4+h)*32 + c)*2 + dt)][lane][j] = V[b*L + c*32 + kperm][h*32+dt*16+(lane&15)]
// kperm(slot s = (lane>>4)*8 + j) = (s>>3)*4 + (s&3) + ((s>>2)&1)*16
__global__ __launch_bounds__(256) void vpack_kernel(
    const unsigned short* __restrict__ qkvbf, unsigned short* __restrict__ vfrag)
{
  const int idx = blockIdx.x*256 + (int)threadIdx.x;
  const int lane = idx & 63;
  const int dt = (idx >> 6) & 1;
  const int c  = (idx >> 7) & 31;
  const int h  = (idx >> 12) & 3;
  const int b  = idx >> 14;
  const int g = lane >> 4;
  const int dcol = lane & 15;
  unsigned short vals[8];
#pragma unroll
  for (int j = 0; j < 8; ++j) {
    const int key = c*32 + g*4 + (j & 3) + ((j >> 2) << 4);
    vals[j] = qkvbf[(size_t)(b*L_ + key)*384 + 256 + h*32 + dt*16 + dcol];
  }
  uint4 u;
  u.x = (unsigned)vals[0] | ((unsigned)vals[1] << 16);
  u.y = (unsigned)vals[2] | ((unsigned)vals[3] << 16);
  u.z = (unsigned)vals[4] | ((unsigned)vals[5] << 16);
  u.w = (unsigned)vals[6] | ((unsigned)vals[7] << 16);
  *reinterpret_cast<uint4*>(vfrag + (size_t)idx*8) = u;
}

// ---------------- global attention via MFMA -----------------------------------
// grid: blockIdx.x = (b*4 + h)*16 + qt; block = 256 thr = 4 waves x 16 queries.
// Per 32-key chunk: S^T = mfma(Kfrag, Qfrag) twice; p = exp(s*scale) (fixed-shift,
// masked at key>=ns); P^T lands exactly as the PV A-frag under kperm; O += mfma(P, Vfrag).
__global__ __launch_bounds__(256) void glb_attn_mfma_kernel(
    const unsigned short* __restrict__ qkvbf,   // [16384][384] bf16
    const unsigned short* __restrict__ vfrag,
    const int* __restrict__ n_seg,
    unsigned short* __restrict__ aobf)          // [16384][128] bf16
{
  const int qt = blockIdx.x & 15;
  const int h  = (blockIdx.x >> 4) & 3;
  const int b  = blockIdx.x >> 6;
  const int ns = n_seg[b];
  if (qt*64 >= ns) return;
  const int wv = (int)threadIdx.x >> 6;
  const int ln = (int)threadIdx.x & 63;
  const int g  = ln >> 4;
  const int qc = ln & 15;
  const float scale = 0.17677669529663687f; // 1/sqrt(32)
  __shared__ float lsumS[4][16];

  const int q0 = qt*64 + wv*16;
  const short8v qf = *reinterpret_cast<const short8v*>(
      qkvbf + (size_t)(b*L_ + q0 + qc)*384 + h*32 + g*8);

  f32x4 O0 = {0.f,0.f,0.f,0.f}, O1 = {0.f,0.f,0.f,0.f};
  const f32x4 zz = {0.f,0.f,0.f,0.f};
  float lsum = 0.f;
  const int nchunk = (ns + 31) >> 5;
  const size_t kbase = (size_t)(b*L_)*384 + 128 + h*32 + g*8;
  const unsigned short* vfb = vfrag + (size_t)((b*4 + h)*32)*1024 + (size_t)ln*8;

  for (int c = 0; c < nchunk; ++c) {
    const int k0 = c*32;
    short8v kf0 = *reinterpret_cast<const short8v*>(qkvbf + kbase + (size_t)(k0 + qc)*384);
    short8v kf1 = *reinterpret_cast<const short8v*>(qkvbf + kbase + (size_t)(k0 + 16 + qc)*384);
    f32x4 s0 = __builtin_amdgcn_mfma_f32_16x16x32_bf16(kf0, qf, zz, 0, 0, 0);
    f32x4 s1 = __builtin_amdgcn_mfma_f32_16x16x32_bf16(kf1, qf, zz, 0, 0, 0);
    // lane holds S^T[key k0 + g*4 + r][q=qc] in s0[r]; +16 in s1[r]
    float p[8];
#pragma unroll
    for (int r = 0; r < 4; ++r) {
      const int key0 = k0 + g*4 + r;
      const float e0 = (key0 < ns)      ? __expf(fminf(s0[r]*scale, 30.f)) : 0.f;
      const float e1 = (key0 + 16 < ns) ? __expf(fminf(s1[r]*scale, 30.f)) : 0.f;
      p[r] = e0; p[4+r] = e1;
      lsum += e0 + e1;
    }
    short8v pf;
#pragma unroll
    for (int i = 0; i < 8; ++i) pf[i] = (short)f2bf(p[i]);
    const unsigned short* vb = vfb + (size_t)c*1024;
    short8v v0 = *reinterpret_cast<const short8v*>(vb);
    short8v v1 = *reinterpret_cast<const short8v*>(vb + 512);
    O0 = __builtin_amdgcn_mfma_f32_16x16x32_bf16(pf, v0, O0, 0, 0, 0);
    O1 = __builtin_amdgcn_mfma_f32_16x16x32_bf16(pf, v1, O1, 0, 0, 0);
  }
  // lsum currently: partial for q=qc over keys of lane-group g. Sum groups:
  lsum += __shfl_xor(lsum, 16, 64);
  lsum += __shfl_xor(lsum, 32, 64);
  if (ln < 16) lsumS[wv][ln] = lsum;
  __syncthreads();
  // O rows: q = q0 + g*4 + r; col d = h*32 + qc (O0) / +16 (O1)
  unsigned short* outp = aobf + (size_t)(b*L_ + q0 + g*4)*128 + h*32 + qc;
#pragma unroll
  for (int r = 0; r < 4; ++r) {
    const float inv = 1.0f / lsumS[wv][g*4 + r];
    outp[(size_t)r*128]      = f2bf(O0[r]*inv);
    outp[(size_t)r*128 + 16] = f2bf(O1[r]*inv);
  }
}

// ---------------- LN(x+r) D=64: dual-write fp32 + bf16 ----------------
__global__ __launch_bounds__(256) void ln64_kernel(
    float* __restrict__ x, const float* __restrict__ r,
    const float* __restrict__ gam, const float* __restrict__ bet,
    unsigned short* __restrict__ xbf)
{
  const int row = blockIdx.x*4 + ((int)threadIdx.x >> 6);
  const int d = (int)threadIdx.x & 63;
  float val = x[(size_t)row*64 + d] + r[(size_t)row*64 + d];
  float s = wave_reduce_sum(val);
  const float mean = s * (1.0f/64.0f);
  const float dv = val - mean;
  float s2 = wave_reduce_sum(dv*dv);
  const float out = dv * rsqrtf(s2*(1.0f/64.0f) + 1e-5f) * gam[d] + bet[d];
  x[(size_t)row*64 + d] = out;
  xbf[(size_t)row*64 + d] = f2bf(out);
}

// ---------------- LN(x+r) D=128 gated: dual-write ----------------
__global__ __launch_bounds__(256) void ln128_kernel(
    float* __restrict__ x, const float* __restrict__ r,
    const float* __restrict__ gam, const float* __restrict__ bet,
    const int* __restrict__ nseg, unsigned short* __restrict__ xbf)
{
  const int row0 = blockIdx.x*2;
  const int b = row0 >> 10;
  if ((row0 & (L_-1)) >= nseg[b]) return;
  const int sub = (int)threadIdx.x >> 7;
  const int d   = (int)threadIdx.x & 127;
  const int row = row0 + sub;
  const bool valid = (row & (L_-1)) < nseg[b];
  __shared__ float red[2][4];
  float val = 0.f;
  if (valid) val = x[(size_t)row*128 + d] + r[(size_t)row*128 + d];
  float s = wave_reduce_sum(val);
  if ((d & 63) == 0) red[sub][d >> 6] = s;
  __syncthreads();
  s = red[sub][0] + red[sub][1];
  const float mean = s * (1.0f/128.0f);
  const float dv = val - mean;
  float s2 = wave_reduce_sum(dv*dv);
  if ((d & 63) == 0) red[sub][2 + (d >> 6)] = s2;
  __syncthreads();
  s2 = red[sub][2] + red[sub][3];
  if (valid) {
    const float out = dv * rsqrtf(s2*(1.0f/128.0f) + 1e-5f) * gam[d] + bet[d];
    x[(size_t)row*128 + d] = out;
    xbf[(size_t)row*128 + d] = f2bf(out);
  }
}

// ---------------- segment mean pooling -> bf16 [row][64] ----------------
__global__ __launch_bounds__(256) void pool_kernel(
    const float* __restrict__ h, const int* __restrict__ seg_start,
    const int* __restrict__ n_seg, unsigned short* __restrict__ meanbf)
{
  const int gs = blockIdx.x*4 + ((int)threadIdx.x >> 6);
  const int b = gs >> 10, s = gs & (L_-1);
  const int d = (int)threadIdx.x & 63;
  if (s >= n_seg[b]) return;
  const int j0 = seg_start[b*(L_+1)+s], j1 = seg_start[b*(L_+1)+s+1];
  float acc = 0.f;
  for (int j = j0; j < j1; ++j) acc += h[(size_t)(b*L_+j)*64 + d];
  meanbf[(size_t)gs*64 + d] = f2bf(acc / (float)(j1 - j0));
}

// ---------------- save row0 of xg for ns==1 path ----------------
__global__ __launch_bounds__(128) void row0_kernel(
    const float* __restrict__ xg, float* __restrict__ semb0)
{
  semb0[blockIdx.x*128 + threadIdx.x] = xg[(size_t)blockIdx.x*L_*128 + threadIdx.x];
}

// ---------------- final pooling phase A ----------------
__global__ __launch_bounds__(128) void pool_final_kernel(
    const float* __restrict__ g, const int* __restrict__ n_seg,
    float* __restrict__ partial)
{
  const int b = blockIdx.x >> 4, c = blockIdx.x & 15;
  const int d = (int)threadIdx.x;
  const int ns = n_seg[b];
  const int i0 = c*64, i1 = min(ns, i0 + 64);
  float acc = 0.f;
  for (int i = i0; i < i1; ++i) acc += g[(size_t)(b*L_+i)*128 + d];
  partial[(size_t)blockIdx.x*128 + d] = acc;
}

// ---------------- final phase B ----------------
__global__ __launch_bounds__(128) void final_kernel(
    const float* __restrict__ partial, const float* __restrict__ semb0,
    const int* __restrict__ n_seg, const float* __restrict__ fin_w,
    const float* __restrict__ fin_b, float* __restrict__ out)
{
  const int b = blockIdx.x, d = threadIdx.x;
  const int ns = n_seg[b];
  __shared__ float pl[128];
  float pooled;
  if (ns == 1) pooled = semb0[b*128 + d];
  else {
    float acc = 0.f;
#pragma unroll
    for (int c = 0; c < 16; ++c) acc += partial[(size_t)(b*16 + c)*128 + d];
    pooled = acc / (float)ns;
  }
  pl[d] = pooled;
  __syncthreads();
  float o = fin_b[d];
#pragma unroll 8
  for (int k2 = 0; k2 < 128; ++k2) o = fmaf(pl[k2], fin_w[k2*128+d], o);
  out[b*128+d] = o;
}

extern "C" void kernel_launch(void* const* d_in, const int* in_sizes, int n_in,
                              void* d_out, int out_size, void* d_ws, size_t ws_size,
                              hipStream_t stream) {
  const float* pts     = (const float*)d_in[0];
  const float* fs      = (const float*)d_in[1];
  const float* ft      = (const float*)d_in[2];
  const float* w_space = (const float*)d_in[3];
  const float* b_space = (const float*)d_in[4];
  const float* w_time  = (const float*)d_in[5];
  const float* b_time  = (const float*)d_in[6];
  const float* w_fout  = (const float*)d_in[7];
  const float* b_fout  = (const float*)d_in[8];
  const float* w_gate  = (const float*)d_in[9];
  const float* b_gate  = (const float*)d_in[10];
  const float* seg_attn_w = (const float*)d_in[11];
  const float* seg_attn_b = (const float*)d_in[12];
  const float* seg_ln_g   = (const float*)d_in[13];
  const float* seg_ln_b   = (const float*)d_in[14];
  const float* seg_ff1_w  = (const float*)d_in[15];
  const float* seg_ff1_b  = (const float*)d_in[16];
  const float* seg_ff2_w  = (const float*)d_in[17];
  const float* seg_ff2_b  = (const float*)d_in[18];
  const float* glb_attn_w = (const float*)d_in[19];
  const float* glb_attn_b = (const float*)d_in[20];
  const float* glb_ln_g   = (const float*)d_in[21];
  const float* glb_ln_b   = (const float*)d_in[22];
  const float* glb_ff1_w  = (const float*)d_in[23];
  const float* glb_ff1_b  = (const float*)d_in[24];
  const float* glb_ff2_w  = (const float*)d_in[25];
  const float* glb_ff2_b  = (const float*)d_in[26];
  const float* up_w    = (const float*)d_in[27];
  const float* up_b    = (const float*)d_in[28];
  const float* fin_w   = (const float*)d_in[29];
  const float* fin_b   = (const float*)d_in[30];

  // workspace layout (MB offsets):
  // 0-4  : zx f32 (seg)        | xg_bf bf16 (glb, alias)
  // 4-30 : qkv f32 (seg) / qkv_bf bf16 (glb) / tmp f32 (alias, disjoint lifetimes)
  // 30-38: aob f32 | 38-46: xg f32 (+zx_bf head during seg)
  // 46-47: ints | 47: semb0+partial | 50-58: tmp_bf | 58-62: vfrag
  // 84-88: abf | 88-89: wpk
  char* ws = (char*)d_ws;
  float* zx   = (float*)(ws);
  unsigned short* xg_bf = (unsigned short*)(ws);
  float* qkv  = (float*)(ws + ((size_t)4  << 20));
  unsigned short* qkv_bf = (unsigned short*)(ws + ((size_t)4 << 20));
  float* tmp  = qkv;
  float* aob  = (float*)(ws + ((size_t)30 << 20));
  float* xg   = (float*)(ws + ((size_t)38 << 20));
  unsigned short* zx_bf = (unsigned short*)(ws + ((size_t)38 << 20));
  int* boundary  = (int*)(ws + ((size_t)46 << 20));
  int* seg_id    = boundary + M_TOT;
  int* seg_start = seg_id + M_TOT;
  int* n_seg     = seg_start + B_*(L_+1);
  float* semb0     = (float*)(ws + ((size_t)47 << 20));
  float* partial   = (float*)(ws + ((size_t)47 << 20) + 65536);
  unsigned short* tmp_bf = (unsigned short*)(ws + ((size_t)50 << 20));
  unsigned short* vfrag  = (unsigned short*)(ws + ((size_t)58 << 20));
  unsigned short* abf    = (unsigned short*)(ws + ((size_t)84 << 20));
  unsigned short* wpk    = (unsigned short*)(ws + ((size_t)88 << 20));

  unsigned short* wpk_segA  = wpk;
  unsigned short* wpk_segF1 = wpk + 32768;
  unsigned short* wpk_segF2 = wpk + 49152;
  unsigned short* wpk_glbA  = wpk + 65536;
  unsigned short* wpk_glbF1 = wpk + 196608;
  unsigned short* wpk_glbF2 = wpk + 262144;
  unsigned short* wpk_up    = wpk + 327680;

  pack_all_kernel<<<164, 256, 0, stream>>>(seg_attn_w, seg_ff1_w, seg_ff2_w,
                                           glb_attn_w, glb_ff1_w, glb_ff2_w, up_w, wpk);

  featurize_kernel<<<M_TOT/4, 256, 0, stream>>>(pts, fs, ft, w_space, b_space, w_time, b_time,
                                                w_fout, b_fout, w_gate, b_gate, zx, zx_bf, boundary);
  scan_kernel<<<B_, 1024, 0, stream>>>(boundary, seg_id, seg_start, n_seg);

  // ---- segment-level encoder (D=64, H=2, FF=128) ----
  for (int l = 0; l < 2; ++l) {
    const float* ab = seg_attn_b + (size_t)l*4*64;
    mgemm_kernel<64,64,3,false,false,true,false><<<dim3(256,3),256,0,stream>>>(
        zx_bf, wpk_segA + (size_t)l*4*4096, ab, qkv, nullptr, nullptr);
    seg_attn_kernel<<<(M_TOT*2)/64, 64, 0, stream>>>(qkv, seg_id, seg_start, abf);
    mgemm_kernel<64,64,1,false,false,true,false><<<dim3(256,1),256,0,stream>>>(
        abf, wpk_segA + (size_t)(l*4+3)*4096, ab + 192, tmp, nullptr, nullptr);
    ln64_kernel<<<M_TOT/4, 256, 0, stream>>>(zx, tmp, seg_ln_g + l*128, seg_ln_b + l*128, zx_bf);
    mgemm_kernel<64,128,1,true,false,false,true><<<dim3(256,2),256,0,stream>>>(
        zx_bf, wpk_segF1 + (size_t)l*8192, seg_ff1_b + l*128, nullptr, tmp_bf, nullptr);
    mgemm_kernel<128,64,1,false,false,true,false><<<dim3(256,1),256,0,stream>>>(
        tmp_bf, wpk_segF2 + (size_t)l*8192, seg_ff2_b + l*64, aob, nullptr, nullptr);
    ln64_kernel<<<M_TOT/4, 256, 0, stream>>>(zx, aob, seg_ln_g + l*128 + 64, seg_ln_b + l*128 + 64, zx_bf);
  }

  // ---- pooling + up-projection (gated) ----
  pool_kernel<<<M_TOT/4, 256, 0, stream>>>(zx, seg_start, n_seg, abf);
  mgemm_kernel<64,128,1,false,true,true,true><<<dim3(256,2),256,0,stream>>>(
      abf, wpk_up, up_b, xg, xg_bf, n_seg);
  row0_kernel<<<B_, 128, 0, stream>>>(xg, semb0);

  // ---- global-level encoder (D=128, H=4, FF=256), row-gated ----
  for (int l = 0; l < 2; ++l) {
    const float* ab = glb_attn_b + (size_t)l*4*128;
    mgemm_kernel<128,128,3,false,true,false,true><<<dim3(256,6),256,0,stream>>>(
        xg_bf, wpk_glbA + (size_t)l*4*16384, ab, nullptr, qkv_bf, n_seg);
    vpack_kernel<<<1024, 256, 0, stream>>>(qkv_bf, vfrag);
    glb_attn_mfma_kernel<<<B_*4*16, 256, 0, stream>>>(qkv_bf, vfrag, n_seg, abf);
    mgemm_kernel<128,128,1,false,true,true,false><<<dim3(256,2),256,0,stream>>>(
        abf, wpk_glbA + (size_t)(l*4+3)*16384, ab + 384, tmp, nullptr, n_seg);
    ln128_kernel<<<M_TOT/2, 256, 0, stream>>>(xg, tmp, glb_ln_g + l*256, glb_ln_b + l*256, n_seg, xg_bf);
    mgemm_kernel<128,256,1,true,true,false,true><<<dim3(256,4),256,0,stream>>>(
        xg_bf, wpk_glbF1 + (size_t)l*32768, glb_ff1_b + l*256, nullptr, tmp_bf, n_seg);
    mgemm_kernel<256,128,1,false,true,true,false><<<dim3(256,2),256,0,stream>>>(
        tmp_bf, wpk_glbF2 + (size_t)l*32768, glb_ff2_b + l*128, aob, nullptr, n_seg);
    ln128_kernel<<<M_TOT/2, 256, 0, stream>>>(xg, aob, glb_ln_g + l*256 + 128, glb_ln_b + l*256 + 128, n_seg, xg_bf);
  }

  pool_final_kernel<<<B_*16, 128, 0, stream>>>(xg, n_seg, partial);
  final_kernel<<<B_, 128, 0, stream>>>(partial, semb0, n_seg, fin_w, fin_b, (float*)d_out);
}

// Round 8
// 315.085 us; speedup vs baseline: 4.3758x; 1.0128x over previous
//
#include <hip/hip_runtime.h>
#include <math.h>

#define B_ 16
#define L_ 1024
#define M_TOT (B_*L_)   // 16384

typedef __attribute__((ext_vector_type(8))) short short8v;  // 8 bf16 (4 VGPRs)
typedef __attribute__((ext_vector_type(4))) float f32x4;

__device__ __forceinline__ float wave_reduce_sum(float v) {
#pragma unroll
  for (int o = 32; o >= 1; o >>= 1) v += __shfl_xor(v, o, 64);
  return v;
}

__device__ __forceinline__ unsigned short f2bf(float f) {
  union { float f; unsigned u; } v; v.f = f;
  unsigned r = v.u + 0x7FFFu + ((v.u >> 16) & 1u);
  return (unsigned short)(r >> 16);
}

// ---------------- fused weight pack: fp32 [nmat][K][N] -> MFMA B-frag bf16 ----
__global__ __launch_bounds__(256) void pack_all_kernel(
    const float* __restrict__ s0, const float* __restrict__ s1,
    const float* __restrict__ s2, const float* __restrict__ s3,
    const float* __restrict__ s4, const float* __restrict__ s5,
    const float* __restrict__ s6, unsigned short* __restrict__ wpk)
{
  int idx = blockIdx.x*256 + (int)threadIdx.x;
  const float* src; unsigned short* dst; int K, N;
  if      (idx <  4096) { src=s0; dst=wpk;          K=64;  N=64;  }
  else if (idx <  6144) { src=s1; dst=wpk+32768;    K=64;  N=128; idx-=4096; }
  else if (idx <  8192) { src=s2; dst=wpk+49152;    K=128; N=64;  idx-=6144; }
  else if (idx < 24576) { src=s3; dst=wpk+65536;    K=128; N=128; idx-=8192; }
  else if (idx < 32768) { src=s4; dst=wpk+196608;   K=128; N=256; idx-=24576; }
  else if (idx < 40960) { src=s5; dst=wpk+262144;   K=256; N=128; idx-=32768; }
  else if (idx < 41984) { src=s6; dst=wpk+327680;   K=64;  N=128; idx-=40960; }
  else return;
  const int l = idx & 63;
  int f = idx >> 6;
  const int ntn = N >> 4;
  const int nt = f % ntn; f /= ntn;
  const int ktn = K >> 5;
  const int kt = f % ktn;
  const int m  = f / ktn;
  const float* s = src + (size_t)m*K*N + (size_t)(kt*32 + ((l>>4)<<3))*N + nt*16 + (l&15);
  unsigned pw[4];
#pragma unroll
  for (int jj = 0; jj < 4; ++jj)
    pw[jj] = (unsigned)f2bf(s[(size_t)(2*jj)*N]) | ((unsigned)f2bf(s[(size_t)(2*jj+1)*N]) << 16);
  uint4 u; u.x = pw[0]; u.y = pw[1]; u.z = pw[2]; u.w = pw[3];
  *reinterpret_cast<uint4*>(dst + (size_t)idx*8) = u;
}

// ---------------- MFMA GEMM: C = act(A[M,K] @ W[K,PN per part] + bias) --------
// SPART >= 0: multiply that part's output by 1/sqrt(32)*log2(e) (Q pre-scale).
template<int K, int PN, int NPARTS, bool RELU, bool GATED, bool WF32, bool WBF, int SPART = -1>
__global__ __launch_bounds__(256) void mgemm_kernel(
    const unsigned short* __restrict__ Abf,
    const unsigned short* __restrict__ Wpk,
    const float* __restrict__ bias,
    float* __restrict__ C, unsigned short* __restrict__ Cbf,
    const int* __restrict__ nseg)
{
  constexpr int NOUT = NPARTS*PN;
  constexpr int KT = K/32;
  constexpr int NTP = PN/16;
  constexpr int CPP = PN/64;
  const int row0 = blockIdx.x * 64;
  if (GATED) { const int b = row0 >> 10; if ((row0 & (L_-1)) >= nseg[b]) return; }
  const int ct = blockIdx.y;
  const int part = ct / CPP;
  const int nt0  = (ct % CPP) * 4;
  const int wv = (int)threadIdx.x >> 6;
  const int ln = (int)threadIdx.x & 63;
  const int rbase = row0 + wv*16;
  const unsigned short* aptr = Abf + (size_t)(rbase + (ln & 15))*K + ((ln >> 4) << 3);
  const unsigned short* bptr = Wpk + ((size_t)part*KT*NTP + nt0)*512 + (size_t)ln*8;
  f32x4 acc0 = {0.f,0.f,0.f,0.f}, acc1 = {0.f,0.f,0.f,0.f};
  f32x4 acc2 = {0.f,0.f,0.f,0.f}, acc3 = {0.f,0.f,0.f,0.f};
#pragma unroll
  for (int kt = 0; kt < KT; ++kt) {
    short8v a = *reinterpret_cast<const short8v*>(aptr + kt*32);
    const unsigned short* bk = bptr + (size_t)kt*NTP*512;
    short8v b0 = *reinterpret_cast<const short8v*>(bk);
    short8v b1 = *reinterpret_cast<const short8v*>(bk + 512);
    short8v b2 = *reinterpret_cast<const short8v*>(bk + 1024);
    short8v b3 = *reinterpret_cast<const short8v*>(bk + 1536);
    acc0 = __builtin_amdgcn_mfma_f32_16x16x32_bf16(a, b0, acc0, 0, 0, 0);
    acc1 = __builtin_amdgcn_mfma_f32_16x16x32_bf16(a, b1, acc1, 0, 0, 0);
    acc2 = __builtin_amdgcn_mfma_f32_16x16x32_bf16(a, b2, acc2, 0, 0, 0);
    acc3 = __builtin_amdgcn_mfma_f32_16x16x32_bf16(a, b3, acc3, 0, 0, 0);
  }
  const int colb = part*PN + nt0*16 + (ln & 15);
  const int rowe = rbase + ((ln >> 4) << 2);
  f32x4 av[4] = {acc0, acc1, acc2, acc3};
#pragma unroll
  for (int i = 0; i < 4; ++i) {
    const int col = colb + i*16;
    const float bs = bias[col];
#pragma unroll
    for (int r = 0; r < 4; ++r) {
      float v = av[i][r] + bs;
      if (SPART >= 0) { if (part == SPART) v *= 0.25506972533f; }  // 1/sqrt(32)*log2e
      if (RELU) v = fmaxf(v, 0.f);
      if (WF32) C[(size_t)(rowe + r)*NOUT + col] = v;
      if (WBF)  Cbf[(size_t)(rowe + r)*NOUT + col] = f2bf(v);
    }
  }
}

// ---------------- featurize: 4 points per 256-thr block (dual-write) ----------
__global__ __launch_bounds__(256) void featurize_kernel(
    const float* __restrict__ pts, const float* __restrict__ fs, const float* __restrict__ ft,
    const float* __restrict__ w_space, const float* __restrict__ b_space,
    const float* __restrict__ w_time, const float* __restrict__ b_time,
    const float* __restrict__ w_fout, const float* __restrict__ b_fout,
    const float* __restrict__ w_gate, const float* __restrict__ b_gate,
    float* __restrict__ z, unsigned short* __restrict__ zbf, int* __restrict__ boundary)
{
  const int sub = threadIdx.x >> 6;
  const int d   = threadIdx.x & 63;
  const int p   = blockIdx.x * 4 + sub;
  const float TWO_PI = 6.283185307179586f;
  __shared__ float feat[4][32];
  __shared__ float tfeat[4][16];
  __shared__ float g96[4][96];
  const float x = pts[p*3+0], y = pts[p*3+1], t = pts[p*3+2];
  if (d < 16) {
    float sp = (x*fs[d] + y*fs[16+d]) * TWO_PI;
    feat[sub][d]    = sinf(sp);
    feat[sub][16+d] = cosf(sp);
  } else if (d < 24) {
    int r = d - 16;
    float tp = t * ft[r] * TWO_PI;
    tfeat[sub][r]   = sinf(tp);
    tfeat[sub][8+r] = cosf(tp);
  }
  __syncthreads();
  float sf = b_space[d];
#pragma unroll
  for (int k2 = 0; k2 < 32; ++k2) sf = fmaf(feat[sub][k2], w_space[k2*64+d], sf);
  g96[sub][d] = sf;
  if (d < 32) {
    float tf = b_time[d];
#pragma unroll
    for (int k2 = 0; k2 < 16; ++k2) tf = fmaf(tfeat[sub][k2], w_time[k2*32+d], tf);
    g96[sub][64+d] = tf;
  }
  __syncthreads();
  float zv = b_fout[d];
#pragma unroll
  for (int k2 = 0; k2 < 96; ++k2) zv = fmaf(g96[sub][k2], w_fout[k2*64+d], zv);
  z[(size_t)p*64+d] = zv;
  zbf[(size_t)p*64+d] = f2bf(zv);
  float gv = wave_reduce_sum(zv * w_gate[d]);
  if (d == 0) {
    float logit = gv + b_gate[0];
    float gate = 1.0f / (1.0f + expf(-logit));
    int bnd = (gate > 0.5f) ? 1 : 0;
    if ((p & (L_-1)) == 0) bnd = 1;
    boundary[p] = bnd;
  }
}

// ---------------- scan: seg_id, seg_start, n_seg ----------------
__global__ __launch_bounds__(1024) void scan_kernel(const int* __restrict__ boundary,
    int* __restrict__ seg_id, int* __restrict__ seg_start, int* __restrict__ n_seg)
{
  __shared__ int sc[1024];
  const int b = blockIdx.x, l = threadIdx.x;
  const int v = boundary[b*L_ + l];
  sc[l] = v;
  __syncthreads();
  for (int off = 1; off < 1024; off <<= 1) {
    int add = (l >= off) ? sc[l - off] : 0;
    __syncthreads();
    sc[l] += add;
    __syncthreads();
  }
  const int sid = sc[l] - 1;
  seg_id[b*L_ + l] = sid;
  if (v) seg_start[b*(L_+1) + sid] = l;
  if (l == L_-1) {
    n_seg[b] = sid + 1;
    seg_start[b*(L_+1) + sid + 1] = L_;
  }
}

// ---------------- segment attention: 8 lanes per (pt,h) item -------------------
// qkv packed [row][3][64]; lane sub owns dims [sub*4, sub*4+4)
__global__ __launch_bounds__(256) void seg_attn_kernel(
    const float* __restrict__ qkv,
    const int* __restrict__ seg_id, const int* __restrict__ seg_start,
    unsigned short* __restrict__ aobf)
{
  const int gid = blockIdx.x * 256 + (int)threadIdx.x;  // item*8 + sub
  const int sub = gid & 7;
  const int item = gid >> 3;        // ((b*L + pt)*2 + h)
  const int h  = item & 1;
  const int pt = (item >> 1) & (L_-1);
  const int b  = item >> 11;
  const float scale = 0.17677669529663687f;
  float4 q4 = *reinterpret_cast<const float4*>(qkv + (size_t)(b*L_+pt)*192 + h*32 + sub*4);
  q4.x*=scale; q4.y*=scale; q4.z*=scale; q4.w*=scale;
  const int s  = seg_id[b*L_ + pt];
  const int j0 = seg_start[b*(L_+1) + s];
  const int j1 = seg_start[b*(L_+1) + s + 1];
  float lsum = 0.f;
  float4 acc = {0.f,0.f,0.f,0.f};
  for (int j = j0; j < j1; ++j) {
    const float* base = qkv + (size_t)(b*L_ + j)*192 + h*32 + sub*4;
    float4 k4 = *reinterpret_cast<const float4*>(base + 64);
    float4 v4 = *reinterpret_cast<const float4*>(base + 128);
    float dot = q4.x*k4.x;
    dot = fmaf(q4.y, k4.y, dot);
    dot = fmaf(q4.z, k4.z, dot);
    dot = fmaf(q4.w, k4.w, dot);
    dot += __shfl_xor(dot, 1, 64);
    dot += __shfl_xor(dot, 2, 64);
    dot += __shfl_xor(dot, 4, 64);
    const float p = __expf(fminf(dot, 30.f));
    lsum += p;
    acc.x = fmaf(p, v4.x, acc.x);
    acc.y = fmaf(p, v4.y, acc.y);
    acc.z = fmaf(p, v4.z, acc.z);
    acc.w = fmaf(p, v4.w, acc.w);
  }
  const float inv = 1.0f / lsum;
  unsigned* op = reinterpret_cast<unsigned*>(aobf + (size_t)(b*L_+pt)*64 + h*32 + sub*4);
  op[0] = (unsigned)f2bf(acc.x*inv) | ((unsigned)f2bf(acc.y*inv) << 16);
  op[1] = (unsigned)f2bf(acc.z*inv) | ((unsigned)f2bf(acc.w*inv) << 16);
}

// ---------------- V fragment pack for MFMA attention -------------------------
__global__ __launch_bounds__(256) void vpack_kernel(
    const unsigned short* __restrict__ qkvbf, unsigned short* __restrict__ vfrag)
{
  const int idx = blockIdx.x*256 + (int)threadIdx.x;
  const int lane = idx & 63;
  const int dt = (idx >> 6) & 1;
  const int c  = (idx >> 7) & 31;
  const int h  = (idx >> 12) & 3;
  const int b  = idx >> 14;
  const int g = lane >> 4;
  const int dcol = lane & 15;
  unsigned short vals[8];
#pragma unroll
  for (int j = 0; j < 8; ++j) {
    const int key = c*32 + g*4 + (j & 3) + ((j >> 2) << 4);
    vals[j] = qkvbf[(size_t)(b*L_ + key)*384 + 256 + h*32 + dt*16 + dcol];
  }
  uint4 u;
  u.x = (unsigned)vals[0] | ((unsigned)vals[1] << 16);
  u.y = (unsigned)vals[2] | ((unsigned)vals[3] << 16);
  u.z = (unsigned)vals[4] | ((unsigned)vals[5] << 16);
  u.w = (unsigned)vals[6] | ((unsigned)vals[7] << 16);
  *reinterpret_cast<uint4*>(vfrag + (size_t)idx*8) = u;
}

// ---------------- global attention via MFMA (prefetched, exp2) -----------------
// Q was pre-scaled by 1/sqrt(32)*log2e in the QKV GEMM -> p = exp2(S).
__global__ __launch_bounds__(256) void glb_attn_mfma_kernel(
    const unsigned short* __restrict__ qkvbf,   // [16384][384] bf16
    const unsigned short* __restrict__ vfrag,
    const int* __restrict__ n_seg,
    unsigned short* __restrict__ aobf)          // [16384][128] bf16
{
  const int qt = blockIdx.x & 15;
  const int h  = (blockIdx.x >> 4) & 3;
  const int b  = blockIdx.x >> 6;
  const int ns = n_seg[b];
  if (qt*64 >= ns) return;
  const int wv = (int)threadIdx.x >> 6;
  const int ln = (int)threadIdx.x & 63;
  const int g  = ln >> 4;
  const int qc = ln & 15;
  __shared__ float lsumS[4][16];

  const int q0 = qt*64 + wv*16;
  const short8v qf = *reinterpret_cast<const short8v*>(
      qkvbf + (size_t)(b*L_ + q0 + qc)*384 + h*32 + g*8);

  f32x4 O0 = {0.f,0.f,0.f,0.f}, O1 = {0.f,0.f,0.f,0.f};
  const f32x4 zz = {0.f,0.f,0.f,0.f};
  float lsum = 0.f;
  const int nchunk = (ns + 31) >> 5;
  const unsigned short* kp = qkvbf + (size_t)(b*L_)*384 + 128 + h*32 + g*8;
  const unsigned short* vfb = vfrag + (size_t)((b*4 + h)*32)*1024 + (size_t)ln*8;

  // prefetch chunk 0
  short8v kf0c = *reinterpret_cast<const short8v*>(kp + (size_t)qc*384);
  short8v kf1c = *reinterpret_cast<const short8v*>(kp + (size_t)(16 + qc)*384);
  short8v v0c  = *reinterpret_cast<const short8v*>(vfb);
  short8v v1c  = *reinterpret_cast<const short8v*>(vfb + 512);

  for (int c = 0; c < nchunk; ++c) {
    const int cn = (c + 1 < nchunk) ? c + 1 : c;
    // issue next chunk's loads before computing current (hide L2/L3 latency)
    short8v kf0n = *reinterpret_cast<const short8v*>(kp + (size_t)(cn*32 + qc)*384);
    short8v kf1n = *reinterpret_cast<const short8v*>(kp + (size_t)(cn*32 + 16 + qc)*384);
    short8v v0n  = *reinterpret_cast<const short8v*>(vfb + (size_t)cn*1024);
    short8v v1n  = *reinterpret_cast<const short8v*>(vfb + (size_t)cn*1024 + 512);

    f32x4 s0 = __builtin_amdgcn_mfma_f32_16x16x32_bf16(kf0c, qf, zz, 0, 0, 0);
    f32x4 s1 = __builtin_amdgcn_mfma_f32_16x16x32_bf16(kf1c, qf, zz, 0, 0, 0);
    const int k0 = c*32;
    float p[8];
#pragma unroll
    for (int r = 0; r < 4; ++r) {
      const int key0 = k0 + g*4 + r;
      const float e0 = (key0 < ns)      ? exp2f(fminf(s0[r], 43.f)) : 0.f;
      const float e1 = (key0 + 16 < ns) ? exp2f(fminf(s1[r], 43.f)) : 0.f;
      p[r] = e0; p[4+r] = e1;
      lsum += e0 + e1;
    }
    short8v pf;
#pragma unroll
    for (int i = 0; i < 8; ++i) pf[i] = (short)f2bf(p[i]);
    O0 = __builtin_amdgcn_mfma_f32_16x16x32_bf16(pf, v0c, O0, 0, 0, 0);
    O1 = __builtin_amdgcn_mfma_f32_16x16x32_bf16(pf, v1c, O1, 0, 0, 0);
    kf0c = kf0n; kf1c = kf1n; v0c = v0n; v1c = v1n;
  }
  lsum += __shfl_xor(lsum, 16, 64);
  lsum += __shfl_xor(lsum, 32, 64);
  if (ln < 16) lsumS[wv][ln] = lsum;
  __syncthreads();
  unsigned short* outp = aobf + (size_t)(b*L_ + q0 + g*4)*128 + h*32 + qc;
#pragma unroll
  for (int r = 0; r < 4; ++r) {
    const float inv = 1.0f / lsumS[wv][g*4 + r];
    outp[(size_t)r*128]      = f2bf(O0[r]*inv);
    outp[(size_t)r*128 + 16] = f2bf(O1[r]*inv);
  }
}

// ---------------- LN(x+r) D=64: dual-write fp32 + bf16 ----------------
__global__ __launch_bounds__(256) void ln64_kernel(
    float* __restrict__ x, const float* __restrict__ r,
    const float* __restrict__ gam, const float* __restrict__ bet,
    unsigned short* __restrict__ xbf)
{
  const int row = blockIdx.x*4 + ((int)threadIdx.x >> 6);
  const int d = (int)threadIdx.x & 63;
  float val = x[(size_t)row*64 + d] + r[(size_t)row*64 + d];
  float s = wave_reduce_sum(val);
  const float mean = s * (1.0f/64.0f);
  const float dv = val - mean;
  float s2 = wave_reduce_sum(dv*dv);
  const float out = dv * rsqrtf(s2*(1.0f/64.0f) + 1e-5f) * gam[d] + bet[d];
  x[(size_t)row*64 + d] = out;
  xbf[(size_t)row*64 + d] = f2bf(out);
}

// ---------------- LN(x+r) D=128 gated: dual-write ----------------
__global__ __launch_bounds__(256) void ln128_kernel(
    float* __restrict__ x, const float* __restrict__ r,
    const float* __restrict__ gam, const float* __restrict__ bet,
    const int* __restrict__ nseg, unsigned short* __restrict__ xbf)
{
  const int row0 = blockIdx.x*2;
  const int b = row0 >> 10;
  if ((row0 & (L_-1)) >= nseg[b]) return;
  const int sub = (int)threadIdx.x >> 7;
  const int d   = (int)threadIdx.x & 127;
  const int row = row0 + sub;
  const bool valid = (row & (L_-1)) < nseg[b];
  __shared__ float red[2][4];
  float val = 0.f;
  if (valid) val = x[(size_t)row*128 + d] + r[(size_t)row*128 + d];
  float s = wave_reduce_sum(val);
  if ((d & 63) == 0) red[sub][d >> 6] = s;
  __syncthreads();
  s = red[sub][0] + red[sub][1];
  const float mean = s * (1.0f/128.0f);
  const float dv = val - mean;
  float s2 = wave_reduce_sum(dv*dv);
  if ((d & 63) == 0) red[sub][2 + (d >> 6)] = s2;
  __syncthreads();
  s2 = red[sub][2] + red[sub][3];
  if (valid) {
    const float out = dv * rsqrtf(s2*(1.0f/128.0f) + 1e-5f) * gam[d] + bet[d];
    x[(size_t)row*128 + d] = out;
    xbf[(size_t)row*128 + d] = f2bf(out);
  }
}

// ---------------- segment mean pooling -> bf16 [row][64] ----------------
__global__ __launch_bounds__(256) void pool_kernel(
    const float* __restrict__ h, const int* __restrict__ seg_start,
    const int* __restrict__ n_seg, unsigned short* __restrict__ meanbf)
{
  const int gs = blockIdx.x*4 + ((int)threadIdx.x >> 6);
  const int b = gs >> 10, s = gs & (L_-1);
  const int d = (int)threadIdx.x & 63;
  if (s >= n_seg[b]) return;
  const int j0 = seg_start[b*(L_+1)+s], j1 = seg_start[b*(L_+1)+s+1];
  float acc = 0.f;
  for (int j = j0; j < j1; ++j) acc += h[(size_t)(b*L_+j)*64 + d];
  meanbf[(size_t)gs*64 + d] = f2bf(acc / (float)(j1 - j0));
}

// ---------------- save row0 of xg for ns==1 path ----------------
__global__ __launch_bounds__(128) void row0_kernel(
    const float* __restrict__ xg, float* __restrict__ semb0)
{
  semb0[blockIdx.x*128 + threadIdx.x] = xg[(size_t)blockIdx.x*L_*128 + threadIdx.x];
}

// ---------------- final pooling phase A ----------------
__global__ __launch_bounds__(128) void pool_final_kernel(
    const float* __restrict__ g, const int* __restrict__ n_seg,
    float* __restrict__ partial)
{
  const int b = blockIdx.x >> 4, c = blockIdx.x & 15;
  const int d = (int)threadIdx.x;
  const int ns = n_seg[b];
  const int i0 = c*64, i1 = min(ns, i0 + 64);
  float acc = 0.f;
  for (int i = i0; i < i1; ++i) acc += g[(size_t)(b*L_+i)*128 + d];
  partial[(size_t)blockIdx.x*128 + d] = acc;
}

// ---------------- final phase B ----------------
__global__ __launch_bounds__(128) void final_kernel(
    const float* __restrict__ partial, const float* __restrict__ semb0,
    const int* __restrict__ n_seg, const float* __restrict__ fin_w,
    const float* __restrict__ fin_b, float* __restrict__ out)
{
  const int b = blockIdx.x, d = threadIdx.x;
  const int ns = n_seg[b];
  __shared__ float pl[128];
  float pooled;
  if (ns == 1) pooled = semb0[b*128 + d];
  else {
    float acc = 0.f;
#pragma unroll
    for (int c = 0; c < 16; ++c) acc += partial[(size_t)(b*16 + c)*128 + d];
    pooled = acc / (float)ns;
  }
  pl[d] = pooled;
  __syncthreads();
  float o = fin_b[d];
#pragma unroll 8
  for (int k2 = 0; k2 < 128; ++k2) o = fmaf(pl[k2], fin_w[k2*128+d], o);
  out[b*128+d] = o;
}

extern "C" void kernel_launch(void* const* d_in, const int* in_sizes, int n_in,
                              void* d_out, int out_size, void* d_ws, size_t ws_size,
                              hipStream_t stream) {
  const float* pts     = (const float*)d_in[0];
  const float* fs      = (const float*)d_in[1];
  const float* ft      = (const float*)d_in[2];
  const float* w_space = (const float*)d_in[3];
  const float* b_space = (const float*)d_in[4];
  const float* w_time  = (const float*)d_in[5];
  const float* b_time  = (const float*)d_in[6];
  const float* w_fout  = (const float*)d_in[7];
  const float* b_fout  = (const float*)d_in[8];
  const float* w_gate  = (const float*)d_in[9];
  const float* b_gate  = (const float*)d_in[10];
  const float* seg_attn_w = (const float*)d_in[11];
  const float* seg_attn_b = (const float*)d_in[12];
  const float* seg_ln_g   = (const float*)d_in[13];
  const float* seg_ln_b   = (const float*)d_in[14];
  const float* seg_ff1_w  = (const float*)d_in[15];
  const float* seg_ff1_b  = (const float*)d_in[16];
  const float* seg_ff2_w  = (const float*)d_in[17];
  const float* seg_ff2_b  = (const float*)d_in[18];
  const float* glb_attn_w = (const float*)d_in[19];
  const float* glb_attn_b = (const float*)d_in[20];
  const float* glb_ln_g   = (const float*)d_in[21];
  const float* glb_ln_b   = (const float*)d_in[22];
  const float* glb_ff1_w  = (const float*)d_in[23];
  const float* glb_ff1_b  = (const float*)d_in[24];
  const float* glb_ff2_w  = (const float*)d_in[25];
  const float* glb_ff2_b  = (const float*)d_in[26];
  const float* up_w    = (const float*)d_in[27];
  const float* up_b    = (const float*)d_in[28];
  const float* fin_w   = (const float*)d_in[29];
  const float* fin_b   = (const float*)d_in[30];

  char* ws = (char*)d_ws;
  float* zx   = (float*)(ws);
  unsigned short* xg_bf = (unsigned short*)(ws);
  float* qkv  = (float*)(ws + ((size_t)4  << 20));
  unsigned short* qkv_bf = (unsigned short*)(ws + ((size_t)4 << 20));
  float* tmp  = qkv;
  float* aob  = (float*)(ws + ((size_t)30 << 20));
  float* xg   = (float*)(ws + ((size_t)38 << 20));
  unsigned short* zx_bf = (unsigned short*)(ws + ((size_t)38 << 20));
  int* boundary  = (int*)(ws + ((size_t)46 << 20));
  int* seg_id    = boundary + M_TOT;
  int* seg_start = seg_id + M_TOT;
  int* n_seg     = seg_start + B_*(L_+1);
  float* semb0     = (float*)(ws + ((size_t)47 << 20));
  float* partial   = (float*)(ws + ((size_t)47 << 20) + 65536);
  unsigned short* tmp_bf = (unsigned short*)(ws + ((size_t)50 << 20));
  unsigned short* vfrag  = (unsigned short*)(ws + ((size_t)58 << 20));
  unsigned short* abf    = (unsigned short*)(ws + ((size_t)84 << 20));
  unsigned short* wpk    = (unsigned short*)(ws + ((size_t)88 << 20));

  unsigned short* wpk_segA  = wpk;
  unsigned short* wpk_segF1 = wpk + 32768;
  unsigned short* wpk_segF2 = wpk + 49152;
  unsigned short* wpk_glbA  = wpk + 65536;
  unsigned short* wpk_glbF1 = wpk + 196608;
  unsigned short* wpk_glbF2 = wpk + 262144;
  unsigned short* wpk_up    = wpk + 327680;

  pack_all_kernel<<<164, 256, 0, stream>>>(seg_attn_w, seg_ff1_w, seg_ff2_w,
                                           glb_attn_w, glb_ff1_w, glb_ff2_w, up_w, wpk);

  featurize_kernel<<<M_TOT/4, 256, 0, stream>>>(pts, fs, ft, w_space, b_space, w_time, b_time,
                                                w_fout, b_fout, w_gate, b_gate, zx, zx_bf, boundary);
  scan_kernel<<<B_, 1024, 0, stream>>>(boundary, seg_id, seg_start, n_seg);

  // ---- segment-level encoder (D=64, H=2, FF=128) ----
  for (int l = 0; l < 2; ++l) {
    const float* ab = seg_attn_b + (size_t)l*4*64;
    mgemm_kernel<64,64,3,false,false,true,false><<<dim3(256,3),256,0,stream>>>(
        zx_bf, wpk_segA + (size_t)l*4*4096, ab, qkv, nullptr, nullptr);
    seg_attn_kernel<<<(M_TOT*2*8)/256, 256, 0, stream>>>(qkv, seg_id, seg_start, abf);
    mgemm_kernel<64,64,1,false,false,true,false><<<dim3(256,1),256,0,stream>>>(
        abf, wpk_segA + (size_t)(l*4+3)*4096, ab + 192, tmp, nullptr, nullptr);
    ln64_kernel<<<M_TOT/4, 256, 0, stream>>>(zx, tmp, seg_ln_g + l*128, seg_ln_b + l*128, zx_bf);
    mgemm_kernel<64,128,1,true,false,false,true><<<dim3(256,2),256,0,stream>>>(
        zx_bf, wpk_segF1 + (size_t)l*8192, seg_ff1_b + l*128, nullptr, tmp_bf, nullptr);
    mgemm_kernel<128,64,1,false,false,true,false><<<dim3(256,1),256,0,stream>>>(
        tmp_bf, wpk_segF2 + (size_t)l*8192, seg_ff2_b + l*64, aob, nullptr, nullptr);
    ln64_kernel<<<M_TOT/4, 256, 0, stream>>>(zx, aob, seg_ln_g + l*128 + 64, seg_ln_b + l*128 + 64, zx_bf);
  }

  // ---- pooling + up-projection (gated) ----
  pool_kernel<<<M_TOT/4, 256, 0, stream>>>(zx, seg_start, n_seg, abf);
  mgemm_kernel<64,128,1,false,true,true,true><<<dim3(256,2),256,0,stream>>>(
      abf, wpk_up, up_b, xg, xg_bf, n_seg);
  row0_kernel<<<B_, 128, 0, stream>>>(xg, semb0);

  // ---- global-level encoder (D=128, H=4, FF=256), row-gated ----
  for (int l = 0; l < 2; ++l) {
    const float* ab = glb_attn_b + (size_t)l*4*128;
    mgemm_kernel<128,128,3,false,true,false,true,0><<<dim3(256,6),256,0,stream>>>(
        xg_bf, wpk_glbA + (size_t)l*4*16384, ab, nullptr, qkv_bf, n_seg);
    vpack_kernel<<<1024, 256, 0, stream>>>(qkv_bf, vfrag);
    glb_attn_mfma_kernel<<<B_*4*16, 256, 0, stream>>>(qkv_bf, vfrag, n_seg, abf);
    mgemm_kernel<128,128,1,false,true,true,false><<<dim3(256,2),256,0,stream>>>(
        abf, wpk_glbA + (size_t)(l*4+3)*16384, ab + 384, tmp, nullptr, n_seg);
    ln128_kernel<<<M_TOT/2, 256, 0, stream>>>(xg, tmp, glb_ln_g + l*256, glb_ln_b + l*256, n_seg, xg_bf);
    mgemm_kernel<128,256,1,true,true,false,true><<<dim3(256,4),256,0,stream>>>(
        xg_bf, wpk_glbF1 + (size_t)l*32768, glb_ff1_b + l*256, nullptr, tmp_bf, n_seg);
    mgemm_kernel<256,128,1,false,true,true,false><<<dim3(256,2),256,0,stream>>>(
        tmp_bf, wpk_glbF2 + (size_t)l*32768, glb_ff2_b + l*128, aob, nullptr, n_seg);
    ln128_kernel<<<M_TOT/2, 256, 0, stream>>>(xg, aob, glb_ln_g + l*256 + 128, glb_ln_b + l*256 + 128, n_seg, xg_bf);
  }

  pool_final_kernel<<<B_*16, 128, 0, stream>>>(xg, n_seg, partial);
  final_kernel<<<B_, 128, 0, stream>>>(partial, semb0, n_seg, fin_w, fin_b, (float*)d_out);
}

// Round 9
// 300.498 us; speedup vs baseline: 4.5882x; 1.0485x over previous
//
#include <hip/hip_runtime.h>
#include <math.h>

#define B_ 16
#define L_ 1024
#define M_TOT (B_*L_)   // 16384

typedef __attribute__((ext_vector_type(8))) short short8v;  // 8 bf16 (4 VGPRs)
typedef __attribute__((ext_vector_type(4))) float f32x4;

__device__ __forceinline__ float wave_reduce_sum(float v) {
#pragma unroll
  for (int o = 32; o >= 1; o >>= 1) v += __shfl_xor(v, o, 64);
  return v;
}

__device__ __forceinline__ unsigned short f2bf(float f) {
  union { float f; unsigned u; } v; v.f = f;
  unsigned r = v.u + 0x7FFFu + ((v.u >> 16) & 1u);
  return (unsigned short)(r >> 16);
}

// ---------------- fused weight pack: fp32 [nmat][K][N] -> MFMA B-frag bf16 ----
__global__ __launch_bounds__(256) void pack_all_kernel(
    const float* __restrict__ s0, const float* __restrict__ s1,
    const float* __restrict__ s2, const float* __restrict__ s3,
    const float* __restrict__ s4, const float* __restrict__ s5,
    const float* __restrict__ s6, unsigned short* __restrict__ wpk)
{
  int idx = blockIdx.x*256 + (int)threadIdx.x;
  const float* src; unsigned short* dst; int K, N;
  if      (idx <  4096) { src=s0; dst=wpk;          K=64;  N=64;  }
  else if (idx <  6144) { src=s1; dst=wpk+32768;    K=64;  N=128; idx-=4096; }
  else if (idx <  8192) { src=s2; dst=wpk+49152;    K=128; N=64;  idx-=6144; }
  else if (idx < 24576) { src=s3; dst=wpk+65536;    K=128; N=128; idx-=8192; }
  else if (idx < 32768) { src=s4; dst=wpk+196608;   K=128; N=256; idx-=24576; }
  else if (idx < 40960) { src=s5; dst=wpk+262144;   K=256; N=128; idx-=32768; }
  else if (idx < 41984) { src=s6; dst=wpk+327680;   K=64;  N=128; idx-=40960; }
  else return;
  const int l = idx & 63;
  int f = idx >> 6;
  const int ntn = N >> 4;
  const int nt = f % ntn; f /= ntn;
  const int ktn = K >> 5;
  const int kt = f % ktn;
  const int m  = f / ktn;
  const float* s = src + (size_t)m*K*N + (size_t)(kt*32 + ((l>>4)<<3))*N + nt*16 + (l&15);
  unsigned pw[4];
#pragma unroll
  for (int jj = 0; jj < 4; ++jj)
    pw[jj] = (unsigned)f2bf(s[(size_t)(2*jj)*N]) | ((unsigned)f2bf(s[(size_t)(2*jj+1)*N]) << 16);
  uint4 u; u.x = pw[0]; u.y = pw[1]; u.z = pw[2]; u.w = pw[3];
  *reinterpret_cast<uint4*>(dst + (size_t)idx*8) = u;
}

// ---------------- MFMA GEMM: C = act(A[M,K] @ W[K,PN per part] + bias) --------
template<int K, int PN, int NPARTS, bool RELU, bool GATED, bool WF32, bool WBF, int SPART = -1>
__global__ __launch_bounds__(256) void mgemm_kernel(
    const unsigned short* __restrict__ Abf,
    const unsigned short* __restrict__ Wpk,
    const float* __restrict__ bias,
    float* __restrict__ C, unsigned short* __restrict__ Cbf,
    const int* __restrict__ nseg)
{
  constexpr int NOUT = NPARTS*PN;
  constexpr int KT = K/32;
  constexpr int NTP = PN/16;
  constexpr int CPP = PN/64;
  const int row0 = blockIdx.x * 64;
  if (GATED) { const int b = row0 >> 10; if ((row0 & (L_-1)) >= nseg[b]) return; }
  const int ct = blockIdx.y;
  const int part = ct / CPP;
  const int nt0  = (ct % CPP) * 4;
  const int wv = (int)threadIdx.x >> 6;
  const int ln = (int)threadIdx.x & 63;
  const int rbase = row0 + wv*16;
  const unsigned short* aptr = Abf + (size_t)(rbase + (ln & 15))*K + ((ln >> 4) << 3);
  const unsigned short* bptr = Wpk + ((size_t)part*KT*NTP + nt0)*512 + (size_t)ln*8;
  f32x4 acc0 = {0.f,0.f,0.f,0.f}, acc1 = {0.f,0.f,0.f,0.f};
  f32x4 acc2 = {0.f,0.f,0.f,0.f}, acc3 = {0.f,0.f,0.f,0.f};
#pragma unroll
  for (int kt = 0; kt < KT; ++kt) {
    short8v a = *reinterpret_cast<const short8v*>(aptr + kt*32);
    const unsigned short* bk = bptr + (size_t)kt*NTP*512;
    short8v b0 = *reinterpret_cast<const short8v*>(bk);
    short8v b1 = *reinterpret_cast<const short8v*>(bk + 512);
    short8v b2 = *reinterpret_cast<const short8v*>(bk + 1024);
    short8v b3 = *reinterpret_cast<const short8v*>(bk + 1536);
    acc0 = __builtin_amdgcn_mfma_f32_16x16x32_bf16(a, b0, acc0, 0, 0, 0);
    acc1 = __builtin_amdgcn_mfma_f32_16x16x32_bf16(a, b1, acc1, 0, 0, 0);
    acc2 = __builtin_amdgcn_mfma_f32_16x16x32_bf16(a, b2, acc2, 0, 0, 0);
    acc3 = __builtin_amdgcn_mfma_f32_16x16x32_bf16(a, b3, acc3, 0, 0, 0);
  }
  const int colb = part*PN + nt0*16 + (ln & 15);
  const int rowe = rbase + ((ln >> 4) << 2);
  f32x4 av[4] = {acc0, acc1, acc2, acc3};
#pragma unroll
  for (int i = 0; i < 4; ++i) {
    const int col = colb + i*16;
    const float bs = bias[col];
#pragma unroll
    for (int r = 0; r < 4; ++r) {
      float v = av[i][r] + bs;
      if (SPART >= 0) { if (part == SPART) v *= 0.25506972533f; }  // 1/sqrt(32)*log2e
      if (RELU) v = fmaxf(v, 0.f);
      if (WF32) C[(size_t)(rowe + r)*NOUT + col] = v;
      if (WBF)  Cbf[(size_t)(rowe + r)*NOUT + col] = f2bf(v);
    }
  }
}

// ---------------- MFMA GEMM + residual + LayerNorm fused (D=64 rows) ----------
// PN=64, NPARTS=1: each wave owns full 64-wide rows -> LN via 16-lane shfl.
template<int K>
__global__ __launch_bounds__(256) void mgemm_ln64_kernel(
    const unsigned short* __restrict__ Abf,
    const unsigned short* __restrict__ Wpk,
    const float* __restrict__ bias,
    float* __restrict__ x,                 // residual in, fp32 out (in-place)
    const float* __restrict__ gam, const float* __restrict__ bet,
    unsigned short* __restrict__ xbf)
{
  constexpr int KT = K/32;
  const int row0 = blockIdx.x * 64;
  const int wv = (int)threadIdx.x >> 6;
  const int ln = (int)threadIdx.x & 63;
  const int rbase = row0 + wv*16;
  const unsigned short* aptr = Abf + (size_t)(rbase + (ln & 15))*K + ((ln >> 4) << 3);
  const unsigned short* bptr = Wpk + (size_t)ln*8;
  f32x4 acc0 = {0.f,0.f,0.f,0.f}, acc1 = {0.f,0.f,0.f,0.f};
  f32x4 acc2 = {0.f,0.f,0.f,0.f}, acc3 = {0.f,0.f,0.f,0.f};
#pragma unroll
  for (int kt = 0; kt < KT; ++kt) {
    short8v a = *reinterpret_cast<const short8v*>(aptr + kt*32);
    const unsigned short* bk = bptr + (size_t)kt*4*512;
    short8v b0 = *reinterpret_cast<const short8v*>(bk);
    short8v b1 = *reinterpret_cast<const short8v*>(bk + 512);
    short8v b2 = *reinterpret_cast<const short8v*>(bk + 1024);
    short8v b3 = *reinterpret_cast<const short8v*>(bk + 1536);
    acc0 = __builtin_amdgcn_mfma_f32_16x16x32_bf16(a, b0, acc0, 0, 0, 0);
    acc1 = __builtin_amdgcn_mfma_f32_16x16x32_bf16(a, b1, acc1, 0, 0, 0);
    acc2 = __builtin_amdgcn_mfma_f32_16x16x32_bf16(a, b2, acc2, 0, 0, 0);
    acc3 = __builtin_amdgcn_mfma_f32_16x16x32_bf16(a, b3, acc3, 0, 0, 0);
  }
  const int colc = ln & 15;
  const int rowe = rbase + ((ln >> 4) << 2);
  f32x4 av[4] = {acc0, acc1, acc2, acc3};
  float v[4][4];
#pragma unroll
  for (int i = 0; i < 4; ++i) {
    const int col = i*16 + colc;
    const float bs = bias[col];
#pragma unroll
    for (int r = 0; r < 4; ++r)
      v[i][r] = av[i][r] + bs + x[(size_t)(rowe + r)*64 + col];
  }
  float rs[4];
#pragma unroll
  for (int r = 0; r < 4; ++r) rs[r] = v[0][r]+v[1][r]+v[2][r]+v[3][r];
#pragma unroll
  for (int m = 1; m <= 8; m <<= 1)
#pragma unroll
    for (int r = 0; r < 4; ++r) rs[r] += __shfl_xor(rs[r], m, 64);
  float mean[4], vs[4];
#pragma unroll
  for (int r = 0; r < 4; ++r) { mean[r] = rs[r]*(1.0f/64.0f); vs[r] = 0.f; }
#pragma unroll
  for (int i = 0; i < 4; ++i)
#pragma unroll
    for (int r = 0; r < 4; ++r) { const float d = v[i][r]-mean[r]; vs[r] = fmaf(d, d, vs[r]); }
#pragma unroll
  for (int m = 1; m <= 8; m <<= 1)
#pragma unroll
    for (int r = 0; r < 4; ++r) vs[r] += __shfl_xor(vs[r], m, 64);
  float rstd[4];
#pragma unroll
  for (int r = 0; r < 4; ++r) rstd[r] = rsqrtf(vs[r]*(1.0f/64.0f) + 1e-5f);
#pragma unroll
  for (int i = 0; i < 4; ++i) {
    const int col = i*16 + colc;
    const float g = gam[col], bb = bet[col];
#pragma unroll
    for (int r = 0; r < 4; ++r) {
      const float out = (v[i][r]-mean[r])*rstd[r]*g + bb;
      x[(size_t)(rowe + r)*64 + col] = out;
      xbf[(size_t)(rowe + r)*64 + col] = f2bf(out);
    }
  }
}

// ---------------- featurize: 4 points per 256-thr block (dual-write) ----------
__global__ __launch_bounds__(256) void featurize_kernel(
    const float* __restrict__ pts, const float* __restrict__ fs, const float* __restrict__ ft,
    const float* __restrict__ w_space, const float* __restrict__ b_space,
    const float* __restrict__ w_time, const float* __restrict__ b_time,
    const float* __restrict__ w_fout, const float* __restrict__ b_fout,
    const float* __restrict__ w_gate, const float* __restrict__ b_gate,
    float* __restrict__ z, unsigned short* __restrict__ zbf, int* __restrict__ boundary)
{
  const int sub = threadIdx.x >> 6;
  const int d   = threadIdx.x & 63;
  const int p   = blockIdx.x * 4 + sub;
  const float TWO_PI = 6.283185307179586f;
  __shared__ float feat[4][32];
  __shared__ float tfeat[4][16];
  __shared__ float g96[4][96];
  const float x = pts[p*3+0], y = pts[p*3+1], t = pts[p*3+2];
  if (d < 16) {
    float sp = (x*fs[d] + y*fs[16+d]) * TWO_PI;
    feat[sub][d]    = sinf(sp);
    feat[sub][16+d] = cosf(sp);
  } else if (d < 24) {
    int r = d - 16;
    float tp = t * ft[r] * TWO_PI;
    tfeat[sub][r]   = sinf(tp);
    tfeat[sub][8+r] = cosf(tp);
  }
  __syncthreads();
  float sf = b_space[d];
#pragma unroll
  for (int k2 = 0; k2 < 32; ++k2) sf = fmaf(feat[sub][k2], w_space[k2*64+d], sf);
  g96[sub][d] = sf;
  if (d < 32) {
    float tf = b_time[d];
#pragma unroll
    for (int k2 = 0; k2 < 16; ++k2) tf = fmaf(tfeat[sub][k2], w_time[k2*32+d], tf);
    g96[sub][64+d] = tf;
  }
  __syncthreads();
  float zv = b_fout[d];
#pragma unroll
  for (int k2 = 0; k2 < 96; ++k2) zv = fmaf(g96[sub][k2], w_fout[k2*64+d], zv);
  z[(size_t)p*64+d] = zv;
  zbf[(size_t)p*64+d] = f2bf(zv);
  float gv = wave_reduce_sum(zv * w_gate[d]);
  if (d == 0) {
    float logit = gv + b_gate[0];
    float gate = 1.0f / (1.0f + expf(-logit));
    int bnd = (gate > 0.5f) ? 1 : 0;
    if ((p & (L_-1)) == 0) bnd = 1;
    boundary[p] = bnd;
  }
}

// ---------------- scan: seg_id, seg_start, n_seg ----------------
__global__ __launch_bounds__(1024) void scan_kernel(const int* __restrict__ boundary,
    int* __restrict__ seg_id, int* __restrict__ seg_start, int* __restrict__ n_seg)
{
  __shared__ int sc[1024];
  const int b = blockIdx.x, l = threadIdx.x;
  const int v = boundary[b*L_ + l];
  sc[l] = v;
  __syncthreads();
  for (int off = 1; off < 1024; off <<= 1) {
    int add = (l >= off) ? sc[l - off] : 0;
    __syncthreads();
    sc[l] += add;
    __syncthreads();
  }
  const int sid = sc[l] - 1;
  seg_id[b*L_ + l] = sid;
  if (v) seg_start[b*(L_+1) + sid] = l;
  if (l == L_-1) {
    n_seg[b] = sid + 1;
    seg_start[b*(L_+1) + sid + 1] = L_;
  }
}

// ---------------- segment attention: 8 lanes per (pt,h) item -------------------
__global__ __launch_bounds__(256) void seg_attn_kernel(
    const float* __restrict__ qkv,
    const int* __restrict__ seg_id, const int* __restrict__ seg_start,
    unsigned short* __restrict__ aobf)
{
  const int gid = blockIdx.x * 256 + (int)threadIdx.x;  // item*8 + sub
  const int sub = gid & 7;
  const int item = gid >> 3;        // ((b*L + pt)*2 + h)
  const int h  = item & 1;
  const int pt = (item >> 1) & (L_-1);
  const int b  = item >> 11;
  const float scale = 0.17677669529663687f;
  float4 q4 = *reinterpret_cast<const float4*>(qkv + (size_t)(b*L_+pt)*192 + h*32 + sub*4);
  q4.x*=scale; q4.y*=scale; q4.z*=scale; q4.w*=scale;
  const int s  = seg_id[b*L_ + pt];
  const int j0 = seg_start[b*(L_+1) + s];
  const int j1 = seg_start[b*(L_+1) + s + 1];
  float lsum = 0.f;
  float4 acc = {0.f,0.f,0.f,0.f};
  for (int j = j0; j < j1; ++j) {
    const float* base = qkv + (size_t)(b*L_ + j)*192 + h*32 + sub*4;
    float4 k4 = *reinterpret_cast<const float4*>(base + 64);
    float4 v4 = *reinterpret_cast<const float4*>(base + 128);
    float dot = q4.x*k4.x;
    dot = fmaf(q4.y, k4.y, dot);
    dot = fmaf(q4.z, k4.z, dot);
    dot = fmaf(q4.w, k4.w, dot);
    dot += __shfl_xor(dot, 1, 64);
    dot += __shfl_xor(dot, 2, 64);
    dot += __shfl_xor(dot, 4, 64);
    const float p = __expf(fminf(dot, 30.f));
    lsum += p;
    acc.x = fmaf(p, v4.x, acc.x);
    acc.y = fmaf(p, v4.y, acc.y);
    acc.z = fmaf(p, v4.z, acc.z);
    acc.w = fmaf(p, v4.w, acc.w);
  }
  const float inv = 1.0f / lsum;
  unsigned* op = reinterpret_cast<unsigned*>(aobf + (size_t)(b*L_+pt)*64 + h*32 + sub*4);
  op[0] = (unsigned)f2bf(acc.x*inv) | ((unsigned)f2bf(acc.y*inv) << 16);
  op[1] = (unsigned)f2bf(acc.z*inv) | ((unsigned)f2bf(acc.w*inv) << 16);
}

// ---------------- V fragment pack for MFMA attention -------------------------
__global__ __launch_bounds__(256) void vpack_kernel(
    const unsigned short* __restrict__ qkvbf, unsigned short* __restrict__ vfrag)
{
  const int idx = blockIdx.x*256 + (int)threadIdx.x;
  const int lane = idx & 63;
  const int dt = (idx >> 6) & 1;
  const int c  = (idx >> 7) & 31;
  const int h  = (idx >> 12) & 3;
  const int b  = idx >> 14;
  const int g = lane >> 4;
  const int dcol = lane & 15;
  unsigned short vals[8];
#pragma unroll
  for (int j = 0; j < 8; ++j) {
    const int key = c*32 + g*4 + (j & 3) + ((j >> 2) << 4);
    vals[j] = qkvbf[(size_t)(b*L_ + key)*384 + 256 + h*32 + dt*16 + dcol];
  }
  uint4 u;
  u.x = (unsigned)vals[0] | ((unsigned)vals[1] << 16);
  u.y = (unsigned)vals[2] | ((unsigned)vals[3] << 16);
  u.z = (unsigned)vals[4] | ((unsigned)vals[5] << 16);
  u.w = (unsigned)vals[6] | ((unsigned)vals[7] << 16);
  *reinterpret_cast<uint4*>(vfrag + (size_t)idx*8) = u;
}

// ---------------- global attention via MFMA (XCD-swizzled grid) ----------------
// launch: blockIdx.x = qt*64 + (b*4+h)  -> all 16 qt blocks of one (b,h) land on
// the same XCD (idx % 8 == (b*4+h) % 8), so K/V are fetched once per XCD L2.
__global__ __launch_bounds__(256) void glb_attn_mfma_kernel(
    const unsigned short* __restrict__ qkvbf,   // [16384][384] bf16
    const unsigned short* __restrict__ vfrag,
    const int* __restrict__ n_seg,
    unsigned short* __restrict__ aobf)          // [16384][128] bf16
{
  const int g64 = blockIdx.x & 63;    // (b*4 + h)
  const int qt  = blockIdx.x >> 6;
  const int h  = g64 & 3;
  const int b  = g64 >> 2;
  const int ns = n_seg[b];
  if (qt*64 >= ns) return;
  const int wv = (int)threadIdx.x >> 6;
  const int ln = (int)threadIdx.x & 63;
  const int g  = ln >> 4;
  const int qc = ln & 15;
  __shared__ float lsumS[4][16];

  const int q0 = qt*64 + wv*16;
  const short8v qf = *reinterpret_cast<const short8v*>(
      qkvbf + (size_t)(b*L_ + q0 + qc)*384 + h*32 + g*8);

  f32x4 O0 = {0.f,0.f,0.f,0.f}, O1 = {0.f,0.f,0.f,0.f};
  const f32x4 zz = {0.f,0.f,0.f,0.f};
  float lsum = 0.f;
  const int nchunk = (ns + 31) >> 5;
  const unsigned short* kp = qkvbf + (size_t)(b*L_)*384 + 128 + h*32 + g*8;
  const unsigned short* vfb = vfrag + (size_t)((b*4 + h)*32)*1024 + (size_t)ln*8;

  short8v kf0c = *reinterpret_cast<const short8v*>(kp + (size_t)qc*384);
  short8v kf1c = *reinterpret_cast<const short8v*>(kp + (size_t)(16 + qc)*384);
  short8v v0c  = *reinterpret_cast<const short8v*>(vfb);
  short8v v1c  = *reinterpret_cast<const short8v*>(vfb + 512);

  for (int c = 0; c < nchunk; ++c) {
    const int cn = (c + 1 < nchunk) ? c + 1 : c;
    short8v kf0n = *reinterpret_cast<const short8v*>(kp + (size_t)(cn*32 + qc)*384);
    short8v kf1n = *reinterpret_cast<const short8v*>(kp + (size_t)(cn*32 + 16 + qc)*384);
    short8v v0n  = *reinterpret_cast<const short8v*>(vfb + (size_t)cn*1024);
    short8v v1n  = *reinterpret_cast<const short8v*>(vfb + (size_t)cn*1024 + 512);

    f32x4 s0 = __builtin_amdgcn_mfma_f32_16x16x32_bf16(kf0c, qf, zz, 0, 0, 0);
    f32x4 s1 = __builtin_amdgcn_mfma_f32_16x16x32_bf16(kf1c, qf, zz, 0, 0, 0);
    const int k0 = c*32;
    float p[8];
#pragma unroll
    for (int r = 0; r < 4; ++r) {
      const int key0 = k0 + g*4 + r;
      const float e0 = (key0 < ns)      ? exp2f(fminf(s0[r], 43.f)) : 0.f;
      const float e1 = (key0 + 16 < ns) ? exp2f(fminf(s1[r], 43.f)) : 0.f;
      p[r] = e0; p[4+r] = e1;
      lsum += e0 + e1;
    }
    short8v pf;
#pragma unroll
    for (int i = 0; i < 8; ++i) pf[i] = (short)f2bf(p[i]);
    O0 = __builtin_amdgcn_mfma_f32_16x16x32_bf16(pf, v0c, O0, 0, 0, 0);
    O1 = __builtin_amdgcn_mfma_f32_16x16x32_bf16(pf, v1c, O1, 0, 0, 0);
    kf0c = kf0n; kf1c = kf1n; v0c = v0n; v1c = v1n;
  }
  lsum += __shfl_xor(lsum, 16, 64);
  lsum += __shfl_xor(lsum, 32, 64);
  if (ln < 16) lsumS[wv][ln] = lsum;
  __syncthreads();
  unsigned short* outp = aobf + (size_t)(b*L_ + q0 + g*4)*128 + h*32 + qc;
#pragma unroll
  for (int r = 0; r < 4; ++r) {
    const float inv = 1.0f / lsumS[wv][g*4 + r];
    outp[(size_t)r*128]      = f2bf(O0[r]*inv);
    outp[(size_t)r*128 + 16] = f2bf(O1[r]*inv);
  }
}

// ---------------- LN(x+r) D=128 gated: dual-write ----------------
__global__ __launch_bounds__(256) void ln128_kernel(
    float* __restrict__ x, const float* __restrict__ r,
    const float* __restrict__ gam, const float* __restrict__ bet,
    const int* __restrict__ nseg, unsigned short* __restrict__ xbf)
{
  const int row0 = blockIdx.x*2;
  const int b = row0 >> 10;
  if ((row0 & (L_-1)) >= nseg[b]) return;
  const int sub = (int)threadIdx.x >> 7;
  const int d   = (int)threadIdx.x & 127;
  const int row = row0 + sub;
  const bool valid = (row & (L_-1)) < nseg[b];
  __shared__ float red[2][4];
  float val = 0.f;
  if (valid) val = x[(size_t)row*128 + d] + r[(size_t)row*128 + d];
  float s = wave_reduce_sum(val);
  if ((d & 63) == 0) red[sub][d >> 6] = s;
  __syncthreads();
  s = red[sub][0] + red[sub][1];
  const float mean = s * (1.0f/128.0f);
  const float dv = val - mean;
  float s2 = wave_reduce_sum(dv*dv);
  if ((d & 63) == 0) red[sub][2 + (d >> 6)] = s2;
  __syncthreads();
  s2 = red[sub][2] + red[sub][3];
  if (valid) {
    const float out = dv * rsqrtf(s2*(1.0f/128.0f) + 1e-5f) * gam[d] + bet[d];
    x[(size_t)row*128 + d] = out;
    xbf[(size_t)row*128 + d] = f2bf(out);
  }
}

// ---------------- segment mean pooling -> bf16 [row][64] ----------------
__global__ __launch_bounds__(256) void pool_kernel(
    const float* __restrict__ h, const int* __restrict__ seg_start,
    const int* __restrict__ n_seg, unsigned short* __restrict__ meanbf)
{
  const int gs = blockIdx.x*4 + ((int)threadIdx.x >> 6);
  const int b = gs >> 10, s = gs & (L_-1);
  const int d = (int)threadIdx.x & 63;
  if (s >= n_seg[b]) return;
  const int j0 = seg_start[b*(L_+1)+s], j1 = seg_start[b*(L_+1)+s+1];
  float acc = 0.f;
  for (int j = j0; j < j1; ++j) acc += h[(size_t)(b*L_+j)*64 + d];
  meanbf[(size_t)gs*64 + d] = f2bf(acc / (float)(j1 - j0));
}

// ---------------- save row0 of xg for ns==1 path ----------------
__global__ __launch_bounds__(128) void row0_kernel(
    const float* __restrict__ xg, float* __restrict__ semb0)
{
  semb0[blockIdx.x*128 + threadIdx.x] = xg[(size_t)blockIdx.x*L_*128 + threadIdx.x];
}

// ---------------- final pooling phase A ----------------
__global__ __launch_bounds__(128) void pool_final_kernel(
    const float* __restrict__ g, const int* __restrict__ n_seg,
    float* __restrict__ partial)
{
  const int b = blockIdx.x >> 4, c = blockIdx.x & 15;
  const int d = (int)threadIdx.x;
  const int ns = n_seg[b];
  const int i0 = c*64, i1 = min(ns, i0 + 64);
  float acc = 0.f;
  for (int i = i0; i < i1; ++i) acc += g[(size_t)(b*L_+i)*128 + d];
  partial[(size_t)blockIdx.x*128 + d] = acc;
}

// ---------------- final phase B ----------------
__global__ __launch_bounds__(128) void final_kernel(
    const float* __restrict__ partial, const float* __restrict__ semb0,
    const int* __restrict__ n_seg, const float* __restrict__ fin_w,
    const float* __restrict__ fin_b, float* __restrict__ out)
{
  const int b = blockIdx.x, d = threadIdx.x;
  const int ns = n_seg[b];
  __shared__ float pl[128];
  float pooled;
  if (ns == 1) pooled = semb0[b*128 + d];
  else {
    float acc = 0.f;
#pragma unroll
    for (int c = 0; c < 16; ++c) acc += partial[(size_t)(b*16 + c)*128 + d];
    pooled = acc / (float)ns;
  }
  pl[d] = pooled;
  __syncthreads();
  float o = fin_b[d];
#pragma unroll 8
  for (int k2 = 0; k2 < 128; ++k2) o = fmaf(pl[k2], fin_w[k2*128+d], o);
  out[b*128+d] = o;
}

extern "C" void kernel_launch(void* const* d_in, const int* in_sizes, int n_in,
                              void* d_out, int out_size, void* d_ws, size_t ws_size,
                              hipStream_t stream) {
  const float* pts     = (const float*)d_in[0];
  const float* fs      = (const float*)d_in[1];
  const float* ft      = (const float*)d_in[2];
  const float* w_space = (const float*)d_in[3];
  const float* b_space = (const float*)d_in[4];
  const float* w_time  = (const float*)d_in[5];
  const float* b_time  = (const float*)d_in[6];
  const float* w_fout  = (const float*)d_in[7];
  const float* b_fout  = (const float*)d_in[8];
  const float* w_gate  = (const float*)d_in[9];
  const float* b_gate  = (const float*)d_in[10];
  const float* seg_attn_w = (const float*)d_in[11];
  const float* seg_attn_b = (const float*)d_in[12];
  const float* seg_ln_g   = (const float*)d_in[13];
  const float* seg_ln_b   = (const float*)d_in[14];
  const float* seg_ff1_w  = (const float*)d_in[15];
  const float* seg_ff1_b  = (const float*)d_in[16];
  const float* seg_ff2_w  = (const float*)d_in[17];
  const float* seg_ff2_b  = (const float*)d_in[18];
  const float* glb_attn_w = (const float*)d_in[19];
  const float* glb_attn_b = (const float*)d_in[20];
  const float* glb_ln_g   = (const float*)d_in[21];
  const float* glb_ln_b   = (const float*)d_in[22];
  const float* glb_ff1_w  = (const float*)d_in[23];
  const float* glb_ff1_b  = (const float*)d_in[24];
  const float* glb_ff2_w  = (const float*)d_in[25];
  const float* glb_ff2_b  = (const float*)d_in[26];
  const float* up_w    = (const float*)d_in[27];
  const float* up_b    = (const float*)d_in[28];
  const float* fin_w   = (const float*)d_in[29];
  const float* fin_b   = (const float*)d_in[30];

  char* ws = (char*)d_ws;
  float* zx   = (float*)(ws);
  unsigned short* xg_bf = (unsigned short*)(ws);
  float* qkv  = (float*)(ws + ((size_t)4  << 20));
  unsigned short* qkv_bf = (unsigned short*)(ws + ((size_t)4 << 20));
  float* tmp  = qkv;
  float* aob  = (float*)(ws + ((size_t)30 << 20));
  float* xg   = (float*)(ws + ((size_t)38 << 20));
  unsigned short* zx_bf = (unsigned short*)(ws + ((size_t)38 << 20));
  int* boundary  = (int*)(ws + ((size_t)46 << 20));
  int* seg_id    = boundary + M_TOT;
  int* seg_start = seg_id + M_TOT;
  int* n_seg     = seg_start + B_*(L_+1);
  float* semb0     = (float*)(ws + ((size_t)47 << 20));
  float* partial   = (float*)(ws + ((size_t)47 << 20) + 65536);
  unsigned short* tmp_bf = (unsigned short*)(ws + ((size_t)50 << 20));
  unsigned short* vfrag  = (unsigned short*)(ws + ((size_t)58 << 20));
  unsigned short* abf    = (unsigned short*)(ws + ((size_t)84 << 20));
  unsigned short* wpk    = (unsigned short*)(ws + ((size_t)88 << 20));

  unsigned short* wpk_segA  = wpk;
  unsigned short* wpk_segF1 = wpk + 32768;
  unsigned short* wpk_segF2 = wpk + 49152;
  unsigned short* wpk_glbA  = wpk + 65536;
  unsigned short* wpk_glbF1 = wpk + 196608;
  unsigned short* wpk_glbF2 = wpk + 262144;
  unsigned short* wpk_up    = wpk + 327680;

  pack_all_kernel<<<164, 256, 0, stream>>>(seg_attn_w, seg_ff1_w, seg_ff2_w,
                                           glb_attn_w, glb_ff1_w, glb_ff2_w, up_w, wpk);

  featurize_kernel<<<M_TOT/4, 256, 0, stream>>>(pts, fs, ft, w_space, b_space, w_time, b_time,
                                                w_fout, b_fout, w_gate, b_gate, zx, zx_bf, boundary);
  scan_kernel<<<B_, 1024, 0, stream>>>(boundary, seg_id, seg_start, n_seg);

  // ---- segment-level encoder (D=64, H=2, FF=128); LN fused into GEMM epilogues
  for (int l = 0; l < 2; ++l) {
    const float* ab = seg_attn_b + (size_t)l*4*64;
    mgemm_kernel<64,64,3,false,false,true,false><<<dim3(256,3),256,0,stream>>>(
        zx_bf, wpk_segA + (size_t)l*4*4096, ab, qkv, nullptr, nullptr);
    seg_attn_kernel<<<(M_TOT*2*8)/256, 256, 0, stream>>>(qkv, seg_id, seg_start, abf);
    mgemm_ln64_kernel<64><<<256,256,0,stream>>>(
        abf, wpk_segA + (size_t)(l*4+3)*4096, ab + 192,
        zx, seg_ln_g + l*128, seg_ln_b + l*128, zx_bf);
    mgemm_kernel<64,128,1,true,false,false,true><<<dim3(256,2),256,0,stream>>>(
        zx_bf, wpk_segF1 + (size_t)l*8192, seg_ff1_b + l*128, nullptr, tmp_bf, nullptr);
    mgemm_ln64_kernel<128><<<256,256,0,stream>>>(
        tmp_bf, wpk_segF2 + (size_t)l*8192, seg_ff2_b + l*64,
        zx, seg_ln_g + l*128 + 64, seg_ln_b + l*128 + 64, zx_bf);
  }

  // ---- pooling + up-projection (gated) ----
  pool_kernel<<<M_TOT/4, 256, 0, stream>>>(zx, seg_start, n_seg, abf);
  mgemm_kernel<64,128,1,false,true,true,true><<<dim3(256,2),256,0,stream>>>(
      abf, wpk_up, up_b, xg, xg_bf, n_seg);
  row0_kernel<<<B_, 128, 0, stream>>>(xg, semb0);

  // ---- global-level encoder (D=128, H=4, FF=256), row-gated ----
  for (int l = 0; l < 2; ++l) {
    const float* ab = glb_attn_b + (size_t)l*4*128;
    mgemm_kernel<128,128,3,false,true,false,true,0><<<dim3(256,6),256,0,stream>>>(
        xg_bf, wpk_glbA + (size_t)l*4*16384, ab, nullptr, qkv_bf, n_seg);
    vpack_kernel<<<1024, 256, 0, stream>>>(qkv_bf, vfrag);
    glb_attn_mfma_kernel<<<B_*4*16, 256, 0, stream>>>(qkv_bf, vfrag, n_seg, abf);
    mgemm_kernel<128,128,1,false,true,true,false><<<dim3(256,2),256,0,stream>>>(
        abf, wpk_glbA + (size_t)(l*4+3)*16384, ab + 384, tmp, nullptr, n_seg);
    ln128_kernel<<<M_TOT/2, 256, 0, stream>>>(xg, tmp, glb_ln_g + l*256, glb_ln_b + l*256, n_seg, xg_bf);
    mgemm_kernel<128,256,1,true,true,false,true><<<dim3(256,4),256,0,stream>>>(
        xg_bf, wpk_glbF1 + (size_t)l*32768, glb_ff1_b + l*256, nullptr, tmp_bf, n_seg);
    mgemm_kernel<256,128,1,false,true,true,false><<<dim3(256,2),256,0,stream>>>(
        tmp_bf, wpk_glbF2 + (size_t)l*32768, glb_ff2_b + l*128, aob, nullptr, n_seg);
    ln128_kernel<<<M_TOT/2, 256, 0, stream>>>(xg, aob, glb_ln_g + l*256 + 128, glb_ln_b + l*256 + 128, n_seg, xg_bf);
  }

  pool_final_kernel<<<B_*16, 128, 0, stream>>>(xg, n_seg, partial);
  final_kernel<<<B_, 128, 0, stream>>>(partial, semb0, n_seg, fin_w, fin_b, (float*)d_out);
}

// Round 10
// 284.513 us; speedup vs baseline: 4.8460x; 1.0562x over previous
//
#include <hip/hip_runtime.h>
#include <math.h>

#define B_ 16
#define L_ 1024
#define M_TOT (B_*L_)   // 16384

typedef __attribute__((ext_vector_type(8))) short short8v;  // 8 bf16 (4 VGPRs)
typedef __attribute__((ext_vector_type(4))) float f32x4;

__device__ __forceinline__ float wave_reduce_sum(float v) {
#pragma unroll
  for (int o = 32; o >= 1; o >>= 1) v += __shfl_xor(v, o, 64);
  return v;
}

__device__ __forceinline__ unsigned short f2bf(float f) {
  union { float f; unsigned u; } v; v.f = f;
  unsigned r = v.u + 0x7FFFu + ((v.u >> 16) & 1u);
  return (unsigned short)(r >> 16);
}

// ---------------- fused weight pack: fp32 [nmat][K][N] -> MFMA B-frag bf16 ----
__global__ __launch_bounds__(256) void pack_all_kernel(
    const float* __restrict__ s0, const float* __restrict__ s1,
    const float* __restrict__ s2, const float* __restrict__ s3,
    const float* __restrict__ s4, const float* __restrict__ s5,
    const float* __restrict__ s6, unsigned short* __restrict__ wpk)
{
  int idx = blockIdx.x*256 + (int)threadIdx.x;
  const float* src; unsigned short* dst; int K, N;
  if      (idx <  4096) { src=s0; dst=wpk;          K=64;  N=64;  }
  else if (idx <  6144) { src=s1; dst=wpk+32768;    K=64;  N=128; idx-=4096; }
  else if (idx <  8192) { src=s2; dst=wpk+49152;    K=128; N=64;  idx-=6144; }
  else if (idx < 24576) { src=s3; dst=wpk+65536;    K=128; N=128; idx-=8192; }
  else if (idx < 32768) { src=s4; dst=wpk+196608;   K=128; N=256; idx-=24576; }
  else if (idx < 40960) { src=s5; dst=wpk+262144;   K=256; N=128; idx-=32768; }
  else if (idx < 41984) { src=s6; dst=wpk+327680;   K=64;  N=128; idx-=40960; }
  else return;
  const int l = idx & 63;
  int f = idx >> 6;
  const int ntn = N >> 4;
  const int nt = f % ntn; f /= ntn;
  const int ktn = K >> 5;
  const int kt = f % ktn;
  const int m  = f / ktn;
  const float* s = src + (size_t)m*K*N + (size_t)(kt*32 + ((l>>4)<<3))*N + nt*16 + (l&15);
  unsigned pw[4];
#pragma unroll
  for (int jj = 0; jj < 4; ++jj)
    pw[jj] = (unsigned)f2bf(s[(size_t)(2*jj)*N]) | ((unsigned)f2bf(s[(size_t)(2*jj+1)*N]) << 16);
  uint4 u; u.x = pw[0]; u.y = pw[1]; u.z = pw[2]; u.w = pw[3];
  *reinterpret_cast<uint4*>(dst + (size_t)idx*8) = u;
}

// ---------------- MFMA GEMM: C = act(A[M,K] @ W[K,PN per part] + bias) --------
template<int K, int PN, int NPARTS, bool RELU, bool GATED, bool WF32, bool WBF, int SPART = -1>
__global__ __launch_bounds__(256) void mgemm_kernel(
    const unsigned short* __restrict__ Abf,
    const unsigned short* __restrict__ Wpk,
    const float* __restrict__ bias,
    float* __restrict__ C, unsigned short* __restrict__ Cbf,
    const int* __restrict__ nseg)
{
  constexpr int NOUT = NPARTS*PN;
  constexpr int KT = K/32;
  constexpr int NTP = PN/16;
  constexpr int CPP = PN/64;
  const int row0 = blockIdx.x * 64;
  if (GATED) { const int b = row0 >> 10; if ((row0 & (L_-1)) >= nseg[b]) return; }
  const int ct = blockIdx.y;
  const int part = ct / CPP;
  const int nt0  = (ct % CPP) * 4;
  const int wv = (int)threadIdx.x >> 6;
  const int ln = (int)threadIdx.x & 63;
  const int rbase = row0 + wv*16;
  const unsigned short* aptr = Abf + (size_t)(rbase + (ln & 15))*K + ((ln >> 4) << 3);
  const unsigned short* bptr = Wpk + ((size_t)part*KT*NTP + nt0)*512 + (size_t)ln*8;
  f32x4 acc0 = {0.f,0.f,0.f,0.f}, acc1 = {0.f,0.f,0.f,0.f};
  f32x4 acc2 = {0.f,0.f,0.f,0.f}, acc3 = {0.f,0.f,0.f,0.f};
#pragma unroll
  for (int kt = 0; kt < KT; ++kt) {
    short8v a = *reinterpret_cast<const short8v*>(aptr + kt*32);
    const unsigned short* bk = bptr + (size_t)kt*NTP*512;
    short8v b0 = *reinterpret_cast<const short8v*>(bk);
    short8v b1 = *reinterpret_cast<const short8v*>(bk + 512);
    short8v b2 = *reinterpret_cast<const short8v*>(bk + 1024);
    short8v b3 = *reinterpret_cast<const short8v*>(bk + 1536);
    acc0 = __builtin_amdgcn_mfma_f32_16x16x32_bf16(a, b0, acc0, 0, 0, 0);
    acc1 = __builtin_amdgcn_mfma_f32_16x16x32_bf16(a, b1, acc1, 0, 0, 0);
    acc2 = __builtin_amdgcn_mfma_f32_16x16x32_bf16(a, b2, acc2, 0, 0, 0);
    acc3 = __builtin_amdgcn_mfma_f32_16x16x32_bf16(a, b3, acc3, 0, 0, 0);
  }
  const int colb = part*PN + nt0*16 + (ln & 15);
  const int rowe = rbase + ((ln >> 4) << 2);
  f32x4 av[4] = {acc0, acc1, acc2, acc3};
#pragma unroll
  for (int i = 0; i < 4; ++i) {
    const int col = colb + i*16;
    const float bs = bias[col];
#pragma unroll
    for (int r = 0; r < 4; ++r) {
      float v = av[i][r] + bs;
      if (SPART >= 0) { if (part == SPART) v *= 0.25506972533f; }  // 1/sqrt(32)*log2e
      if (RELU) v = fmaxf(v, 0.f);
      if (WF32) C[(size_t)(rowe + r)*NOUT + col] = v;
      if (WBF)  Cbf[(size_t)(rowe + r)*NOUT + col] = f2bf(v);
    }
  }
}

// ---------------- MFMA GEMM + residual + LayerNorm fused (D=64 rows) ----------
template<int K>
__global__ __launch_bounds__(256) void mgemm_ln64_kernel(
    const unsigned short* __restrict__ Abf,
    const unsigned short* __restrict__ Wpk,
    const float* __restrict__ bias,
    float* __restrict__ x,                 // residual in, fp32 out (in-place)
    const float* __restrict__ gam, const float* __restrict__ bet,
    unsigned short* __restrict__ xbf)
{
  constexpr int KT = K/32;
  const int row0 = blockIdx.x * 64;
  const int wv = (int)threadIdx.x >> 6;
  const int ln = (int)threadIdx.x & 63;
  const int rbase = row0 + wv*16;
  const unsigned short* aptr = Abf + (size_t)(rbase + (ln & 15))*K + ((ln >> 4) << 3);
  const unsigned short* bptr = Wpk + (size_t)ln*8;
  f32x4 acc0 = {0.f,0.f,0.f,0.f}, acc1 = {0.f,0.f,0.f,0.f};
  f32x4 acc2 = {0.f,0.f,0.f,0.f}, acc3 = {0.f,0.f,0.f,0.f};
#pragma unroll
  for (int kt = 0; kt < KT; ++kt) {
    short8v a = *reinterpret_cast<const short8v*>(aptr + kt*32);
    const unsigned short* bk = bptr + (size_t)kt*4*512;
    short8v b0 = *reinterpret_cast<const short8v*>(bk);
    short8v b1 = *reinterpret_cast<const short8v*>(bk + 512);
    short8v b2 = *reinterpret_cast<const short8v*>(bk + 1024);
    short8v b3 = *reinterpret_cast<const short8v*>(bk + 1536);
    acc0 = __builtin_amdgcn_mfma_f32_16x16x32_bf16(a, b0, acc0, 0, 0, 0);
    acc1 = __builtin_amdgcn_mfma_f32_16x16x32_bf16(a, b1, acc1, 0, 0, 0);
    acc2 = __builtin_amdgcn_mfma_f32_16x16x32_bf16(a, b2, acc2, 0, 0, 0);
    acc3 = __builtin_amdgcn_mfma_f32_16x16x32_bf16(a, b3, acc3, 0, 0, 0);
  }
  const int colc = ln & 15;
  const int rowe = rbase + ((ln >> 4) << 2);
  f32x4 av[4] = {acc0, acc1, acc2, acc3};
  float v[4][4];
#pragma unroll
  for (int i = 0; i < 4; ++i) {
    const int col = i*16 + colc;
    const float bs = bias[col];
#pragma unroll
    for (int r = 0; r < 4; ++r)
      v[i][r] = av[i][r] + bs + x[(size_t)(rowe + r)*64 + col];
  }
  float rs[4];
#pragma unroll
  for (int r = 0; r < 4; ++r) rs[r] = v[0][r]+v[1][r]+v[2][r]+v[3][r];
#pragma unroll
  for (int m = 1; m <= 8; m <<= 1)
#pragma unroll
    for (int r = 0; r < 4; ++r) rs[r] += __shfl_xor(rs[r], m, 64);
  float mean[4], vs[4];
#pragma unroll
  for (int r = 0; r < 4; ++r) { mean[r] = rs[r]*(1.0f/64.0f); vs[r] = 0.f; }
#pragma unroll
  for (int i = 0; i < 4; ++i)
#pragma unroll
    for (int r = 0; r < 4; ++r) { const float d = v[i][r]-mean[r]; vs[r] = fmaf(d, d, vs[r]); }
#pragma unroll
  for (int m = 1; m <= 8; m <<= 1)
#pragma unroll
    for (int r = 0; r < 4; ++r) vs[r] += __shfl_xor(vs[r], m, 64);
  float rstd[4];
#pragma unroll
  for (int r = 0; r < 4; ++r) rstd[r] = rsqrtf(vs[r]*(1.0f/64.0f) + 1e-5f);
#pragma unroll
  for (int i = 0; i < 4; ++i) {
    const int col = i*16 + colc;
    const float g = gam[col], bb = bet[col];
#pragma unroll
    for (int r = 0; r < 4; ++r) {
      const float out = (v[i][r]-mean[r])*rstd[r]*g + bb;
      x[(size_t)(rowe + r)*64 + col] = out;
      xbf[(size_t)(rowe + r)*64 + col] = f2bf(out);
    }
  }
}

// ---------------- featurize: 4 points per 256-thr block (dual-write) ----------
__global__ __launch_bounds__(256) void featurize_kernel(
    const float* __restrict__ pts, const float* __restrict__ fs, const float* __restrict__ ft,
    const float* __restrict__ w_space, const float* __restrict__ b_space,
    const float* __restrict__ w_time, const float* __restrict__ b_time,
    const float* __restrict__ w_fout, const float* __restrict__ b_fout,
    const float* __restrict__ w_gate, const float* __restrict__ b_gate,
    float* __restrict__ z, unsigned short* __restrict__ zbf, int* __restrict__ boundary)
{
  const int sub = threadIdx.x >> 6;
  const int d   = threadIdx.x & 63;
  const int p   = blockIdx.x * 4 + sub;
  const float TWO_PI = 6.283185307179586f;
  __shared__ float feat[4][32];
  __shared__ float tfeat[4][16];
  __shared__ float g96[4][96];
  const float x = pts[p*3+0], y = pts[p*3+1], t = pts[p*3+2];
  if (d < 16) {
    float sp = (x*fs[d] + y*fs[16+d]) * TWO_PI;
    feat[sub][d]    = sinf(sp);
    feat[sub][16+d] = cosf(sp);
  } else if (d < 24) {
    int r = d - 16;
    float tp = t * ft[r] * TWO_PI;
    tfeat[sub][r]   = sinf(tp);
    tfeat[sub][8+r] = cosf(tp);
  }
  __syncthreads();
  float sf = b_space[d];
#pragma unroll
  for (int k2 = 0; k2 < 32; ++k2) sf = fmaf(feat[sub][k2], w_space[k2*64+d], sf);
  g96[sub][d] = sf;
  if (d < 32) {
    float tf = b_time[d];
#pragma unroll
    for (int k2 = 0; k2 < 16; ++k2) tf = fmaf(tfeat[sub][k2], w_time[k2*32+d], tf);
    g96[sub][64+d] = tf;
  }
  __syncthreads();
  float zv = b_fout[d];
#pragma unroll
  for (int k2 = 0; k2 < 96; ++k2) zv = fmaf(g96[sub][k2], w_fout[k2*64+d], zv);
  z[(size_t)p*64+d] = zv;
  zbf[(size_t)p*64+d] = f2bf(zv);
  float gv = wave_reduce_sum(zv * w_gate[d]);
  if (d == 0) {
    float logit = gv + b_gate[0];
    float gate = 1.0f / (1.0f + expf(-logit));
    int bnd = (gate > 0.5f) ? 1 : 0;
    if ((p & (L_-1)) == 0) bnd = 1;
    boundary[p] = bnd;
  }
}

// ---------------- scan: seg_id, seg_start, n_seg ----------------
__global__ __launch_bounds__(1024) void scan_kernel(const int* __restrict__ boundary,
    int* __restrict__ seg_id, int* __restrict__ seg_start, int* __restrict__ n_seg)
{
  __shared__ int sc[1024];
  const int b = blockIdx.x, l = threadIdx.x;
  const int v = boundary[b*L_ + l];
  sc[l] = v;
  __syncthreads();
  for (int off = 1; off < 1024; off <<= 1) {
    int add = (l >= off) ? sc[l - off] : 0;
    __syncthreads();
    sc[l] += add;
    __syncthreads();
  }
  const int sid = sc[l] - 1;
  seg_id[b*L_ + l] = sid;
  if (v) seg_start[b*(L_+1) + sid] = l;
  if (l == L_-1) {
    n_seg[b] = sid + 1;
    seg_start[b*(L_+1) + sid + 1] = L_;
  }
}

// ---------------- segment attention: 8 lanes per (pt,h) item -------------------
__global__ __launch_bounds__(256) void seg_attn_kernel(
    const float* __restrict__ qkv,
    const int* __restrict__ seg_id, const int* __restrict__ seg_start,
    unsigned short* __restrict__ aobf)
{
  const int gid = blockIdx.x * 256 + (int)threadIdx.x;  // item*8 + sub
  const int sub = gid & 7;
  const int item = gid >> 3;        // ((b*L + pt)*2 + h)
  const int h  = item & 1;
  const int pt = (item >> 1) & (L_-1);
  const int b  = item >> 11;
  const float scale = 0.17677669529663687f;
  float4 q4 = *reinterpret_cast<const float4*>(qkv + (size_t)(b*L_+pt)*192 + h*32 + sub*4);
  q4.x*=scale; q4.y*=scale; q4.z*=scale; q4.w*=scale;
  const int s  = seg_id[b*L_ + pt];
  const int j0 = seg_start[b*(L_+1) + s];
  const int j1 = seg_start[b*(L_+1) + s + 1];
  float lsum = 0.f;
  float4 acc = {0.f,0.f,0.f,0.f};
  for (int j = j0; j < j1; ++j) {
    const float* base = qkv + (size_t)(b*L_ + j)*192 + h*32 + sub*4;
    float4 k4 = *reinterpret_cast<const float4*>(base + 64);
    float4 v4 = *reinterpret_cast<const float4*>(base + 128);
    float dot = q4.x*k4.x;
    dot = fmaf(q4.y, k4.y, dot);
    dot = fmaf(q4.z, k4.z, dot);
    dot = fmaf(q4.w, k4.w, dot);
    dot += __shfl_xor(dot, 1, 64);
    dot += __shfl_xor(dot, 2, 64);
    dot += __shfl_xor(dot, 4, 64);
    const float p = __expf(fminf(dot, 30.f));
    lsum += p;
    acc.x = fmaf(p, v4.x, acc.x);
    acc.y = fmaf(p, v4.y, acc.y);
    acc.z = fmaf(p, v4.z, acc.z);
    acc.w = fmaf(p, v4.w, acc.w);
  }
  const float inv = 1.0f / lsum;
  unsigned* op = reinterpret_cast<unsigned*>(aobf + (size_t)(b*L_+pt)*64 + h*32 + sub*4);
  op[0] = (unsigned)f2bf(acc.x*inv) | ((unsigned)f2bf(acc.y*inv) << 16);
  op[1] = (unsigned)f2bf(acc.z*inv) | ((unsigned)f2bf(acc.w*inv) << 16);
}

// ---------------- K+V fragment pack for MFMA attention -----------------------
// V: vfrag[(((b*4+h)*32 + c)*2 + dt)][lane][j] = V[b*L + c*32 + kperm][h*32+dt*16+(lane&15)]
//    kperm(slot s=(lane>>4)*8+j) = (s>>3)*4 + (s&3) + ((s>>2)&1)*16   (8 scattered ushort reads)
// K: kfrag[(((b*4+h)*32 + c)*2 + sub)][lane][j] = K[b*L + c*32+sub*16+(lane&15)][h*32+(lane>>4)*8+j]
//    (one coalesced 16B read per thread)
__global__ __launch_bounds__(256) void kvpack_kernel(
    const unsigned short* __restrict__ qkvbf, const int* __restrict__ n_seg,
    unsigned short* __restrict__ vfrag, unsigned short* __restrict__ kfrag)
{
  int idx = blockIdx.x*256 + (int)threadIdx.x;
  const bool isK = idx >= (1 << 18);
  idx &= (1 << 18) - 1;
  const int lane = idx & 63;
  const int dt = (idx >> 6) & 1;
  const int c  = (idx >> 7) & 31;
  const int h  = (idx >> 12) & 3;
  const int b  = idx >> 14;
  if (c*32 >= n_seg[b]) return;
  if (isK) {
    const int key = c*32 + dt*16 + (lane & 15);
    const uint4 u = *reinterpret_cast<const uint4*>(
        qkvbf + (size_t)(b*L_ + key)*384 + 128 + h*32 + ((lane >> 4) << 3));
    *reinterpret_cast<uint4*>(kfrag + (size_t)idx*8) = u;
    return;
  }
  const int g = lane >> 4;
  const int dcol = lane & 15;
  unsigned short vals[8];
#pragma unroll
  for (int j = 0; j < 8; ++j) {
    const int key = c*32 + g*4 + (j & 3) + ((j >> 2) << 4);
    vals[j] = qkvbf[(size_t)(b*L_ + key)*384 + 256 + h*32 + dt*16 + dcol];
  }
  uint4 u;
  u.x = (unsigned)vals[0] | ((unsigned)vals[1] << 16);
  u.y = (unsigned)vals[2] | ((unsigned)vals[3] << 16);
  u.z = (unsigned)vals[4] | ((unsigned)vals[5] << 16);
  u.w = (unsigned)vals[6] | ((unsigned)vals[7] << 16);
  *reinterpret_cast<uint4*>(vfrag + (size_t)idx*8) = u;
}

// ---------------- global attention via MFMA (coalesced frags, XCD-swizzled) ----
// launch: blockIdx.x = qt*64 + (b*4+h); Q pre-scaled by 1/sqrt(32)*log2e.
__global__ __launch_bounds__(256) void glb_attn_mfma_kernel(
    const unsigned short* __restrict__ qkvbf,   // [16384][384] bf16 (Q only here)
    const unsigned short* __restrict__ kfrag,
    const unsigned short* __restrict__ vfrag,
    const int* __restrict__ n_seg,
    unsigned short* __restrict__ aobf)          // [16384][128] bf16
{
  const int g64 = blockIdx.x & 63;    // (b*4 + h)
  const int qt  = blockIdx.x >> 6;
  const int h  = g64 & 3;
  const int b  = g64 >> 2;
  const int ns = n_seg[b];
  if (qt*64 >= ns) return;
  const int wv = (int)threadIdx.x >> 6;
  const int ln = (int)threadIdx.x & 63;
  const int g  = ln >> 4;
  const int qc = ln & 15;
  __shared__ float lsumS[4][16];

  const int q0 = qt*64 + wv*16;
  const short8v qf = *reinterpret_cast<const short8v*>(
      qkvbf + (size_t)(b*L_ + q0 + qc)*384 + h*32 + g*8);

  f32x4 O0 = {0.f,0.f,0.f,0.f}, O1 = {0.f,0.f,0.f,0.f};
  const f32x4 zz = {0.f,0.f,0.f,0.f};
  float lsum = 0.f;
  const unsigned short* kfb = kfrag + (size_t)((b*4 + h)*32)*1024 + (size_t)ln*8;
  const unsigned short* vfb = vfrag + (size_t)((b*4 + h)*32)*1024 + (size_t)ln*8;

  const int nfull = ns >> 5;
#pragma unroll 2
  for (int c = 0; c < nfull; ++c) {
    short8v kf0 = *reinterpret_cast<const short8v*>(kfb);
    short8v kf1 = *reinterpret_cast<const short8v*>(kfb + 512);
    short8v v0  = *reinterpret_cast<const short8v*>(vfb);
    short8v v1  = *reinterpret_cast<const short8v*>(vfb + 512);
    f32x4 s0 = __builtin_amdgcn_mfma_f32_16x16x32_bf16(kf0, qf, zz, 0, 0, 0);
    f32x4 s1 = __builtin_amdgcn_mfma_f32_16x16x32_bf16(kf1, qf, zz, 0, 0, 0);
    float p[8];
#pragma unroll
    for (int r = 0; r < 4; ++r) {
      const float e0 = exp2f(fminf(s0[r], 43.f));
      const float e1 = exp2f(fminf(s1[r], 43.f));
      p[r] = e0; p[4+r] = e1;
      lsum += e0 + e1;
    }
    short8v pf;
#pragma unroll
    for (int i = 0; i < 8; ++i) pf[i] = (short)f2bf(p[i]);
    O0 = __builtin_amdgcn_mfma_f32_16x16x32_bf16(pf, v0, O0, 0, 0, 0);
    O1 = __builtin_amdgcn_mfma_f32_16x16x32_bf16(pf, v1, O1, 0, 0, 0);
    kfb += 1024; vfb += 1024;
  }
  if (ns & 31) {   // masked tail chunk
    short8v kf0 = *reinterpret_cast<const short8v*>(kfb);
    short8v kf1 = *reinterpret_cast<const short8v*>(kfb + 512);
    short8v v0  = *reinterpret_cast<const short8v*>(vfb);
    short8v v1  = *reinterpret_cast<const short8v*>(vfb + 512);
    f32x4 s0 = __builtin_amdgcn_mfma_f32_16x16x32_bf16(kf0, qf, zz, 0, 0, 0);
    f32x4 s1 = __builtin_amdgcn_mfma_f32_16x16x32_bf16(kf1, qf, zz, 0, 0, 0);
    const int k0 = nfull*32;
    float p[8];
#pragma unroll
    for (int r = 0; r < 4; ++r) {
      const int key0 = k0 + g*4 + r;
      const float e0 = (key0 < ns)      ? exp2f(fminf(s0[r], 43.f)) : 0.f;
      const float e1 = (key0 + 16 < ns) ? exp2f(fminf(s1[r], 43.f)) : 0.f;
      p[r] = e0; p[4+r] = e1;
      lsum += e0 + e1;
    }
    short8v pf;
#pragma unroll
    for (int i = 0; i < 8; ++i) pf[i] = (short)f2bf(p[i]);
    O0 = __builtin_amdgcn_mfma_f32_16x16x32_bf16(pf, v0, O0, 0, 0, 0);
    O1 = __builtin_amdgcn_mfma_f32_16x16x32_bf16(pf, v1, O1, 0, 0, 0);
  }
  lsum += __shfl_xor(lsum, 16, 64);
  lsum += __shfl_xor(lsum, 32, 64);
  if (ln < 16) lsumS[wv][ln] = lsum;
  __syncthreads();
  unsigned short* outp = aobf + (size_t)(b*L_ + q0 + g*4)*128 + h*32 + qc;
#pragma unroll
  for (int r = 0; r < 4; ++r) {
    const float inv = 1.0f / lsumS[wv][g*4 + r];
    outp[(size_t)r*128]      = f2bf(O0[r]*inv);
    outp[(size_t)r*128 + 16] = f2bf(O1[r]*inv);
  }
}

// ---------------- LN(x+r) D=128 gated: dual-write ----------------
__global__ __launch_bounds__(256) void ln128_kernel(
    float* __restrict__ x, const float* __restrict__ r,
    const float* __restrict__ gam, const float* __restrict__ bet,
    const int* __restrict__ nseg, unsigned short* __restrict__ xbf)
{
  const int row0 = blockIdx.x*2;
  const int b = row0 >> 10;
  if ((row0 & (L_-1)) >= nseg[b]) return;
  const int sub = (int)threadIdx.x >> 7;
  const int d   = (int)threadIdx.x & 127;
  const int row = row0 + sub;
  const bool valid = (row & (L_-1)) < nseg[b];
  __shared__ float red[2][4];
  float val = 0.f;
  if (valid) val = x[(size_t)row*128 + d] + r[(size_t)row*128 + d];
  float s = wave_reduce_sum(val);
  if ((d & 63) == 0) red[sub][d >> 6] = s;
  __syncthreads();
  s = red[sub][0] + red[sub][1];
  const float mean = s * (1.0f/128.0f);
  const float dv = val - mean;
  float s2 = wave_reduce_sum(dv*dv);
  if ((d & 63) == 0) red[sub][2 + (d >> 6)] = s2;
  __syncthreads();
  s2 = red[sub][2] + red[sub][3];
  if (valid) {
    const float out = dv * rsqrtf(s2*(1.0f/128.0f) + 1e-5f) * gam[d] + bet[d];
    x[(size_t)row*128 + d] = out;
    xbf[(size_t)row*128 + d] = f2bf(out);
  }
}

// ---------------- segment mean pooling -> bf16 [row][64] ----------------
__global__ __launch_bounds__(256) void pool_kernel(
    const float* __restrict__ h, const int* __restrict__ seg_start,
    const int* __restrict__ n_seg, unsigned short* __restrict__ meanbf)
{
  const int gs = blockIdx.x*4 + ((int)threadIdx.x >> 6);
  const int b = gs >> 10, s = gs & (L_-1);
  const int d = (int)threadIdx.x & 63;
  if (s >= n_seg[b]) return;
  const int j0 = seg_start[b*(L_+1)+s], j1 = seg_start[b*(L_+1)+s+1];
  float acc = 0.f;
  for (int j = j0; j < j1; ++j) acc += h[(size_t)(b*L_+j)*64 + d];
  meanbf[(size_t)gs*64 + d] = f2bf(acc / (float)(j1 - j0));
}

// ---------------- save row0 of xg for ns==1 path ----------------
__global__ __launch_bounds__(128) void row0_kernel(
    const float* __restrict__ xg, float* __restrict__ semb0)
{
  semb0[blockIdx.x*128 + threadIdx.x] = xg[(size_t)blockIdx.x*L_*128 + threadIdx.x];
}

// ---------------- final pooling phase A ----------------
__global__ __launch_bounds__(128) void pool_final_kernel(
    const float* __restrict__ g, const int* __restrict__ n_seg,
    float* __restrict__ partial)
{
  const int b = blockIdx.x >> 4, c = blockIdx.x & 15;
  const int d = (int)threadIdx.x;
  const int ns = n_seg[b];
  const int i0 = c*64, i1 = min(ns, i0 + 64);
  float acc = 0.f;
  for (int i = i0; i < i1; ++i) acc += g[(size_t)(b*L_+i)*128 + d];
  partial[(size_t)blockIdx.x*128 + d] = acc;
}

// ---------------- final phase B ----------------
__global__ __launch_bounds__(128) void final_kernel(
    const float* __restrict__ partial, const float* __restrict__ semb0,
    const int* __restrict__ n_seg, const float* __restrict__ fin_w,
    const float* __restrict__ fin_b, float* __restrict__ out)
{
  const int b = blockIdx.x, d = threadIdx.x;
  const int ns = n_seg[b];
  __shared__ float pl[128];
  float pooled;
  if (ns == 1) pooled = semb0[b*128 + d];
  else {
    float acc = 0.f;
#pragma unroll
    for (int c = 0; c < 16; ++c) acc += partial[(size_t)(b*16 + c)*128 + d];
    pooled = acc / (float)ns;
  }
  pl[d] = pooled;
  __syncthreads();
  float o = fin_b[d];
#pragma unroll 8
  for (int k2 = 0; k2 < 128; ++k2) o = fmaf(pl[k2], fin_w[k2*128+d], o);
  out[b*128+d] = o;
}

extern "C" void kernel_launch(void* const* d_in, const int* in_sizes, int n_in,
                              void* d_out, int out_size, void* d_ws, size_t ws_size,
                              hipStream_t stream) {
  const float* pts     = (const float*)d_in[0];
  const float* fs      = (const float*)d_in[1];
  const float* ft      = (const float*)d_in[2];
  const float* w_space = (const float*)d_in[3];
  const float* b_space = (const float*)d_in[4];
  const float* w_time  = (const float*)d_in[5];
  const float* b_time  = (const float*)d_in[6];
  const float* w_fout  = (const float*)d_in[7];
  const float* b_fout  = (const float*)d_in[8];
  const float* w_gate  = (const float*)d_in[9];
  const float* b_gate  = (const float*)d_in[10];
  const float* seg_attn_w = (const float*)d_in[11];
  const float* seg_attn_b = (const float*)d_in[12];
  const float* seg_ln_g   = (const float*)d_in[13];
  const float* seg_ln_b   = (const float*)d_in[14];
  const float* seg_ff1_w  = (const float*)d_in[15];
  const float* seg_ff1_b  = (const float*)d_in[16];
  const float* seg_ff2_w  = (const float*)d_in[17];
  const float* seg_ff2_b  = (const float*)d_in[18];
  const float* glb_attn_w = (const float*)d_in[19];
  const float* glb_attn_b = (const float*)d_in[20];
  const float* glb_ln_g   = (const float*)d_in[21];
  const float* glb_ln_b   = (const float*)d_in[22];
  const float* glb_ff1_w  = (const float*)d_in[23];
  const float* glb_ff1_b  = (const float*)d_in[24];
  const float* glb_ff2_w  = (const float*)d_in[25];
  const float* glb_ff2_b  = (const float*)d_in[26];
  const float* up_w    = (const float*)d_in[27];
  const float* up_b    = (const float*)d_in[28];
  const float* fin_w   = (const float*)d_in[29];
  const float* fin_b   = (const float*)d_in[30];

  char* ws = (char*)d_ws;
  float* zx   = (float*)(ws);
  unsigned short* xg_bf = (unsigned short*)(ws);
  float* qkv  = (float*)(ws + ((size_t)4  << 20));
  unsigned short* qkv_bf = (unsigned short*)(ws + ((size_t)4 << 20));
  float* tmp  = qkv;
  float* aob  = (float*)(ws + ((size_t)30 << 20));
  float* xg   = (float*)(ws + ((size_t)38 << 20));
  unsigned short* zx_bf = (unsigned short*)(ws + ((size_t)38 << 20));
  int* boundary  = (int*)(ws + ((size_t)46 << 20));
  int* seg_id    = boundary + M_TOT;
  int* seg_start = seg_id + M_TOT;
  int* n_seg     = seg_start + B_*(L_+1);
  float* semb0     = (float*)(ws + ((size_t)47 << 20));
  float* partial   = (float*)(ws + ((size_t)47 << 20) + 65536);
  unsigned short* tmp_bf = (unsigned short*)(ws + ((size_t)50 << 20));  // 8MB
  unsigned short* vfrag  = (unsigned short*)(ws + ((size_t)58 << 20));  // 4MB
  unsigned short* kfrag  = (unsigned short*)(ws + ((size_t)62 << 20));  // 4MB
  unsigned short* abf    = (unsigned short*)(ws + ((size_t)84 << 20));
  unsigned short* wpk    = (unsigned short*)(ws + ((size_t)88 << 20));

  unsigned short* wpk_segA  = wpk;
  unsigned short* wpk_segF1 = wpk + 32768;
  unsigned short* wpk_segF2 = wpk + 49152;
  unsigned short* wpk_glbA  = wpk + 65536;
  unsigned short* wpk_glbF1 = wpk + 196608;
  unsigned short* wpk_glbF2 = wpk + 262144;
  unsigned short* wpk_up    = wpk + 327680;

  pack_all_kernel<<<164, 256, 0, stream>>>(seg_attn_w, seg_ff1_w, seg_ff2_w,
                                           glb_attn_w, glb_ff1_w, glb_ff2_w, up_w, wpk);

  featurize_kernel<<<M_TOT/4, 256, 0, stream>>>(pts, fs, ft, w_space, b_space, w_time, b_time,
                                                w_fout, b_fout, w_gate, b_gate, zx, zx_bf, boundary);
  scan_kernel<<<B_, 1024, 0, stream>>>(boundary, seg_id, seg_start, n_seg);

  // ---- segment-level encoder (D=64, H=2, FF=128); LN fused into GEMM epilogues
  for (int l = 0; l < 2; ++l) {
    const float* ab = seg_attn_b + (size_t)l*4*64;
    mgemm_kernel<64,64,3,false,false,true,false><<<dim3(256,3),256,0,stream>>>(
        zx_bf, wpk_segA + (size_t)l*4*4096, ab, qkv, nullptr, nullptr);
    seg_attn_kernel<<<(M_TOT*2*8)/256, 256, 0, stream>>>(qkv, seg_id, seg_start, abf);
    mgemm_ln64_kernel<64><<<256,256,0,stream>>>(
        abf, wpk_segA + (size_t)(l*4+3)*4096, ab + 192,
        zx, seg_ln_g + l*128, seg_ln_b + l*128, zx_bf);
    mgemm_kernel<64,128,1,true,false,false,true><<<dim3(256,2),256,0,stream>>>(
        zx_bf, wpk_segF1 + (size_t)l*8192, seg_ff1_b + l*128, nullptr, tmp_bf, nullptr);
    mgemm_ln64_kernel<128><<<256,256,0,stream>>>(
        tmp_bf, wpk_segF2 + (size_t)l*8192, seg_ff2_b + l*64,
        zx, seg_ln_g + l*128 + 64, seg_ln_b + l*128 + 64, zx_bf);
  }

  // ---- pooling + up-projection (gated) ----
  pool_kernel<<<M_TOT/4, 256, 0, stream>>>(zx, seg_start, n_seg, abf);
  mgemm_kernel<64,128,1,false,true,true,true><<<dim3(256,2),256,0,stream>>>(
      abf, wpk_up, up_b, xg, xg_bf, n_seg);
  row0_kernel<<<B_, 128, 0, stream>>>(xg, semb0);

  // ---- global-level encoder (D=128, H=4, FF=256), row-gated ----
  for (int l = 0; l < 2; ++l) {
    const float* ab = glb_attn_b + (size_t)l*4*128;
    mgemm_kernel<128,128,3,false,true,false,true,0><<<dim3(256,6),256,0,stream>>>(
        xg_bf, wpk_glbA + (size_t)l*4*16384, ab, nullptr, qkv_bf, n_seg);
    kvpack_kernel<<<2048, 256, 0, stream>>>(qkv_bf, n_seg, vfrag, kfrag);
    glb_attn_mfma_kernel<<<B_*4*16, 256, 0, stream>>>(qkv_bf, kfrag, vfrag, n_seg, abf);
    mgemm_kernel<128,128,1,false,true,true,false><<<dim3(256,2),256,0,stream>>>(
        abf, wpk_glbA + (size_t)(l*4+3)*16384, ab + 384, tmp, nullptr, n_seg);
    ln128_kernel<<<M_TOT/2, 256, 0, stream>>>(xg, tmp, glb_ln_g + l*256, glb_ln_b + l*256, n_seg, xg_bf);
    mgemm_kernel<128,256,1,true,true,false,true><<<dim3(256,4),256,0,stream>>>(
        xg_bf, wpk_glbF1 + (size_t)l*32768, glb_ff1_b + l*256, nullptr, tmp_bf, n_seg);
    mgemm_kernel<256,128,1,false,true,true,false><<<dim3(256,2),256,0,stream>>>(
        tmp_bf, wpk_glbF2 + (size_t)l*32768, glb_ff2_b + l*128, aob, nullptr, n_seg);
    ln128_kernel<<<M_TOT/2, 256, 0, stream>>>(xg, aob, glb_ln_g + l*256 + 128, glb_ln_b + l*256 + 128, n_seg, xg_bf);
  }

  pool_final_kernel<<<B_*16, 128, 0, stream>>>(xg, n_seg, partial);
  final_kernel<<<B_, 128, 0, stream>>>(partial, semb0, n_seg, fin_w, fin_b, (float*)d_out);
}

// Round 11
// 237.241 us; speedup vs baseline: 5.8116x; 1.1993x over previous
//
#include <hip/hip_runtime.h>
#include <math.h>

#define B_ 16
#define L_ 1024
#define M_TOT (B_*L_)   // 16384

typedef __attribute__((ext_vector_type(8))) short short8v;  // 8 bf16 (4 VGPRs)
typedef __attribute__((ext_vector_type(4))) float f32x4;

__device__ __forceinline__ float wave_reduce_sum(float v) {
#pragma unroll
  for (int o = 32; o >= 1; o >>= 1) v += __shfl_xor(v, o, 64);
  return v;
}

__device__ __forceinline__ unsigned short f2bf(float f) {
  union { float f; unsigned u; } v; v.f = f;
  unsigned r = v.u + 0x7FFFu + ((v.u >> 16) & 1u);
  return (unsigned short)(r >> 16);
}

// ---------------- fused weight pack: fp32 [nmat][K][N] -> MFMA B-frag bf16 ----
__global__ __launch_bounds__(256) void pack_all_kernel(
    const float* __restrict__ s0, const float* __restrict__ s1,
    const float* __restrict__ s2, const float* __restrict__ s3,
    const float* __restrict__ s4, const float* __restrict__ s5,
    const float* __restrict__ s6, unsigned short* __restrict__ wpk)
{
  int idx = blockIdx.x*256 + (int)threadIdx.x;
  const float* src; unsigned short* dst; int K, N;
  if      (idx <  4096) { src=s0; dst=wpk;          K=64;  N=64;  }
  else if (idx <  6144) { src=s1; dst=wpk+32768;    K=64;  N=128; idx-=4096; }
  else if (idx <  8192) { src=s2; dst=wpk+49152;    K=128; N=64;  idx-=6144; }
  else if (idx < 24576) { src=s3; dst=wpk+65536;    K=128; N=128; idx-=8192; }
  else if (idx < 32768) { src=s4; dst=wpk+196608;   K=128; N=256; idx-=24576; }
  else if (idx < 40960) { src=s5; dst=wpk+262144;   K=256; N=128; idx-=32768; }
  else if (idx < 41984) { src=s6; dst=wpk+327680;   K=64;  N=128; idx-=40960; }
  else return;
  const int l = idx & 63;
  int f = idx >> 6;
  const int ntn = N >> 4;
  const int nt = f % ntn; f /= ntn;
  const int ktn = K >> 5;
  const int kt = f % ktn;
  const int m  = f / ktn;
  const float* s = src + (size_t)m*K*N + (size_t)(kt*32 + ((l>>4)<<3))*N + nt*16 + (l&15);
  unsigned pw[4];
#pragma unroll
  for (int jj = 0; jj < 4; ++jj)
    pw[jj] = (unsigned)f2bf(s[(size_t)(2*jj)*N]) | ((unsigned)f2bf(s[(size_t)(2*jj+1)*N]) << 16);
  uint4 u; u.x = pw[0]; u.y = pw[1]; u.z = pw[2]; u.w = pw[3];
  *reinterpret_cast<uint4*>(dst + (size_t)idx*8) = u;
}

// ---------------- MFMA GEMM: C = act(A[M,K] @ W[K,PN per part] + bias) --------
template<int K, int PN, int NPARTS, bool RELU, bool GATED, bool WF32, bool WBF,
         int SPART = -1, bool SEMB0 = false>
__global__ __launch_bounds__(256) void mgemm_kernel(
    const unsigned short* __restrict__ Abf,
    const unsigned short* __restrict__ Wpk,
    const float* __restrict__ bias,
    float* __restrict__ C, unsigned short* __restrict__ Cbf,
    const int* __restrict__ nseg, float* __restrict__ semb0)
{
  constexpr int NOUT = NPARTS*PN;
  constexpr int KT = K/32;
  constexpr int NTP = PN/16;
  constexpr int CPP = PN/64;
  const int row0 = blockIdx.x * 64;
  if (GATED) { const int b = row0 >> 10; if ((row0 & (L_-1)) >= nseg[b]) return; }
  const int ct = blockIdx.y;
  const int part = ct / CPP;
  const int nt0  = (ct % CPP) * 4;
  const int wv = (int)threadIdx.x >> 6;
  const int ln = (int)threadIdx.x & 63;
  const int rbase = row0 + wv*16;
  const unsigned short* aptr = Abf + (size_t)(rbase + (ln & 15))*K + ((ln >> 4) << 3);
  const unsigned short* bptr = Wpk + ((size_t)part*KT*NTP + nt0)*512 + (size_t)ln*8;
  f32x4 acc0 = {0.f,0.f,0.f,0.f}, acc1 = {0.f,0.f,0.f,0.f};
  f32x4 acc2 = {0.f,0.f,0.f,0.f}, acc3 = {0.f,0.f,0.f,0.f};
#pragma unroll
  for (int kt = 0; kt < KT; ++kt) {
    short8v a = *reinterpret_cast<const short8v*>(aptr + kt*32);
    const unsigned short* bk = bptr + (size_t)kt*NTP*512;
    short8v b0 = *reinterpret_cast<const short8v*>(bk);
    short8v b1 = *reinterpret_cast<const short8v*>(bk + 512);
    short8v b2 = *reinterpret_cast<const short8v*>(bk + 1024);
    short8v b3 = *reinterpret_cast<const short8v*>(bk + 1536);
    acc0 = __builtin_amdgcn_mfma_f32_16x16x32_bf16(a, b0, acc0, 0, 0, 0);
    acc1 = __builtin_amdgcn_mfma_f32_16x16x32_bf16(a, b1, acc1, 0, 0, 0);
    acc2 = __builtin_amdgcn_mfma_f32_16x16x32_bf16(a, b2, acc2, 0, 0, 0);
    acc3 = __builtin_amdgcn_mfma_f32_16x16x32_bf16(a, b3, acc3, 0, 0, 0);
  }
  const int colb = part*PN + nt0*16 + (ln & 15);
  const int rowe = rbase + ((ln >> 4) << 2);
  f32x4 av[4] = {acc0, acc1, acc2, acc3};
#pragma unroll
  for (int i = 0; i < 4; ++i) {
    const int col = colb + i*16;
    const float bs = bias[col];
#pragma unroll
    for (int r = 0; r < 4; ++r) {
      float v = av[i][r] + bs;
      if (SPART >= 0) { if (part == SPART) v *= 0.25506972533f; }  // 1/sqrt(32)*log2e
      if (RELU) v = fmaxf(v, 0.f);
      const int row = rowe + r;
      if (WF32) C[(size_t)row*NOUT + col] = v;
      if (WBF)  Cbf[(size_t)row*NOUT + col] = f2bf(v);
      if (SEMB0) { if ((row & (L_-1)) == 0) semb0[(row >> 10)*NOUT + col] = v; }
    }
  }
}

// ---------------- fused QKV GEMM -> attention fragment layouts ----------------
// part 0: Q (pre-scaled) -> qbf[row][128] row-major bf16
// part 1: K -> kfrag in MFMA A-operand layout
// part 2: V -> vfrag in kperm'd MFMA A-operand layout
__global__ __launch_bounds__(256) void mgemm_qkvfrag_kernel(
    const unsigned short* __restrict__ Abf,
    const unsigned short* __restrict__ Wpk,
    const float* __restrict__ bias,
    unsigned short* __restrict__ qbf,
    unsigned short* __restrict__ kfrag,
    unsigned short* __restrict__ vfrag,
    const int* __restrict__ nseg)
{
  constexpr int K = 128, PN = 128, KT = 4, NTP = 8;
  const int row0 = blockIdx.x * 64;
  const int bb = row0 >> 10;
  if ((row0 & (L_-1)) >= nseg[bb]) return;
  const int ct = blockIdx.y;          // 0..5
  const int part = ct >> 1;
  const int nt0 = (ct & 1) * 4;
  const int wv = (int)threadIdx.x >> 6;
  const int ln = (int)threadIdx.x & 63;
  const int qc = ln & 15;
  const int rbase = row0 + wv*16;
  const unsigned short* aptr = Abf + (size_t)(rbase + qc)*K + ((ln >> 4) << 3);
  const unsigned short* bptr = Wpk + ((size_t)part*KT*NTP + nt0)*512 + (size_t)ln*8;
  f32x4 acc[4];
#pragma unroll
  for (int i = 0; i < 4; ++i) acc[i] = f32x4{0.f,0.f,0.f,0.f};
#pragma unroll
  for (int kt = 0; kt < KT; ++kt) {
    short8v a = *reinterpret_cast<const short8v*>(aptr + kt*32);
    const unsigned short* bk = bptr + (size_t)kt*NTP*512;
#pragma unroll
    for (int i = 0; i < 4; ++i)
      acc[i] = __builtin_amdgcn_mfma_f32_16x16x32_bf16(
          a, *reinterpret_cast<const short8v*>(bk + i*512), acc[i], 0, 0, 0);
  }
  const int rowe = rbase + ((ln >> 4) << 2);
#pragma unroll
  for (int i = 0; i < 4; ++i) {
    const int cl = (nt0 + i)*16 + qc;
    const int h = cl >> 5, dh = cl & 31;
    const float bs = bias[part*PN + cl];
#pragma unroll
    for (int r = 0; r < 4; ++r) {
      float v = acc[i][r] + bs;
      const int row = rowe + r;
      const int key = row & (L_-1);
      if (part == 0) {
        v *= 0.25506972533f;  // 1/sqrt(32)*log2e
        qbf[(size_t)row*128 + cl] = f2bf(v);
      } else if (part == 1) {
        const size_t idx = (((size_t)((bb*4 + h)*32 + (key>>5))*2 + ((key>>4)&1))*64
                            + ((dh>>3)*16 + (key&15)))*8 + (dh&7);
        kfrag[idx] = f2bf(v);
      } else {
        const int kk = key & 31;
        const size_t idx = (((size_t)((bb*4 + h)*32 + (key>>5))*2 + (dh>>4))*64
                            + (((kk&15)>>2)*16 + (dh&15)))*8 + ((kk>>4)*4 + (kk&3));
        vfrag[idx] = f2bf(v);
      }
    }
  }
}

// ---------------- MFMA GEMM + residual + LayerNorm fused (D=64 rows) ----------
template<int K>
__global__ __launch_bounds__(256) void mgemm_ln64_kernel(
    const unsigned short* __restrict__ Abf,
    const unsigned short* __restrict__ Wpk,
    const float* __restrict__ bias,
    float* __restrict__ x,                 // residual in, fp32 out (in-place)
    const float* __restrict__ gam, const float* __restrict__ bet,
    unsigned short* __restrict__ xbf)
{
  constexpr int KT = K/32;
  const int row0 = blockIdx.x * 64;
  const int wv = (int)threadIdx.x >> 6;
  const int ln = (int)threadIdx.x & 63;
  const int rbase = row0 + wv*16;
  const unsigned short* aptr = Abf + (size_t)(rbase + (ln & 15))*K + ((ln >> 4) << 3);
  const unsigned short* bptr = Wpk + (size_t)ln*8;
  f32x4 acc0 = {0.f,0.f,0.f,0.f}, acc1 = {0.f,0.f,0.f,0.f};
  f32x4 acc2 = {0.f,0.f,0.f,0.f}, acc3 = {0.f,0.f,0.f,0.f};
#pragma unroll
  for (int kt = 0; kt < KT; ++kt) {
    short8v a = *reinterpret_cast<const short8v*>(aptr + kt*32);
    const unsigned short* bk = bptr + (size_t)kt*4*512;
    short8v b0 = *reinterpret_cast<const short8v*>(bk);
    short8v b1 = *reinterpret_cast<const short8v*>(bk + 512);
    short8v b2 = *reinterpret_cast<const short8v*>(bk + 1024);
    short8v b3 = *reinterpret_cast<const short8v*>(bk + 1536);
    acc0 = __builtin_amdgcn_mfma_f32_16x16x32_bf16(a, b0, acc0, 0, 0, 0);
    acc1 = __builtin_amdgcn_mfma_f32_16x16x32_bf16(a, b1, acc1, 0, 0, 0);
    acc2 = __builtin_amdgcn_mfma_f32_16x16x32_bf16(a, b2, acc2, 0, 0, 0);
    acc3 = __builtin_amdgcn_mfma_f32_16x16x32_bf16(a, b3, acc3, 0, 0, 0);
  }
  const int colc = ln & 15;
  const int rowe = rbase + ((ln >> 4) << 2);
  f32x4 av[4] = {acc0, acc1, acc2, acc3};
  float v[4][4];
#pragma unroll
  for (int i = 0; i < 4; ++i) {
    const int col = i*16 + colc;
    const float bs = bias[col];
#pragma unroll
    for (int r = 0; r < 4; ++r)
      v[i][r] = av[i][r] + bs + x[(size_t)(rowe + r)*64 + col];
  }
  float rs[4];
#pragma unroll
  for (int r = 0; r < 4; ++r) rs[r] = v[0][r]+v[1][r]+v[2][r]+v[3][r];
#pragma unroll
  for (int m = 1; m <= 8; m <<= 1)
#pragma unroll
    for (int r = 0; r < 4; ++r) rs[r] += __shfl_xor(rs[r], m, 64);
  float mean[4], vs[4];
#pragma unroll
  for (int r = 0; r < 4; ++r) { mean[r] = rs[r]*(1.0f/64.0f); vs[r] = 0.f; }
#pragma unroll
  for (int i = 0; i < 4; ++i)
#pragma unroll
    for (int r = 0; r < 4; ++r) { const float d = v[i][r]-mean[r]; vs[r] = fmaf(d, d, vs[r]); }
#pragma unroll
  for (int m = 1; m <= 8; m <<= 1)
#pragma unroll
    for (int r = 0; r < 4; ++r) vs[r] += __shfl_xor(vs[r], m, 64);
  float rstd[4];
#pragma unroll
  for (int r = 0; r < 4; ++r) rstd[r] = rsqrtf(vs[r]*(1.0f/64.0f) + 1e-5f);
#pragma unroll
  for (int i = 0; i < 4; ++i) {
    const int col = i*16 + colc;
    const float g = gam[col], bb = bet[col];
#pragma unroll
    for (int r = 0; r < 4; ++r) {
      const float out = (v[i][r]-mean[r])*rstd[r]*g + bb;
      x[(size_t)(rowe + r)*64 + col] = out;
      xbf[(size_t)(rowe + r)*64 + col] = f2bf(out);
    }
  }
}

// ---------------- MFMA GEMM + residual + LayerNorm fused (D=128 rows, gated) --
template<int K>
__global__ __launch_bounds__(256) void mgemm_ln128_kernel(
    const unsigned short* __restrict__ Abf,
    const unsigned short* __restrict__ Wpk,
    const float* __restrict__ bias,
    float* __restrict__ x,                 // residual in, fp32 out (in-place)
    const float* __restrict__ gam, const float* __restrict__ bet,
    const int* __restrict__ nseg, unsigned short* __restrict__ xbf)
{
  constexpr int KT = K/32;
  const int row0 = blockIdx.x * 64;
  if ((row0 & (L_-1)) >= nseg[row0 >> 10]) return;
  const int wv = (int)threadIdx.x >> 6;
  const int ln = (int)threadIdx.x & 63;
  const int qc = ln & 15;
  const int rbase = row0 + wv*16;
  const unsigned short* aptr = Abf + (size_t)(rbase + qc)*K + ((ln >> 4) << 3);
  const unsigned short* bptr = Wpk + (size_t)ln*8;
  f32x4 acc[8];
#pragma unroll
  for (int i = 0; i < 8; ++i) acc[i] = f32x4{0.f,0.f,0.f,0.f};
#pragma unroll
  for (int kt = 0; kt < KT; ++kt) {
    short8v a = *reinterpret_cast<const short8v*>(aptr + kt*32);
    const unsigned short* bk = bptr + (size_t)kt*8*512;
#pragma unroll
    for (int i = 0; i < 8; ++i)
      acc[i] = __builtin_amdgcn_mfma_f32_16x16x32_bf16(
          a, *reinterpret_cast<const short8v*>(bk + i*512), acc[i], 0, 0, 0);
  }
  const int rowe = rbase + ((ln >> 4) << 2);
  float v[8][4];
#pragma unroll
  for (int i = 0; i < 8; ++i) {
    const int col = i*16 + qc;
    const float bs = bias[col];
#pragma unroll
    for (int r = 0; r < 4; ++r)
      v[i][r] = acc[i][r] + bs + x[(size_t)(rowe + r)*128 + col];
  }
  float rs[4];
#pragma unroll
  for (int r = 0; r < 4; ++r)
    rs[r] = ((v[0][r]+v[1][r])+(v[2][r]+v[3][r])) + ((v[4][r]+v[5][r])+(v[6][r]+v[7][r]));
#pragma unroll
  for (int m = 1; m <= 8; m <<= 1)
#pragma unroll
    for (int r = 0; r < 4; ++r) rs[r] += __shfl_xor(rs[r], m, 64);
  float mean[4], vs[4];
#pragma unroll
  for (int r = 0; r < 4; ++r) { mean[r] = rs[r]*(1.0f/128.0f); vs[r] = 0.f; }
#pragma unroll
  for (int i = 0; i < 8; ++i)
#pragma unroll
    for (int r = 0; r < 4; ++r) { const float d = v[i][r]-mean[r]; vs[r] = fmaf(d, d, vs[r]); }
#pragma unroll
  for (int m = 1; m <= 8; m <<= 1)
#pragma unroll
    for (int r = 0; r < 4; ++r) vs[r] += __shfl_xor(vs[r], m, 64);
  float rstd[4];
#pragma unroll
  for (int r = 0; r < 4; ++r) rstd[r] = rsqrtf(vs[r]*(1.0f/128.0f) + 1e-5f);
#pragma unroll
  for (int i = 0; i < 8; ++i) {
    const int col = i*16 + qc;
    const float g = gam[col], bb = bet[col];
#pragma unroll
    for (int r = 0; r < 4; ++r) {
      const float out = (v[i][r]-mean[r])*rstd[r]*g + bb;
      x[(size_t)(rowe + r)*128 + col] = out;
      xbf[(size_t)(rowe + r)*128 + col] = f2bf(out);
    }
  }
}

// ---------------- featurize: 4 points per 256-thr block (dual-write) ----------
__global__ __launch_bounds__(256) void featurize_kernel(
    const float* __restrict__ pts, const float* __restrict__ fs, const float* __restrict__ ft,
    const float* __restrict__ w_space, const float* __restrict__ b_space,
    const float* __restrict__ w_time, const float* __restrict__ b_time,
    const float* __restrict__ w_fout, const float* __restrict__ b_fout,
    const float* __restrict__ w_gate, const float* __restrict__ b_gate,
    float* __restrict__ z, unsigned short* __restrict__ zbf, int* __restrict__ boundary)
{
  const int sub = threadIdx.x >> 6;
  const int d   = threadIdx.x & 63;
  const int p   = blockIdx.x * 4 + sub;
  const float TWO_PI = 6.283185307179586f;
  __shared__ float feat[4][32];
  __shared__ float tfeat[4][16];
  __shared__ float g96[4][96];
  const float x = pts[p*3+0], y = pts[p*3+1], t = pts[p*3+2];
  if (d < 16) {
    float sp = (x*fs[d] + y*fs[16+d]) * TWO_PI;
    feat[sub][d]    = sinf(sp);
    feat[sub][16+d] = cosf(sp);
  } else if (d < 24) {
    int r = d - 16;
    float tp = t * ft[r] * TWO_PI;
    tfeat[sub][r]   = sinf(tp);
    tfeat[sub][8+r] = cosf(tp);
  }
  __syncthreads();
  float sf = b_space[d];
#pragma unroll
  for (int k2 = 0; k2 < 32; ++k2) sf = fmaf(feat[sub][k2], w_space[k2*64+d], sf);
  g96[sub][d] = sf;
  if (d < 32) {
    float tf = b_time[d];
#pragma unroll
    for (int k2 = 0; k2 < 16; ++k2) tf = fmaf(tfeat[sub][k2], w_time[k2*32+d], tf);
    g96[sub][64+d] = tf;
  }
  __syncthreads();
  float zv = b_fout[d];
#pragma unroll
  for (int k2 = 0; k2 < 96; ++k2) zv = fmaf(g96[sub][k2], w_fout[k2*64+d], zv);
  z[(size_t)p*64+d] = zv;
  zbf[(size_t)p*64+d] = f2bf(zv);
  float gv = wave_reduce_sum(zv * w_gate[d]);
  if (d == 0) {
    float logit = gv + b_gate[0];
    float gate = 1.0f / (1.0f + expf(-logit));
    int bnd = (gate > 0.5f) ? 1 : 0;
    if ((p & (L_-1)) == 0) bnd = 1;
    boundary[p] = bnd;
  }
}

// ---------------- scan: seg_id, seg_start, n_seg ----------------
__global__ __launch_bounds__(1024) void scan_kernel(const int* __restrict__ boundary,
    int* __restrict__ seg_id, int* __restrict__ seg_start, int* __restrict__ n_seg)
{
  __shared__ int sc[1024];
  const int b = blockIdx.x, l = threadIdx.x;
  const int v = boundary[b*L_ + l];
  sc[l] = v;
  __syncthreads();
  for (int off = 1; off < 1024; off <<= 1) {
    int add = (l >= off) ? sc[l - off] : 0;
    __syncthreads();
    sc[l] += add;
    __syncthreads();
  }
  const int sid = sc[l] - 1;
  seg_id[b*L_ + l] = sid;
  if (v) seg_start[b*(L_+1) + sid] = l;
  if (l == L_-1) {
    n_seg[b] = sid + 1;
    seg_start[b*(L_+1) + sid + 1] = L_;
  }
}

// ---------------- segment attention: 8 lanes per (pt,h) item -------------------
__global__ __launch_bounds__(256) void seg_attn_kernel(
    const float* __restrict__ qkv,
    const int* __restrict__ seg_id, const int* __restrict__ seg_start,
    unsigned short* __restrict__ aobf)
{
  const int gid = blockIdx.x * 256 + (int)threadIdx.x;  // item*8 + sub
  const int sub = gid & 7;
  const int item = gid >> 3;        // ((b*L + pt)*2 + h)
  const int h  = item & 1;
  const int pt = (item >> 1) & (L_-1);
  const int b  = item >> 11;
  const float scale = 0.17677669529663687f;
  float4 q4 = *reinterpret_cast<const float4*>(qkv + (size_t)(b*L_+pt)*192 + h*32 + sub*4);
  q4.x*=scale; q4.y*=scale; q4.z*=scale; q4.w*=scale;
  const int s  = seg_id[b*L_ + pt];
  const int j0 = seg_start[b*(L_+1) + s];
  const int j1 = seg_start[b*(L_+1) + s + 1];
  float lsum = 0.f;
  float4 acc = {0.f,0.f,0.f,0.f};
  for (int j = j0; j < j1; ++j) {
    const float* base = qkv + (size_t)(b*L_ + j)*192 + h*32 + sub*4;
    float4 k4 = *reinterpret_cast<const float4*>(base + 64);
    float4 v4 = *reinterpret_cast<const float4*>(base + 128);
    float dot = q4.x*k4.x;
    dot = fmaf(q4.y, k4.y, dot);
    dot = fmaf(q4.z, k4.z, dot);
    dot = fmaf(q4.w, k4.w, dot);
    dot += __shfl_xor(dot, 1, 64);
    dot += __shfl_xor(dot, 2, 64);
    dot += __shfl_xor(dot, 4, 64);
    const float p = __expf(fminf(dot, 30.f));
    lsum += p;
    acc.x = fmaf(p, v4.x, acc.x);
    acc.y = fmaf(p, v4.y, acc.y);
    acc.z = fmaf(p, v4.z, acc.z);
    acc.w = fmaf(p, v4.w, acc.w);
  }
  const float inv = 1.0f / lsum;
  unsigned* op = reinterpret_cast<unsigned*>(aobf + (size_t)(b*L_+pt)*64 + h*32 + sub*4);
  op[0] = (unsigned)f2bf(acc.x*inv) | ((unsigned)f2bf(acc.y*inv) << 16);
  op[1] = (unsigned)f2bf(acc.z*inv) | ((unsigned)f2bf(acc.w*inv) << 16);
}

// ---------------- global attention via MFMA (coalesced frags, XCD-swizzled) ----
// launch: blockIdx.x = qt*64 + (b*4+h); Q pre-scaled by 1/sqrt(32)*log2e.
__global__ __launch_bounds__(256) void glb_attn_mfma_kernel(
    const unsigned short* __restrict__ qbf,     // [16384][128] bf16 (pre-scaled Q)
    const unsigned short* __restrict__ kfrag,
    const unsigned short* __restrict__ vfrag,
    const int* __restrict__ n_seg,
    unsigned short* __restrict__ aobf)          // [16384][128] bf16
{
  const int g64 = blockIdx.x & 63;    // (b*4 + h)
  const int qt  = blockIdx.x >> 6;
  const int h  = g64 & 3;
  const int b  = g64 >> 2;
  const int ns = n_seg[b];
  if (qt*64 >= ns) return;
  const int wv = (int)threadIdx.x >> 6;
  const int ln = (int)threadIdx.x & 63;
  const int g  = ln >> 4;
  const int qc = ln & 15;
  __shared__ float lsumS[4][16];

  const int q0 = qt*64 + wv*16;
  const short8v qf = *reinterpret_cast<const short8v*>(
      qbf + (size_t)(b*L_ + q0 + qc)*128 + h*32 + g*8);

  f32x4 O0 = {0.f,0.f,0.f,0.f}, O1 = {0.f,0.f,0.f,0.f};
  const f32x4 zz = {0.f,0.f,0.f,0.f};
  float lsum = 0.f;
  const unsigned short* kfb = kfrag + (size_t)((b*4 + h)*32)*1024 + (size_t)ln*8;
  const unsigned short* vfb = vfrag + (size_t)((b*4 + h)*32)*1024 + (size_t)ln*8;

  const int nfull = ns >> 5;
#pragma unroll 2
  for (int c = 0; c < nfull; ++c) {
    short8v kf0 = *reinterpret_cast<const short8v*>(kfb);
    short8v kf1 = *reinterpret_cast<const short8v*>(kfb + 512);
    short8v v0  = *reinterpret_cast<const short8v*>(vfb);
    short8v v1  = *reinterpret_cast<const short8v*>(vfb + 512);
    f32x4 s0 = __builtin_amdgcn_mfma_f32_16x16x32_bf16(kf0, qf, zz, 0, 0, 0);
    f32x4 s1 = __builtin_amdgcn_mfma_f32_16x16x32_bf16(kf1, qf, zz, 0, 0, 0);
    float p[8];
#pragma unroll
    for (int r = 0; r < 4; ++r) {
      const float e0 = exp2f(fminf(s0[r], 43.f));
      const float e1 = exp2f(fminf(s1[r], 43.f));
      p[r] = e0; p[4+r] = e1;
      lsum += e0 + e1;
    }
    short8v pf;
#pragma unroll
    for (int i = 0; i < 8; ++i) pf[i] = (short)f2bf(p[i]);
    O0 = __builtin_amdgcn_mfma_f32_16x16x32_bf16(pf, v0, O0, 0, 0, 0);
    O1 = __builtin_amdgcn_mfma_f32_16x16x32_bf16(pf, v1, O1, 0, 0, 0);
    kfb += 1024; vfb += 1024;
  }
  if (ns & 31) {   // masked tail chunk
    short8v kf0 = *reinterpret_cast<const short8v*>(kfb);
    short8v kf1 = *reinterpret_cast<const short8v*>(kfb + 512);
    short8v v0  = *reinterpret_cast<const short8v*>(vfb);
    short8v v1  = *reinterpret_cast<const short8v*>(vfb + 512);
    f32x4 s0 = __builtin_amdgcn_mfma_f32_16x16x32_bf16(kf0, qf, zz, 0, 0, 0);
    f32x4 s1 = __builtin_amdgcn_mfma_f32_16x16x32_bf16(kf1, qf, zz, 0, 0, 0);
    const int k0 = nfull*32;
    float p[8];
#pragma unroll
    for (int r = 0; r < 4; ++r) {
      const int key0 = k0 + g*4 + r;
      const float e0 = (key0 < ns)      ? exp2f(fminf(s0[r], 43.f)) : 0.f;
      const float e1 = (key0 + 16 < ns) ? exp2f(fminf(s1[r], 43.f)) : 0.f;
      p[r] = e0; p[4+r] = e1;
      lsum += e0 + e1;
    }
    short8v pf;
#pragma unroll
    for (int i = 0; i < 8; ++i) pf[i] = (short)f2bf(p[i]);
    O0 = __builtin_amdgcn_mfma_f32_16x16x32_bf16(pf, v0, O0, 0, 0, 0);
    O1 = __builtin_amdgcn_mfma_f32_16x16x32_bf16(pf, v1, O1, 0, 0, 0);
  }
  lsum += __shfl_xor(lsum, 16, 64);
  lsum += __shfl_xor(lsum, 32, 64);
  if (ln < 16) lsumS[wv][ln] = lsum;
  __syncthreads();
  unsigned short* outp = aobf + (size_t)(b*L_ + q0 + g*4)*128 + h*32 + qc;
#pragma unroll
  for (int r = 0; r < 4; ++r) {
    const float inv = 1.0f / lsumS[wv][g*4 + r];
    outp[(size_t)r*128]      = f2bf(O0[r]*inv);
    outp[(size_t)r*128 + 16] = f2bf(O1[r]*inv);
  }
}

// ---------------- segment mean pooling -> bf16 [row][64] ----------------
__global__ __launch_bounds__(256) void pool_kernel(
    const float* __restrict__ h, const int* __restrict__ seg_start,
    const int* __restrict__ n_seg, unsigned short* __restrict__ meanbf)
{
  const int gs = blockIdx.x*4 + ((int)threadIdx.x >> 6);
  const int b = gs >> 10, s = gs & (L_-1);
  const int d = (int)threadIdx.x & 63;
  if (s >= n_seg[b]) return;
  const int j0 = seg_start[b*(L_+1)+s], j1 = seg_start[b*(L_+1)+s+1];
  float acc = 0.f;
  for (int j = j0; j < j1; ++j) acc += h[(size_t)(b*L_+j)*64 + d];
  meanbf[(size_t)gs*64 + d] = f2bf(acc / (float)(j1 - j0));
}

// ---------------- final pooling phase A ----------------
__global__ __launch_bounds__(128) void pool_final_kernel(
    const float* __restrict__ g, const int* __restrict__ n_seg,
    float* __restrict__ partial)
{
  const int b = blockIdx.x >> 4, c = blockIdx.x & 15;
  const int d = (int)threadIdx.x;
  const int ns = n_seg[b];
  const int i0 = c*64, i1 = min(ns, i0 + 64);
  float acc = 0.f;
  for (int i = i0; i < i1; ++i) acc += g[(size_t)(b*L_+i)*128 + d];
  partial[(size_t)blockIdx.x*128 + d] = acc;
}

// ---------------- final phase B ----------------
__global__ __launch_bounds__(128) void final_kernel(
    const float* __restrict__ partial, const float* __restrict__ semb0,
    const int* __restrict__ n_seg, const float* __restrict__ fin_w,
    const float* __restrict__ fin_b, float* __restrict__ out)
{
  const int b = blockIdx.x, d = threadIdx.x;
  const int ns = n_seg[b];
  __shared__ float pl[128];
  float pooled;
  if (ns == 1) pooled = semb0[b*128 + d];
  else {
    float acc = 0.f;
#pragma unroll
    for (int c = 0; c < 16; ++c) acc += partial[(size_t)(b*16 + c)*128 + d];
    pooled = acc / (float)ns;
  }
  pl[d] = pooled;
  __syncthreads();
  float o = fin_b[d];
#pragma unroll 8
  for (int k2 = 0; k2 < 128; ++k2) o = fmaf(pl[k2], fin_w[k2*128+d], o);
  out[b*128+d] = o;
}

extern "C" void kernel_launch(void* const* d_in, const int* in_sizes, int n_in,
                              void* d_out, int out_size, void* d_ws, size_t ws_size,
                              hipStream_t stream) {
  const float* pts     = (const float*)d_in[0];
  const float* fs      = (const float*)d_in[1];
  const float* ft      = (const float*)d_in[2];
  const float* w_space = (const float*)d_in[3];
  const float* b_space = (const float*)d_in[4];
  const float* w_time  = (const float*)d_in[5];
  const float* b_time  = (const float*)d_in[6];
  const float* w_fout  = (const float*)d_in[7];
  const float* b_fout  = (const float*)d_in[8];
  const float* w_gate  = (const float*)d_in[9];
  const float* b_gate  = (const float*)d_in[10];
  const float* seg_attn_w = (const float*)d_in[11];
  const float* seg_attn_b = (const float*)d_in[12];
  const float* seg_ln_g   = (const float*)d_in[13];
  const float* seg_ln_b   = (const float*)d_in[14];
  const float* seg_ff1_w  = (const float*)d_in[15];
  const float* seg_ff1_b  = (const float*)d_in[16];
  const float* seg_ff2_w  = (const float*)d_in[17];
  const float* seg_ff2_b  = (const float*)d_in[18];
  const float* glb_attn_w = (const float*)d_in[19];
  const float* glb_attn_b = (const float*)d_in[20];
  const float* glb_ln_g   = (const float*)d_in[21];
  const float* glb_ln_b   = (const float*)d_in[22];
  const float* glb_ff1_w  = (const float*)d_in[23];
  const float* glb_ff1_b  = (const float*)d_in[24];
  const float* glb_ff2_w  = (const float*)d_in[25];
  const float* glb_ff2_b  = (const float*)d_in[26];
  const float* up_w    = (const float*)d_in[27];
  const float* up_b    = (const float*)d_in[28];
  const float* fin_w   = (const float*)d_in[29];
  const float* fin_b   = (const float*)d_in[30];

  char* ws = (char*)d_ws;
  float* zx   = (float*)(ws);
  unsigned short* xg_bf = (unsigned short*)(ws);
  float* qkv  = (float*)(ws + ((size_t)4  << 20));   // seg fp32 qkv [16384][192]
  float* xg   = (float*)(ws + ((size_t)38 << 20));
  unsigned short* zx_bf = (unsigned short*)(ws + ((size_t)38 << 20));
  int* boundary  = (int*)(ws + ((size_t)46 << 20));
  int* seg_id    = boundary + M_TOT;
  int* seg_start = seg_id + M_TOT;
  int* n_seg     = seg_start + B_*(L_+1);
  float* semb0     = (float*)(ws + ((size_t)47 << 20));
  float* partial   = (float*)(ws + ((size_t)47 << 20) + 65536);
  unsigned short* tmp_bf = (unsigned short*)(ws + ((size_t)50 << 20));  // 8MB
  unsigned short* vfrag  = (unsigned short*)(ws + ((size_t)58 << 20));  // 4MB
  unsigned short* kfrag  = (unsigned short*)(ws + ((size_t)62 << 20));  // 4MB
  unsigned short* qbf    = (unsigned short*)(ws + ((size_t)66 << 20));  // 4MB
  unsigned short* abf    = (unsigned short*)(ws + ((size_t)84 << 20));
  unsigned short* wpk    = (unsigned short*)(ws + ((size_t)88 << 20));

  unsigned short* wpk_segA  = wpk;
  unsigned short* wpk_segF1 = wpk + 32768;
  unsigned short* wpk_segF2 = wpk + 49152;
  unsigned short* wpk_glbA  = wpk + 65536;
  unsigned short* wpk_glbF1 = wpk + 196608;
  unsigned short* wpk_glbF2 = wpk + 262144;
  unsigned short* wpk_up    = wpk + 327680;

  pack_all_kernel<<<164, 256, 0, stream>>>(seg_attn_w, seg_ff1_w, seg_ff2_w,
                                           glb_attn_w, glb_ff1_w, glb_ff2_w, up_w, wpk);

  featurize_kernel<<<M_TOT/4, 256, 0, stream>>>(pts, fs, ft, w_space, b_space, w_time, b_time,
                                                w_fout, b_fout, w_gate, b_gate, zx, zx_bf, boundary);
  scan_kernel<<<B_, 1024, 0, stream>>>(boundary, seg_id, seg_start, n_seg);

  // ---- segment-level encoder (D=64, H=2, FF=128); LN fused into GEMM epilogues
  for (int l = 0; l < 2; ++l) {
    const float* ab = seg_attn_b + (size_t)l*4*64;
    mgemm_kernel<64,64,3,false,false,true,false><<<dim3(256,3),256,0,stream>>>(
        zx_bf, wpk_segA + (size_t)l*4*4096, ab, qkv, nullptr, nullptr, nullptr);
    seg_attn_kernel<<<(M_TOT*2*8)/256, 256, 0, stream>>>(qkv, seg_id, seg_start, abf);
    mgemm_ln64_kernel<64><<<256,256,0,stream>>>(
        abf, wpk_segA + (size_t)(l*4+3)*4096, ab + 192,
        zx, seg_ln_g + l*128, seg_ln_b + l*128, zx_bf);
    mgemm_kernel<64,128,1,true,false,false,true><<<dim3(256,2),256,0,stream>>>(
        zx_bf, wpk_segF1 + (size_t)l*8192, seg_ff1_b + l*128, nullptr, tmp_bf, nullptr, nullptr);
    mgemm_ln64_kernel<128><<<256,256,0,stream>>>(
        tmp_bf, wpk_segF2 + (size_t)l*8192, seg_ff2_b + l*64,
        zx, seg_ln_g + l*128 + 64, seg_ln_b + l*128 + 64, zx_bf);
  }

  // ---- pooling + up-projection (gated; semb0 snapshot fused) ----
  pool_kernel<<<M_TOT/4, 256, 0, stream>>>(zx, seg_start, n_seg, abf);
  mgemm_kernel<64,128,1,false,true,true,true,-1,true><<<dim3(256,2),256,0,stream>>>(
      abf, wpk_up, up_b, xg, xg_bf, n_seg, semb0);

  // ---- global-level encoder (D=128, H=4, FF=256), row-gated ----
  for (int l = 0; l < 2; ++l) {
    const float* ab = glb_attn_b + (size_t)l*4*128;
    mgemm_qkvfrag_kernel<<<dim3(256,6),256,0,stream>>>(
        xg_bf, wpk_glbA + (size_t)l*4*16384, ab, qbf, kfrag, vfrag, n_seg);
    glb_attn_mfma_kernel<<<B_*4*16, 256, 0, stream>>>(qbf, kfrag, vfrag, n_seg, abf);
    mgemm_ln128_kernel<128><<<256,256,0,stream>>>(
        abf, wpk_glbA + (size_t)(l*4+3)*16384, ab + 384,
        xg, glb_ln_g + l*256, glb_ln_b + l*256, n_seg, xg_bf);
    mgemm_kernel<128,256,1,true,true,false,true><<<dim3(256,4),256,0,stream>>>(
        xg_bf, wpk_glbF1 + (size_t)l*32768, glb_ff1_b + l*256, nullptr, tmp_bf, n_seg, nullptr);
    mgemm_ln128_kernel<256><<<256,256,0,stream>>>(
        tmp_bf, wpk_glbF2 + (size_t)l*32768, glb_ff2_b + l*128,
        xg, glb_ln_g + l*256 + 128, glb_ln_b + l*256 + 128, n_seg, xg_bf);
  }

  pool_final_kernel<<<B_*16, 128, 0, stream>>>(xg, n_seg, partial);
  final_kernel<<<B_, 128, 0, stream>>>(partial, semb0, n_seg, fin_w, fin_b, (float*)d_out);
}